// Round 13
// baseline (315.202 us; speedup 1.0000x reference)
//
#include <hip/hip_runtime.h>
#include <hip/hip_bf16.h>

typedef __bf16 bf16_t;
typedef __bf16 bf16x8 __attribute__((ext_vector_type(8)));
typedef __bf16 bf16x4 __attribute__((ext_vector_type(4)));
typedef float  f32x4  __attribute__((ext_vector_type(4)));
typedef __attribute__((address_space(3))) unsigned int lds_u32_t;
typedef __attribute__((address_space(1))) const unsigned int glb_u32_t;

#define B_    2
#define S_    2048
#define HID_  2048
#define H_    16
#define DH_   192
#define DR_   64
#define DN_   128
#define QL_   512
#define NROWS (B_*S_)          // 4096
#define QKD   (H_*DH_)         // 3072

#if __has_builtin(__builtin_amdgcn_exp2f)
#define EXP2(x) __builtin_amdgcn_exp2f(x)
#else
#define EXP2(x) exp2f(x)
#endif

// XCD-aware bijective block swizzle (requires nwg % 8 == 0).
__device__ inline void xcd_remap(int& bx, int& by) {
  const int gx = gridDim.x;
  const int nwg = gx * gridDim.y;
  const int flat = by * gx + bx;
  const int q = nwg >> 3;
  const int nf = (flat & 7) * q + (flat >> 3);
  bx = nf % gx;
  by = nf / gx;
}

// ---------------- cast f32 -> bf16 (vec4) ----------------
__global__ void cast_f32_to_bf16(const float* __restrict__ in, bf16_t* __restrict__ out, int n4) {
  int i = blockIdx.x * blockDim.x + threadIdx.x;
  if (i >= n4) return;
  const float4 v = reinterpret_cast<const float4*>(in)[i];
  bf16x4 r;
  r[0] = (bf16_t)v.x; r[1] = (bf16_t)v.y; r[2] = (bf16_t)v.z; r[3] = (bf16_t)v.w;
  reinterpret_cast<bf16x4*>(out)[i] = r;
}

// ---------------- all 5 weight transposes in one launch ----------------
__global__ __launch_bounds__(256) void transpose_all(
    const float* __restrict__ i0, const float* __restrict__ i1,
    const float* __restrict__ i2, const float* __restrict__ i3,
    const float* __restrict__ i4,
    bf16_t* __restrict__ o0, bf16_t* __restrict__ o1, bf16_t* __restrict__ o2,
    bf16_t* __restrict__ o3, bf16_t* __restrict__ o4) {
  int id = blockIdx.x;
  const float* in; bf16_t* out; int R, C, lid;
  if (id < 1024)      { in = i0; out = o0; R = 2048; C = 512;  lid = id; }
  else if (id < 2560) { in = i1; out = o1; R = 512;  C = 3072; lid = id - 1024; }
  else if (id < 2944) { in = i2; out = o2; R = 2048; C = 192;  lid = id - 2560; }
  else if (id < 3328) { in = i3; out = o3; R = 2048; C = 192;  lid = id - 2944; }
  else                { in = i4; out = o4; R = 3072; C = 2048; lid = id - 3328; }
  const int cw = C >> 5;
  const int c0 = (lid % cw) * 32, r0 = (lid / cw) * 32;
  __shared__ float t[32][33];
  const int tx = threadIdx.x & 31;
  const int ty = threadIdx.x >> 5;
#pragma unroll
  for (int j = 0; j < 4; ++j)
    t[ty + j * 8][tx] = in[(size_t)(r0 + ty + j * 8) * C + c0 + tx];
  __syncthreads();
#pragma unroll
  for (int j = 0; j < 4; ++j)
    out[(size_t)(c0 + ty + j * 8) * R + r0 + tx] = (bf16_t)t[tx][ty + j * 8];
}

// ---------------- merged K/V GEMM (64x64 tile), B^T input, K-RoPE fused ------
#define BM 64
#define BN 64
#define BK 64
#define LDT 72

__global__ __launch_bounds__(256) void gemm_kv_kernel(
    const bf16_t* __restrict__ A, const bf16_t* __restrict__ BT,
    bf16_t* __restrict__ Kout, bf16_t* __restrict__ VTout) {
  __shared__ __align__(16) bf16_t sA[BM][LDT];
  __shared__ __align__(16) bf16_t sB[BN][LDT];
  const int tid = threadIdx.x;
  const int w  = tid >> 6;
  const int l  = tid & 63;
  const int lg = l >> 4, lr = l & 15;
  int bx = blockIdx.x, by = blockIdx.y;
  xcd_remap(bx, by);
  const int m0 = by * BM, n0 = bx * BN;
  const int K = HID_;

  f32x4 acc[4];
#pragma unroll
  for (int c = 0; c < 4; ++c) acc[c] = f32x4{0.f, 0.f, 0.f, 0.f};

  for (int k0 = 0; k0 < K; k0 += BK) {
#pragma unroll
    for (int i = 0; i < 2; ++i) {
      int cid = tid + i * 256;
      int row = cid >> 3;
      int cb  = (cid & 7) * 8;
      *reinterpret_cast<uint4*>(&sA[row][cb]) =
          *reinterpret_cast<const uint4*>(&A[(size_t)(m0 + row) * K + k0 + cb]);
      *reinterpret_cast<uint4*>(&sB[row][cb]) =
          *reinterpret_cast<const uint4*>(&BT[(size_t)(n0 + row) * K + k0 + cb]);
    }
    __syncthreads();
#pragma unroll
    for (int ks = 0; ks < 2; ++ks) {
      bf16x8 af = *reinterpret_cast<const bf16x8*>(&sA[w * 16 + lr][ks * 32 + lg * 8]);
#pragma unroll
      for (int c = 0; c < 4; ++c) {
        bf16x8 bfr = *reinterpret_cast<const bf16x8*>(&sB[c * 16 + lr][ks * 32 + lg * 8]);
        acc[c] = __builtin_amdgcn_mfma_f32_16x16x32_bf16(af, bfr, acc[c], 0, 0, 0);
      }
    }
    __syncthreads();
  }

  // ---- fused K-RoPE: the n0==128 tile holds cols 128..191 = rope region ----
  if (n0 == 128) {
#pragma unroll
    for (int c = 0; c < 2; ++c) {
      const float invf = expf((float)(c * 16 + lr) * (-9.210340371976184f / 32.0f));
#pragma unroll
      for (int r = 0; r < 4; ++r) {
        int s = (m0 + w * 16 + lg * 4 + r) & (S_ - 1);
        float sn, cs;
        sincosf((float)s * invf, &sn, &cs);
        float x1 = acc[c][r], x2 = acc[c + 2][r];
        acc[c][r]     = x1 * cs - x2 * sn;
        acc[c + 2][r] = x2 * cs + x1 * sn;
      }
    }
  }

#pragma unroll
  for (int c = 0; c < 4; ++c) {
#pragma unroll
    for (int r = 0; r < 4; ++r) {
      int row = m0 + w * 16 + lg * 4 + r;
      int col = n0 + c * 16 + lr;
      float v = acc[c][r];
      if (col < DH_) Kout[(size_t)row * DH_ + col] = (bf16_t)v;
      else           VTout[(size_t)(col - DH_) * NROWS + row] = (bf16_t)v;
    }
  }
}

// ---------------- big bf16 MFMA GEMM (128x128x64 tile, m97 structure) --------
// OMODE 0: f32 C; OMODE 1: bf16 C scaled by oscale. ROPE: fused Q-RoPE
// (head h's rope region = one 64-col wave-half: 2*bx+wn == 3h+2).
template<int OMODE, bool ROPE>
__global__ __launch_bounds__(256) void gemm128_kernel(
    const bf16_t* __restrict__ A, const bf16_t* __restrict__ BT,
    void* __restrict__ C, int M, int N, int K, float oscale) {
  __shared__ __align__(16) bf16_t sA[128 * 64];
  __shared__ __align__(16) bf16_t sB[128 * 64];
  const int tid = threadIdx.x;
  const int w  = tid >> 6;
  const int l  = tid & 63;
  const int lg = l >> 4, lr = l & 15;
  const int wm = w >> 1, wn = w & 1;
  int bx = blockIdx.x, by = blockIdx.y;
  xcd_remap(bx, by);
  const int m0 = by * 128, n0 = bx * 128;

  size_t aoff[4], boff[4];
  int ldsoff[4];
#pragma unroll
  for (int i = 0; i < 4; ++i) {
    int cid = i * 256 + tid;
    int row = cid >> 3, ch = cid & 7;
    int sch = ch ^ (row & 7);
    aoff[i] = (size_t)(m0 + row) * K + sch * 8;
    boff[i] = (size_t)(n0 + row) * K + sch * 8;
    ldsoff[i] = (i * 256 + w * 64) * 8;
  }

  f32x4 acc[4][4];
#pragma unroll
  for (int mi = 0; mi < 4; ++mi)
#pragma unroll
    for (int ni = 0; ni < 4; ++ni) acc[mi][ni] = f32x4{0.f, 0.f, 0.f, 0.f};

  for (int k0 = 0; k0 < K; k0 += 64) {
#pragma unroll
    for (int i = 0; i < 4; ++i) {
      __builtin_amdgcn_global_load_lds((glb_u32_t*)(A + aoff[i] + k0),
                                       (lds_u32_t*)(sA + ldsoff[i]), 16, 0, 0);
      __builtin_amdgcn_global_load_lds((glb_u32_t*)(BT + boff[i] + k0),
                                       (lds_u32_t*)(sB + ldsoff[i]), 16, 0, 0);
    }
    asm volatile("s_waitcnt vmcnt(0)" ::: "memory");
    __syncthreads();

#pragma unroll
    for (int ks = 0; ks < 2; ++ks) {
      bf16x8 af[4], bfr[4];
#pragma unroll
      for (int mi = 0; mi < 4; ++mi) {
        int row = wm * 64 + mi * 16 + lr;
        af[mi] = *reinterpret_cast<const bf16x8*>(
            sA + row * 64 + (((ks * 4 + lg) ^ (row & 7)) << 3));
      }
#pragma unroll
      for (int ni = 0; ni < 4; ++ni) {
        int row = wn * 64 + ni * 16 + lr;
        bfr[ni] = *reinterpret_cast<const bf16x8*>(
            sB + row * 64 + (((ks * 4 + lg) ^ (row & 7)) << 3));
      }
#pragma unroll
      for (int mi = 0; mi < 4; ++mi)
#pragma unroll
        for (int ni = 0; ni < 4; ++ni)
          acc[mi][ni] = __builtin_amdgcn_mfma_f32_16x16x32_bf16(af[mi], bfr[ni], acc[mi][ni], 0, 0, 0);
    }
    __syncthreads();
  }

  if (ROPE) {
    const int t = 2 * bx + wn;
    if (t >= 2 && (t - 2) % 3 == 0) {   // this wave-half is head (t-2)/3's rope region
      float invf[2];
#pragma unroll
      for (int ni = 0; ni < 2; ++ni)
        invf[ni] = expf((float)(ni * 16 + lr) * (-9.210340371976184f / 32.0f));
#pragma unroll
      for (int mi = 0; mi < 4; ++mi) {
#pragma unroll
        for (int ni = 0; ni < 2; ++ni) {
#pragma unroll
          for (int r = 0; r < 4; ++r) {
            int s = (m0 + wm * 64 + mi * 16 + lg * 4 + r) & (S_ - 1);
            float sn, cs;
            sincosf((float)s * invf[ni], &sn, &cs);
            float x1 = acc[mi][ni][r], x2 = acc[mi][ni + 2][r];
            acc[mi][ni][r]     = x1 * cs - x2 * sn;
            acc[mi][ni + 2][r] = x2 * cs + x1 * sn;
          }
        }
      }
    }
  }

#pragma unroll
  for (int mi = 0; mi < 4; ++mi) {
#pragma unroll
    for (int ni = 0; ni < 4; ++ni) {
#pragma unroll
      for (int r = 0; r < 4; ++r) {
        int row = m0 + wm * 64 + mi * 16 + lg * 4 + r;
        int col = n0 + wn * 64 + ni * 16 + lr;
        float v = acc[mi][ni][r];
        if (OMODE == 0) ((float*)C)[(size_t)row * N + col]  = v;
        else            ((bf16_t*)C)[(size_t)row * N + col] = (bf16_t)(v * oscale);
      }
    }
  }
}

// ---------------- 64x128x64-tile GEMM (m97 structure), B^T input --------------
template<int OMODE>
__global__ __launch_bounds__(256) void gemm64x128_kernel(
    const bf16_t* __restrict__ A, const bf16_t* __restrict__ BT,
    void* __restrict__ C, int M, int N, int K, float oscale) {
  __shared__ __align__(16) bf16_t sA[64 * 64];    // 8KB
  __shared__ __align__(16) bf16_t sB[128 * 64];   // 16KB
  const int tid = threadIdx.x;
  const int w  = tid >> 6;
  const int l  = tid & 63;
  const int lg = l >> 4, lr = l & 15;
  const int wm = w >> 1, wn = w & 1;
  int bx = blockIdx.x, by = blockIdx.y;
  xcd_remap(bx, by);
  const int m0 = by * 64, n0 = bx * 128;

  size_t aoff[2], boff[4];
  int ldsa[2], ldsb[4];
#pragma unroll
  for (int i = 0; i < 2; ++i) {
    int cid = i * 256 + tid;
    int row = cid >> 3, ch = cid & 7;
    aoff[i] = (size_t)(m0 + row) * K + (ch ^ (row & 7)) * 8;
    ldsa[i] = (i * 256 + w * 64) * 8;
  }
#pragma unroll
  for (int i = 0; i < 4; ++i) {
    int cid = i * 256 + tid;
    int row = cid >> 3, ch = cid & 7;
    boff[i] = (size_t)(n0 + row) * K + (ch ^ (row & 7)) * 8;
    ldsb[i] = (i * 256 + w * 64) * 8;
  }

  f32x4 acc[2][4];
#pragma unroll
  for (int mi = 0; mi < 2; ++mi)
#pragma unroll
    for (int ni = 0; ni < 4; ++ni) acc[mi][ni] = f32x4{0.f, 0.f, 0.f, 0.f};

  for (int k0 = 0; k0 < K; k0 += 64) {
#pragma unroll
    for (int i = 0; i < 2; ++i)
      __builtin_amdgcn_global_load_lds((glb_u32_t*)(A + aoff[i] + k0),
                                       (lds_u32_t*)(sA + ldsa[i]), 16, 0, 0);
#pragma unroll
    for (int i = 0; i < 4; ++i)
      __builtin_amdgcn_global_load_lds((glb_u32_t*)(BT + boff[i] + k0),
                                       (lds_u32_t*)(sB + ldsb[i]), 16, 0, 0);
    asm volatile("s_waitcnt vmcnt(0)" ::: "memory");
    __syncthreads();

#pragma unroll
    for (int ks = 0; ks < 2; ++ks) {
      bf16x8 af[2], bfr[4];
#pragma unroll
      for (int mi = 0; mi < 2; ++mi) {
        int row = wm * 32 + mi * 16 + lr;
        af[mi] = *reinterpret_cast<const bf16x8*>(
            sA + row * 64 + (((ks * 4 + lg) ^ (row & 7)) << 3));
      }
#pragma unroll
      for (int ni = 0; ni < 4; ++ni) {
        int row = wn * 64 + ni * 16 + lr;
        bfr[ni] = *reinterpret_cast<const bf16x8*>(
            sB + row * 64 + (((ks * 4 + lg) ^ (row & 7)) << 3));
      }
#pragma unroll
      for (int mi = 0; mi < 2; ++mi)
#pragma unroll
        for (int ni = 0; ni < 4; ++ni)
          acc[mi][ni] = __builtin_amdgcn_mfma_f32_16x16x32_bf16(af[mi], bfr[ni], acc[mi][ni], 0, 0, 0);
    }
    __syncthreads();
  }

#pragma unroll
  for (int mi = 0; mi < 2; ++mi) {
#pragma unroll
    for (int ni = 0; ni < 4; ++ni) {
#pragma unroll
      for (int r = 0; r < 4; ++r) {
        int row = m0 + wm * 32 + mi * 16 + lg * 4 + r;
        int col = n0 + wn * 64 + ni * 16 + lr;
        float v = acc[mi][ni][r];
        if (OMODE == 0) ((float*)C)[(size_t)row * N + col]  = v;
        else            ((bf16_t*)C)[(size_t)row * N + col] = (bf16_t)(v * oscale);
      }
    }
  }
}

// ---------------- RMSNorm (in-place, one wave per row of 512) ----------------
__global__ __launch_bounds__(64) void rmsnorm_kernel(bf16_t* __restrict__ qa,
                                                     const float* __restrict__ wnorm) {
  int row = blockIdx.x;
  int l = threadIdx.x;
  bf16x8 v = *reinterpret_cast<const bf16x8*>(&qa[(size_t)row * QL_ + l * 8]);
  float f[8];
  float ss = 0.f;
#pragma unroll
  for (int e = 0; e < 8; ++e) { f[e] = (float)v[e]; ss += f[e] * f[e]; }
#pragma unroll
  for (int off = 32; off >= 1; off >>= 1) ss += __shfl_xor(ss, off);
  float rstd = rsqrtf(ss * (1.0f / 512.0f) + 1e-6f);
  bf16x8 o;
#pragma unroll
  for (int e = 0; e < 8; ++e) o[e] = (bf16_t)(f[e] * rstd * wnorm[l * 8 + e]);
  *reinterpret_cast<bf16x8*>(&qa[(size_t)row * QL_ + l * 8]) = o;
}

// ---------------- causal flash attention with sink, split-K ----------------
// r12 core: 4 waves x 32 rows; K dbuf (24KB) + V single (12KB) + sP (10KB)
// = 46KB -> 3 blocks/CU. One barrier/iter, counted vmcnt. Ones-column
// denominator; defer-max THR=8; q pre-scaled; wave-uniform diag branch.
// Split-K: qt>=8 tiles split into two chunks (<=32 iters) -> partials + merge.
#define KB32  32
#define SPLD  40

__global__ __launch_bounds__(256, 2) void attn_kernel(
    const bf16_t* __restrict__ q, const bf16_t* __restrict__ k,
    const bf16_t* __restrict__ vt, const float* __restrict__ sink,
    bf16_t* __restrict__ attn, bf16_t* __restrict__ Opart,
    float* __restrict__ mpart, float* __restrict__ dpart) {
  __shared__ __align__(16) bf16_t sK[2][KB32 * DH_];   // 24KB dbuf
  __shared__ __align__(16) bf16_t sV[DH_ * KB32];      // 12KB single
  __shared__ __align__(16) bf16_t sP[4][32][SPLD];     // 10KB
  const int tid = threadIdx.x;
  const int w  = tid >> 6;
  const int l  = tid & 63;
  const int lg = l >> 4, lr = l & 15;

  // block decode: ids [0,512): split chunks (qt 15..8, heavy first);
  // ids [512,768): unsplit tiles qt 7..0.
  const int id = blockIdx.x;
  int qt, bh, lo, hib;
  bool split, sink0;
  if (id < 512) {
    split = true;
    qt = 15 - (id >> 6);
    int r2 = id & 63;
    bh = r2 >> 1;
    int chunk = r2 & 1;
    int Kiters = 4 * qt + 4, Hh = Kiters >> 1;
    lo  = chunk ? Hh : 0;
    hib = chunk ? (Kiters - 1) : (Hh - 1);
    sink0 = (chunk == 0);
  } else {
    split = false;
    int j = id - 512;
    qt = 7 - (j >> 5);
    bh = j & 31;
    lo = 0; hib = 4 * qt + 3;
    sink0 = true;
  }
  const int b = bh >> 4, h = bh & 15;
  const int wrow0 = qt * 128 + w * 32;
  const int ktmax_w = 4 * qt + w;

  const bf16_t* kb  = k  + (size_t)(b * S_) * DH_;
  const bf16_t* vtb = vt + (size_t)(b * S_);

  int koff[3], voff[3], ldst[3];
#pragma unroll
  for (int i = 0; i < 3; ++i) {
    int g = i * 256 + tid;
    int krow = g / 24, kch = g - krow * 24;
    koff[i] = krow * DH_ + ((kch ^ (krow & 7)) << 3);
    int vrow = g >> 2, vch = g & 3;
    voff[i] = vrow * NROWS + ((vch ^ (vrow & 3)) << 3);
    ldst[i] = (i * 256 + w * 64) * 8;
  }

  auto stageK = [&](int kt, int bu) {
    const bf16_t* ksrc = kb + (size_t)kt * KB32 * DH_;
#pragma unroll
    for (int i = 0; i < 3; ++i)
      __builtin_amdgcn_global_load_lds((glb_u32_t*)(ksrc + koff[i]),
                                       (lds_u32_t*)(&sK[bu][0] + ldst[i]), 16, 0, 0);
  };
  auto stageV = [&](int kt) {
    const bf16_t* vsrc = vtb + kt * KB32;
#pragma unroll
    for (int i = 0; i < 3; ++i)
      __builtin_amdgcn_global_load_lds((glb_u32_t*)(vsrc + voff[i]),
                                       (lds_u32_t*)(sV + ldst[i]), 16, 0, 0);
  };

  bf16x8 qf[2][6];
#pragma unroll
  for (int rf = 0; rf < 2; ++rf) {
    size_t rowoff = (size_t)(b * S_ + wrow0 + rf * 16 + lr) * QKD + h * DH_;
#pragma unroll
    for (int ks = 0; ks < 6; ++ks)
      qf[rf][ks] = *reinterpret_cast<const bf16x8*>(&q[rowoff + ks * 32 + lg * 8]);
  }

  bf16x8 vones;
#pragma unroll
  for (int e = 0; e < 8; ++e) vones[e] = (bf16_t)((lr == 0) ? 1.0f : 0.0f);

  f32x4 acc[2][13];
#pragma unroll
  for (int rf = 0; rf < 2; ++rf) {
#pragma unroll
    for (int c = 0; c < 12; ++c) acc[rf][c] = f32x4{0.f, 0.f, 0.f, 0.f};
    float init = (sink0 && lr == 0) ? 1.0f : 0.0f;   // sink only in chunk 0
    acc[rf][12] = f32x4{init, init, init, init};
  }

  const float L2E = 1.4426950408889634f;
  float m[2][4];
  float m0v = sink0 ? (sink[h] * L2E) : -1e30f;
#pragma unroll
  for (int rf = 0; rf < 2; ++rf)
#pragma unroll
    for (int r = 0; r < 4; ++r) m[rf][r] = m0v;

  stageK(lo, 0);
  int cur = 0;

  for (int kt = lo; kt <= hib; ++kt) {
    __syncthreads();                 // all waves done PV(kt-1): sV free; sK[cur^1] free

    stageV(kt);                      // must land before PV(kt)
    const bool more = (kt < hib);
    if (more) stageK(kt + 1, cur ^ 1);

    if (kt <= ktmax_w) {
      // ---- wait K(kt) only ----
      if (more) { asm volatile("s_waitcnt vmcnt(6)" ::: "memory"); }
      else      { asm volatile("s_waitcnt vmcnt(3)" ::: "memory"); }

      // ---- QK^T (q pre-scaled; scores in log2 domain) ----
      f32x4 sc[2][2];
#pragma unroll
      for (int rf = 0; rf < 2; ++rf)
#pragma unroll
        for (int c = 0; c < 2; ++c) sc[rf][c] = f32x4{0.f, 0.f, 0.f, 0.f};
#pragma unroll
      for (int c = 0; c < 2; ++c) {
        const int row = c * 16 + lr;
        const int rx  = row & 7;
        const bf16_t* kr = &sK[cur][0] + row * DH_;
#pragma unroll
        for (int ks = 0; ks < 6; ++ks) {
          bf16x8 kf = *reinterpret_cast<const bf16x8*>(kr + (((ks * 4 + lg) ^ rx) << 3));
          sc[0][c] = __builtin_amdgcn_mfma_f32_16x16x32_bf16(qf[0][ks], kf, sc[0][c], 0, 0, 0);
          sc[1][c] = __builtin_amdgcn_mfma_f32_16x16x32_bf16(qf[1][ks], kf, sc[1][c], 0, 0, 0);
        }
      }

      // ---- causal mask only on the wave-diagonal iteration ----
      if (kt == ktmax_w) {
#pragma unroll
        for (int rf = 0; rf < 2; ++rf)
#pragma unroll
          for (int c = 0; c < 2; ++c)
#pragma unroll
            for (int r = 0; r < 4; ++r)
              if ((kt * 32 + c * 16 + lr) > (wrow0 + rf * 16 + lg * 4 + r))
                sc[rf][c][r] = -1e30f;
      }

      // ---- defer-max check ----
      int ok = 1;
      float lmax[2][4];
#pragma unroll
      for (int rf = 0; rf < 2; ++rf)
#pragma unroll
        for (int r = 0; r < 4; ++r) {
          lmax[rf][r] = fmaxf(sc[rf][0][r], sc[rf][1][r]);
          ok &= (lmax[rf][r] <= m[rf][r] + 8.0f);
        }
      if (!__all(ok)) {
#pragma unroll
        for (int rf = 0; rf < 2; ++rf) {
          float rmax[4], alpha[4];
#pragma unroll
          for (int r = 0; r < 4; ++r) rmax[r] = lmax[rf][r];
#pragma unroll
          for (int off = 1; off < 16; off <<= 1) {
#pragma unroll
            for (int r = 0; r < 4; ++r) rmax[r] = fmaxf(rmax[r], __shfl_xor(rmax[r], off));
          }
#pragma unroll
          for (int r = 0; r < 4; ++r) {
            float mn = fmaxf(m[rf][r], rmax[r]);
            alpha[r] = EXP2(m[rf][r] - mn);
            m[rf][r] = mn;
          }
#pragma unroll
          for (int c = 0; c < 13; ++c)
#pragma unroll
            for (int r = 0; r < 4; ++r) acc[rf][c][r] *= alpha[r];
        }
      }

      // ---- P = exp2(sc - m) -> per-wave LDS ----
#pragma unroll
      for (int rf = 0; rf < 2; ++rf)
#pragma unroll
        for (int c = 0; c < 2; ++c)
#pragma unroll
          for (int r = 0; r < 4; ++r)
            sP[w][rf * 16 + lg * 4 + r][c * 16 + lr] = (bf16_t)EXP2(sc[rf][c][r] - m[rf][r]);

      // ---- wait V(kt) only (K(kt+1) keeps riding) ----
      if (more) { asm volatile("s_waitcnt vmcnt(3)" ::: "memory"); }
      else      { asm volatile("s_waitcnt vmcnt(0)" ::: "memory"); }

      // ---- PV + denominator ----
      bf16x8 pf[2];
      pf[0] = *reinterpret_cast<const bf16x8*>(&sP[w][lr][lg * 8]);
      pf[1] = *reinterpret_cast<const bf16x8*>(&sP[w][16 + lr][lg * 8]);
#pragma unroll
      for (int c2 = 0; c2 < 12; ++c2) {
        const int row = c2 * 16 + lr;
        bf16x8 vf = *reinterpret_cast<const bf16x8*>(
            sV + row * KB32 + ((lg ^ (row & 3)) << 3));
        acc[0][c2] = __builtin_amdgcn_mfma_f32_16x16x32_bf16(pf[0], vf, acc[0][c2], 0, 0, 0);
        acc[1][c2] = __builtin_amdgcn_mfma_f32_16x16x32_bf16(pf[1], vf, acc[1][c2], 0, 0, 0);
      }
      acc[0][12] = __builtin_amdgcn_mfma_f32_16x16x32_bf16(pf[0], vones, acc[0][12], 0, 0, 0);
      acc[1][12] = __builtin_amdgcn_mfma_f32_16x16x32_bf16(pf[1], vones, acc[1][12], 0, 0, 0);
    }
    cur ^= 1;
  }

  if (!split) {
#pragma unroll
    for (int rf = 0; rf < 2; ++rf) {
      float rl[4];
#pragma unroll
      for (int r = 0; r < 4; ++r) rl[r] = 1.0f / __shfl(acc[rf][12][r], l & 48);
#pragma unroll
      for (int c2 = 0; c2 < 12; ++c2) {
#pragma unroll
        for (int r = 0; r < 4; ++r) {
          int i = wrow0 + rf * 16 + lg * 4 + r;
          size_t off = (size_t)(b * S_ + i) * QKD + h * DH_ + c2 * 16 + lr;
          attn[off] = (bf16_t)(acc[rf][c2][r] * rl[r]);
        }
      }
    }
  } else {
    const int slot = id;
#pragma unroll
    for (int rf = 0; rf < 2; ++rf) {
#pragma unroll
      for (int c2 = 0; c2 < 12; ++c2) {
#pragma unroll
        for (int r = 0; r < 4; ++r) {
          int rowl = w * 32 + rf * 16 + lg * 4 + r;
          Opart[(size_t)slot * (128 * 192) + rowl * 192 + c2 * 16 + lr] = (bf16_t)acc[rf][c2][r];
        }
      }
      if (lr == 0) {
#pragma unroll
        for (int r = 0; r < 4; ++r) {
          int rowl = w * 32 + rf * 16 + lg * 4 + r;
          mpart[slot * 128 + rowl] = m[rf][r];
          dpart[slot * 128 + rowl] = acc[rf][12][r];
        }
      }
    }
  }
}

// ---------------- merge the two K-chunks of split tiles ----------------
__global__ __launch_bounds__(256) void attn_merge(
    const bf16_t* __restrict__ Opart, const float* __restrict__ mpart,
    const float* __restrict__ dpart, bf16_t* __restrict__ attn) {
  const int t  = blockIdx.x;          // 0..255: (qt 8..15) x bh
  const int qt = 8 + (t >> 5), bh = t & 31;
  const int b = bh >> 4, h = bh & 15;
  const int base = (15 - qt) * 64 + bh * 2;   // chunk0 slot
  const size_t offA = (size_t)base * (128 * 192);
  const size_t offB = offA + 128 * 192;
  const int rbA = base * 128, rbB = rbA + 128;
  for (int c = threadIdx.x; c < 3072; c += 256) {
    int row = c / 24, col8 = (c - row * 24) * 8;
    float mA = mpart[rbA + row], mB = mpart[rbB + row];
    float dA = dpart[rbA + row], dB = dpart[rbB + row];
    float M = fmaxf(mA, mB);
    float wA = EXP2(mA - M), wB = EXP2(mB - M);
    float rden = 1.0f / (wA * dA + wB * dB);
    bf16x8 va = *reinterpret_cast<const bf16x8*>(&Opart[offA + row * 192 + col8]);
    bf16x8 vb = *reinterpret_cast<const bf16x8*>(&Opart[offB + row * 192 + col8]);
    bf16x8 o;
#pragma unroll
    for (int e = 0; e < 8; ++e)
      o[e] = (bf16_t)((wA * (float)va[e] + wB * (float)vb[e]) * rden);
    size_t off = (size_t)(b * S_ + qt * 128 + row) * QKD + h * DH_ + col8;
    *reinterpret_cast<bf16x8*>(&attn[off]) = o;
  }
}

// ---------------- launch ----------------
extern "C" void kernel_launch(void* const* d_in, const int* in_sizes, int n_in,
                              void* d_out, int out_size, void* d_ws, size_t ws_size,
                              hipStream_t stream) {
  const float* x        = (const float*)d_in[0];
  const float* w_qa     = (const float*)d_in[1];
  const float* q_norm_w = (const float*)d_in[2];
  const float* w_qb     = (const float*)d_in[3];
  const float* w_k      = (const float*)d_in[4];
  const float* w_v      = (const float*)d_in[5];
  const float* w_o      = (const float*)d_in[6];
  const float* attn_sink= (const float*)d_in[7];
  float* out = (float*)d_out;

  char* ws = (char*)d_ws;
  size_t off = 0;
  auto alloc = [&](size_t bytes) -> void* {
    void* p = ws + off;
    off += (bytes + 255) & ~(size_t)255;
    return p;
  };
  bf16_t* q_b  = (bf16_t*)alloc((size_t)NROWS * QKD * 2);
  bf16_t* k_b  = (bf16_t*)alloc((size_t)NROWS * DH_ * 2);
  bf16_t* vt_b = (bf16_t*)alloc((size_t)DH_ * NROWS * 2);
  bf16_t* wo_t = (bf16_t*)alloc((size_t)HID_ * QKD * 2);   // w_o^T [2048][3072]
  size_t temp_start = off;
  bf16_t* xb    = (bf16_t*)alloc((size_t)NROWS * HID_ * 2);
  bf16_t* wqa_t = (bf16_t*)alloc((size_t)QL_ * HID_ * 2);  // [512][2048]
  bf16_t* wqb_t = (bf16_t*)alloc((size_t)QKD * QL_ * 2);   // [3072][512]
  bf16_t* wkv_t = (bf16_t*)alloc((size_t)(2 * DH_) * HID_ * 2); // [384][2048]
  bf16_t* qa_b  = (bf16_t*)alloc((size_t)NROWS * QL_ * 2);
  bf16_t* attn_b = (bf16_t*)(ws + temp_start);             // overlays dead temps
  // split-K partials (after temp high-water mark; attn_b extent < temp extent)
  bf16_t* opart = (bf16_t*)alloc((size_t)512 * 128 * 192 * 2);  // 25.2 MB
  float*  mpart = (float*)alloc((size_t)512 * 128 * 4);
  float*  dpart = (float*)alloc((size_t)512 * 128 * 4);

  const float SCALE2 = 0.10411754646447386f;  // 192^-0.5 * log2(e)

  int n4x = (int)((size_t)NROWS * HID_ / 4);
  cast_f32_to_bf16<<<dim3((n4x + 255) / 256), dim3(256), 0, stream>>>(x, xb, n4x);
  transpose_all<<<dim3(9472), dim3(256), 0, stream>>>(
      w_qa, w_qb, w_k, w_v, w_o,
      wqa_t, wqb_t, wkv_t, wkv_t + (size_t)DH_ * HID_, wo_t);

  // q_a = rmsnorm(x @ w_qa)   [64x128 tile: 256 blocks]
  gemm64x128_kernel<1><<<dim3(QL_ / 128, NROWS / 64), 256, 0, stream>>>(xb, wqa_t, qa_b, NROWS, QL_, HID_, 1.0f);
  rmsnorm_kernel<<<dim3(NROWS), dim3(64), 0, stream>>>(qa_b, q_norm_w);
  // q = rope((q_a @ w_qb)) * SCALE2  [128 tile, fused Q-RoPE: 768 blocks]
  gemm128_kernel<1, true><<<dim3(QKD / 128, NROWS / 128), 256, 0, stream>>>(qa_b, wqb_t, q_b, NROWS, QKD, QL_, SCALE2);
  // k (with fused K-RoPE) + v^T in one launch
  gemm_kv_kernel<<<dim3((2 * DH_) / BN, NROWS / BM), 256, 0, stream>>>(xb, wkv_t, k_b, vt_b);
  // attention: 512 split-chunk blocks + 256 unsplit blocks (3/CU resident)
  attn_kernel<<<dim3(768), dim3(256), 0, stream>>>(q_b, k_b, vt_b, attn_sink,
                                                   attn_b, opart, mpart, dpart);
  attn_merge<<<dim3(256), dim3(256), 0, stream>>>(opart, mpart, dpart, attn_b);
  // out = attn @ w_o          [64x128 tile: 1024 blocks, 4/CU]
  gemm64x128_kernel<0><<<dim3(HID_ / 128, NROWS / 64), 256, 0, stream>>>(attn_b, wo_t, out, NROWS, HID_, QKD, 1.0f);
}

// Round 14
// 304.505 us; speedup vs baseline: 1.0351x; 1.0351x over previous
//
#include <hip/hip_runtime.h>
#include <hip/hip_bf16.h>

typedef __bf16 bf16_t;
typedef __bf16 bf16x8 __attribute__((ext_vector_type(8)));
typedef __bf16 bf16x4 __attribute__((ext_vector_type(4)));
typedef float  f32x4  __attribute__((ext_vector_type(4)));
typedef __attribute__((address_space(3))) unsigned int lds_u32_t;
typedef __attribute__((address_space(1))) const unsigned int glb_u32_t;

#define B_    2
#define S_    2048
#define HID_  2048
#define H_    16
#define DH_   192
#define DR_   64
#define DN_   128
#define QL_   512
#define NROWS (B_*S_)          // 4096
#define QKD   (H_*DH_)         // 3072

#if __has_builtin(__builtin_amdgcn_exp2f)
#define EXP2(x) __builtin_amdgcn_exp2f(x)
#else
#define EXP2(x) exp2f(x)
#endif

// XCD-aware bijective block swizzle (requires nwg % 8 == 0).
__device__ inline void xcd_remap(int& bx, int& by) {
  const int gx = gridDim.x;
  const int nwg = gx * gridDim.y;
  const int flat = by * gx + bx;
  const int q = nwg >> 3;
  const int nf = (flat & 7) * q + (flat >> 3);
  bx = nf % gx;
  by = nf / gx;
}

// ---------------- weight transposes + x cast, one launch ----------------
// ids [0,9472): f32 [R][C] -> bf16 [C][R] 32x32 tiles (5 weights).
// ids [9472,11520): cast x f32 -> bf16 (1024 float4 per block).
__global__ __launch_bounds__(256) void prep_all(
    const float* __restrict__ i0, const float* __restrict__ i1,
    const float* __restrict__ i2, const float* __restrict__ i3,
    const float* __restrict__ i4, const float* __restrict__ xin,
    bf16_t* __restrict__ o0, bf16_t* __restrict__ o1, bf16_t* __restrict__ o2,
    bf16_t* __restrict__ o3, bf16_t* __restrict__ o4, bf16_t* __restrict__ xout) {
  int id = blockIdx.x;
  if (id >= 9472) {
    const int lid = id - 9472;
    const float4* src = reinterpret_cast<const float4*>(xin);
    bf16x4* dst = reinterpret_cast<bf16x4*>(xout);
    const int base = lid * 1024;
#pragma unroll
    for (int j = 0; j < 4; ++j) {
      int idx = base + j * 256 + threadIdx.x;
      float4 v = src[idx];
      bf16x4 r;
      r[0] = (bf16_t)v.x; r[1] = (bf16_t)v.y; r[2] = (bf16_t)v.z; r[3] = (bf16_t)v.w;
      dst[idx] = r;
    }
    return;
  }
  const float* in; bf16_t* out; int R, C, lid;
  if (id < 1024)      { in = i0; out = o0; R = 2048; C = 512;  lid = id; }
  else if (id < 2560) { in = i1; out = o1; R = 512;  C = 3072; lid = id - 1024; }
  else if (id < 2944) { in = i2; out = o2; R = 2048; C = 192;  lid = id - 2560; }
  else if (id < 3328) { in = i3; out = o3; R = 2048; C = 192;  lid = id - 2944; }
  else                { in = i4; out = o4; R = 3072; C = 2048; lid = id - 3328; }
  const int cw = C >> 5;
  const int c0 = (lid % cw) * 32, r0 = (lid / cw) * 32;
  __shared__ float t[32][33];
  const int tx = threadIdx.x & 31;
  const int ty = threadIdx.x >> 5;
#pragma unroll
  for (int j = 0; j < 4; ++j)
    t[ty + j * 8][tx] = in[(size_t)(r0 + ty + j * 8) * C + c0 + tx];
  __syncthreads();
#pragma unroll
  for (int j = 0; j < 4; ++j)
    out[(size_t)(c0 + ty + j * 8) * R + r0 + tx] = (bf16_t)t[tx][ty + j * 8];
}

// ---------------- merged K/V GEMM (64x64 tile), B^T input, K-RoPE fused ------
#define BM 64
#define BN 64
#define BK 64
#define LDT 72

__global__ __launch_bounds__(256) void gemm_kv_kernel(
    const bf16_t* __restrict__ A, const bf16_t* __restrict__ BT,
    bf16_t* __restrict__ Kout, bf16_t* __restrict__ VTout) {
  __shared__ __align__(16) bf16_t sA[BM][LDT];
  __shared__ __align__(16) bf16_t sB[BN][LDT];
  const int tid = threadIdx.x;
  const int w  = tid >> 6;
  const int l  = tid & 63;
  const int lg = l >> 4, lr = l & 15;
  int bx = blockIdx.x, by = blockIdx.y;
  xcd_remap(bx, by);
  const int m0 = by * BM, n0 = bx * BN;
  const int K = HID_;

  f32x4 acc[4];
#pragma unroll
  for (int c = 0; c < 4; ++c) acc[c] = f32x4{0.f, 0.f, 0.f, 0.f};

  for (int k0 = 0; k0 < K; k0 += BK) {
#pragma unroll
    for (int i = 0; i < 2; ++i) {
      int cid = tid + i * 256;
      int row = cid >> 3;
      int cb  = (cid & 7) * 8;
      *reinterpret_cast<uint4*>(&sA[row][cb]) =
          *reinterpret_cast<const uint4*>(&A[(size_t)(m0 + row) * K + k0 + cb]);
      *reinterpret_cast<uint4*>(&sB[row][cb]) =
          *reinterpret_cast<const uint4*>(&BT[(size_t)(n0 + row) * K + k0 + cb]);
    }
    __syncthreads();
#pragma unroll
    for (int ks = 0; ks < 2; ++ks) {
      bf16x8 af = *reinterpret_cast<const bf16x8*>(&sA[w * 16 + lr][ks * 32 + lg * 8]);
#pragma unroll
      for (int c = 0; c < 4; ++c) {
        bf16x8 bfr = *reinterpret_cast<const bf16x8*>(&sB[c * 16 + lr][ks * 32 + lg * 8]);
        acc[c] = __builtin_amdgcn_mfma_f32_16x16x32_bf16(af, bfr, acc[c], 0, 0, 0);
      }
    }
    __syncthreads();
  }

  // ---- fused K-RoPE: the n0==128 tile holds cols 128..191 = rope region ----
  if (n0 == 128) {
#pragma unroll
    for (int c = 0; c < 2; ++c) {
      const float invf = expf((float)(c * 16 + lr) * (-9.210340371976184f / 32.0f));
#pragma unroll
      for (int r = 0; r < 4; ++r) {
        int s = (m0 + w * 16 + lg * 4 + r) & (S_ - 1);
        float sn, cs;
        sincosf((float)s * invf, &sn, &cs);
        float x1 = acc[c][r], x2 = acc[c + 2][r];
        acc[c][r]     = x1 * cs - x2 * sn;
        acc[c + 2][r] = x2 * cs + x1 * sn;
      }
    }
  }

#pragma unroll
  for (int c = 0; c < 4; ++c) {
#pragma unroll
    for (int r = 0; r < 4; ++r) {
      int row = m0 + w * 16 + lg * 4 + r;
      int col = n0 + c * 16 + lr;
      float v = acc[c][r];
      if (col < DH_) Kout[(size_t)row * DH_ + col] = (bf16_t)v;
      else           VTout[(size_t)(col - DH_) * NROWS + row] = (bf16_t)v;
    }
  }
}

// ---------------- big bf16 MFMA GEMM (128x128x64 tile, m97 structure) --------
// OMODE 0: f32 C; OMODE 1: bf16 C scaled by oscale. ROPE: fused Q-RoPE.
template<int OMODE, bool ROPE>
__global__ __launch_bounds__(256) void gemm128_kernel(
    const bf16_t* __restrict__ A, const bf16_t* __restrict__ BT,
    void* __restrict__ C, int M, int N, int K, float oscale) {
  __shared__ __align__(16) bf16_t sA[128 * 64];
  __shared__ __align__(16) bf16_t sB[128 * 64];
  const int tid = threadIdx.x;
  const int w  = tid >> 6;
  const int l  = tid & 63;
  const int lg = l >> 4, lr = l & 15;
  const int wm = w >> 1, wn = w & 1;
  int bx = blockIdx.x, by = blockIdx.y;
  xcd_remap(bx, by);
  const int m0 = by * 128, n0 = bx * 128;

  size_t aoff[4], boff[4];
  int ldsoff[4];
#pragma unroll
  for (int i = 0; i < 4; ++i) {
    int cid = i * 256 + tid;
    int row = cid >> 3, ch = cid & 7;
    int sch = ch ^ (row & 7);
    aoff[i] = (size_t)(m0 + row) * K + sch * 8;
    boff[i] = (size_t)(n0 + row) * K + sch * 8;
    ldsoff[i] = (i * 256 + w * 64) * 8;
  }

  f32x4 acc[4][4];
#pragma unroll
  for (int mi = 0; mi < 4; ++mi)
#pragma unroll
    for (int ni = 0; ni < 4; ++ni) acc[mi][ni] = f32x4{0.f, 0.f, 0.f, 0.f};

  for (int k0 = 0; k0 < K; k0 += 64) {
#pragma unroll
    for (int i = 0; i < 4; ++i) {
      __builtin_amdgcn_global_load_lds((glb_u32_t*)(A + aoff[i] + k0),
                                       (lds_u32_t*)(sA + ldsoff[i]), 16, 0, 0);
      __builtin_amdgcn_global_load_lds((glb_u32_t*)(BT + boff[i] + k0),
                                       (lds_u32_t*)(sB + ldsoff[i]), 16, 0, 0);
    }
    asm volatile("s_waitcnt vmcnt(0)" ::: "memory");
    __syncthreads();

#pragma unroll
    for (int ks = 0; ks < 2; ++ks) {
      bf16x8 af[4], bfr[4];
#pragma unroll
      for (int mi = 0; mi < 4; ++mi) {
        int row = wm * 64 + mi * 16 + lr;
        af[mi] = *reinterpret_cast<const bf16x8*>(
            sA + row * 64 + (((ks * 4 + lg) ^ (row & 7)) << 3));
      }
#pragma unroll
      for (int ni = 0; ni < 4; ++ni) {
        int row = wn * 64 + ni * 16 + lr;
        bfr[ni] = *reinterpret_cast<const bf16x8*>(
            sB + row * 64 + (((ks * 4 + lg) ^ (row & 7)) << 3));
      }
#pragma unroll
      for (int mi = 0; mi < 4; ++mi)
#pragma unroll
        for (int ni = 0; ni < 4; ++ni)
          acc[mi][ni] = __builtin_amdgcn_mfma_f32_16x16x32_bf16(af[mi], bfr[ni], acc[mi][ni], 0, 0, 0);
    }
    __syncthreads();
  }

  if (ROPE) {
    const int t = 2 * bx + wn;
    if (t >= 2 && (t - 2) % 3 == 0) {   // wave-half = head (t-2)/3's rope region
      float invf[2];
#pragma unroll
      for (int ni = 0; ni < 2; ++ni)
        invf[ni] = expf((float)(ni * 16 + lr) * (-9.210340371976184f / 32.0f));
#pragma unroll
      for (int mi = 0; mi < 4; ++mi) {
#pragma unroll
        for (int ni = 0; ni < 2; ++ni) {
#pragma unroll
          for (int r = 0; r < 4; ++r) {
            int s = (m0 + wm * 64 + mi * 16 + lg * 4 + r) & (S_ - 1);
            float sn, cs;
            sincosf((float)s * invf[ni], &sn, &cs);
            float x1 = acc[mi][ni][r], x2 = acc[mi][ni + 2][r];
            acc[mi][ni][r]     = x1 * cs - x2 * sn;
            acc[mi][ni + 2][r] = x2 * cs + x1 * sn;
          }
        }
      }
    }
  }

#pragma unroll
  for (int mi = 0; mi < 4; ++mi) {
#pragma unroll
    for (int ni = 0; ni < 4; ++ni) {
#pragma unroll
      for (int r = 0; r < 4; ++r) {
        int row = m0 + wm * 64 + mi * 16 + lg * 4 + r;
        int col = n0 + wn * 64 + ni * 16 + lr;
        float v = acc[mi][ni][r];
        if (OMODE == 0) ((float*)C)[(size_t)row * N + col]  = v;
        else            ((bf16_t*)C)[(size_t)row * N + col] = (bf16_t)(v * oscale);
      }
    }
  }
}

// ---------------- 64x128x64-tile GEMM (m97 structure), B^T input --------------
template<int OMODE>
__global__ __launch_bounds__(256) void gemm64x128_kernel(
    const bf16_t* __restrict__ A, const bf16_t* __restrict__ BT,
    void* __restrict__ C, int M, int N, int K, float oscale) {
  __shared__ __align__(16) bf16_t sA[64 * 64];    // 8KB
  __shared__ __align__(16) bf16_t sB[128 * 64];   // 16KB
  const int tid = threadIdx.x;
  const int w  = tid >> 6;
  const int l  = tid & 63;
  const int lg = l >> 4, lr = l & 15;
  const int wm = w >> 1, wn = w & 1;
  int bx = blockIdx.x, by = blockIdx.y;
  xcd_remap(bx, by);
  const int m0 = by * 64, n0 = bx * 128;

  size_t aoff[2], boff[4];
  int ldsa[2], ldsb[4];
#pragma unroll
  for (int i = 0; i < 2; ++i) {
    int cid = i * 256 + tid;
    int row = cid >> 3, ch = cid & 7;
    aoff[i] = (size_t)(m0 + row) * K + (ch ^ (row & 7)) * 8;
    ldsa[i] = (i * 256 + w * 64) * 8;
  }
#pragma unroll
  for (int i = 0; i < 4; ++i) {
    int cid = i * 256 + tid;
    int row = cid >> 3, ch = cid & 7;
    boff[i] = (size_t)(n0 + row) * K + (ch ^ (row & 7)) * 8;
    ldsb[i] = (i * 256 + w * 64) * 8;
  }

  f32x4 acc[2][4];
#pragma unroll
  for (int mi = 0; mi < 2; ++mi)
#pragma unroll
    for (int ni = 0; ni < 4; ++ni) acc[mi][ni] = f32x4{0.f, 0.f, 0.f, 0.f};

  for (int k0 = 0; k0 < K; k0 += 64) {
#pragma unroll
    for (int i = 0; i < 2; ++i)
      __builtin_amdgcn_global_load_lds((glb_u32_t*)(A + aoff[i] + k0),
                                       (lds_u32_t*)(sA + ldsa[i]), 16, 0, 0);
#pragma unroll
    for (int i = 0; i < 4; ++i)
      __builtin_amdgcn_global_load_lds((glb_u32_t*)(BT + boff[i] + k0),
                                       (lds_u32_t*)(sB + ldsb[i]), 16, 0, 0);
    asm volatile("s_waitcnt vmcnt(0)" ::: "memory");
    __syncthreads();

#pragma unroll
    for (int ks = 0; ks < 2; ++ks) {
      bf16x8 af[2], bfr[4];
#pragma unroll
      for (int mi = 0; mi < 2; ++mi) {
        int row = wm * 32 + mi * 16 + lr;
        af[mi] = *reinterpret_cast<const bf16x8*>(
            sA + row * 64 + (((ks * 4 + lg) ^ (row & 7)) << 3));
      }
#pragma unroll
      for (int ni = 0; ni < 4; ++ni) {
        int row = wn * 64 + ni * 16 + lr;
        bfr[ni] = *reinterpret_cast<const bf16x8*>(
            sB + row * 64 + (((ks * 4 + lg) ^ (row & 7)) << 3));
      }
#pragma unroll
      for (int mi = 0; mi < 2; ++mi)
#pragma unroll
        for (int ni = 0; ni < 4; ++ni)
          acc[mi][ni] = __builtin_amdgcn_mfma_f32_16x16x32_bf16(af[mi], bfr[ni], acc[mi][ni], 0, 0, 0);
    }
    __syncthreads();
  }

#pragma unroll
  for (int mi = 0; mi < 2; ++mi) {
#pragma unroll
    for (int ni = 0; ni < 4; ++ni) {
#pragma unroll
      for (int r = 0; r < 4; ++r) {
        int row = m0 + wm * 32 + mi * 16 + lg * 4 + r;
        int col = n0 + wn * 64 + ni * 16 + lr;
        float v = acc[mi][ni][r];
        if (OMODE == 0) ((float*)C)[(size_t)row * N + col]  = v;
        else            ((bf16_t*)C)[(size_t)row * N + col] = (bf16_t)(v * oscale);
      }
    }
  }
}

// ---------------- RMSNorm (in-place, one wave per row of 512) ----------------
__global__ __launch_bounds__(64) void rmsnorm_kernel(bf16_t* __restrict__ qa,
                                                     const float* __restrict__ wnorm) {
  int row = blockIdx.x;
  int l = threadIdx.x;
  bf16x8 v = *reinterpret_cast<const bf16x8*>(&qa[(size_t)row * QL_ + l * 8]);
  float f[8];
  float ss = 0.f;
#pragma unroll
  for (int e = 0; e < 8; ++e) { f[e] = (float)v[e]; ss += f[e] * f[e]; }
#pragma unroll
  for (int off = 32; off >= 1; off >>= 1) ss += __shfl_xor(ss, off);
  float rstd = rsqrtf(ss * (1.0f / 512.0f) + 1e-6f);
  bf16x8 o;
#pragma unroll
  for (int e = 0; e < 8; ++e) o[e] = (bf16_t)(f[e] * rstd * wnorm[l * 8 + e]);
  *reinterpret_cast<bf16x8*>(&qa[(size_t)row * QL_ + l * 8]) = o;
}

// ---------------- causal flash attention with sink (r12 core) ----------------
// 4 waves x 32 rows. K dbuf (24KB) + V single (12KB) + sP (10KB) = 46KB.
// One barrier/iter, counted vmcnt. Ones-column denominator; defer-max THR=8;
// q pre-scaled by 192^-0.5*log2e; wave-uniform diag branch.
#define KB32  32
#define SPLD  40

__global__ __launch_bounds__(256, 2) void attn_kernel(
    const bf16_t* __restrict__ q, const bf16_t* __restrict__ k,
    const bf16_t* __restrict__ vt, const float* __restrict__ sink,
    bf16_t* __restrict__ attn) {
  __shared__ __align__(16) bf16_t sK[2][KB32 * DH_];   // 24KB dbuf
  __shared__ __align__(16) bf16_t sV[DH_ * KB32];      // 12KB single
  __shared__ __align__(16) bf16_t sP[4][32][SPLD];     // 10KB
  const int tid = threadIdx.x;
  const int w  = tid >> 6;
  const int l  = tid & 63;
  const int lg = l >> 4, lr = l & 15;
  const int qx = blockIdx.x >> 5;
  const int qt = (qx < 8) ? (15 - qx) : (qx - 8);  // heavy first
  const int bh = blockIdx.x & 31;
  const int b  = bh >> 4, h = bh & 15;
  const int wrow0 = qt * 128 + w * 32;
  const int ktmax_w = 4 * qt + w;
  const int ktmax_b = 4 * qt + 3;

  const bf16_t* kb  = k  + (size_t)(b * S_) * DH_;
  const bf16_t* vtb = vt + (size_t)(b * S_);

  int koff[3], voff[3], ldst[3];
#pragma unroll
  for (int i = 0; i < 3; ++i) {
    int g = i * 256 + tid;
    int krow = g / 24, kch = g - krow * 24;
    koff[i] = krow * DH_ + ((kch ^ (krow & 7)) << 3);
    int vrow = g >> 2, vch = g & 3;
    voff[i] = vrow * NROWS + ((vch ^ (vrow & 3)) << 3);
    ldst[i] = (i * 256 + w * 64) * 8;
  }

  auto stageK = [&](int kt, int bu) {
    const bf16_t* ksrc = kb + (size_t)kt * KB32 * DH_;
#pragma unroll
    for (int i = 0; i < 3; ++i)
      __builtin_amdgcn_global_load_lds((glb_u32_t*)(ksrc + koff[i]),
                                       (lds_u32_t*)(&sK[bu][0] + ldst[i]), 16, 0, 0);
  };
  auto stageV = [&](int kt) {
    const bf16_t* vsrc = vtb + kt * KB32;
#pragma unroll
    for (int i = 0; i < 3; ++i)
      __builtin_amdgcn_global_load_lds((glb_u32_t*)(vsrc + voff[i]),
                                       (lds_u32_t*)(sV + ldst[i]), 16, 0, 0);
  };

  bf16x8 qf[2][6];
#pragma unroll
  for (int rf = 0; rf < 2; ++rf) {
    size_t rowoff = (size_t)(b * S_ + wrow0 + rf * 16 + lr) * QKD + h * DH_;
#pragma unroll
    for (int ks = 0; ks < 6; ++ks)
      qf[rf][ks] = *reinterpret_cast<const bf16x8*>(&q[rowoff + ks * 32 + lg * 8]);
  }

  bf16x8 vones;
#pragma unroll
  for (int e = 0; e < 8; ++e) vones[e] = (bf16_t)((lr == 0) ? 1.0f : 0.0f);

  f32x4 acc[2][13];
#pragma unroll
  for (int rf = 0; rf < 2; ++rf) {
#pragma unroll
    for (int c = 0; c < 12; ++c) acc[rf][c] = f32x4{0.f, 0.f, 0.f, 0.f};
    float init = (lr == 0) ? 1.0f : 0.0f;
    acc[rf][12] = f32x4{init, init, init, init};
  }

  const float L2E = 1.4426950408889634f;
  float m[2][4];
  float sk2 = sink[h] * L2E;
#pragma unroll
  for (int rf = 0; rf < 2; ++rf)
#pragma unroll
    for (int r = 0; r < 4; ++r) m[rf][r] = sk2;

  stageK(0, 0);
  int cur = 0;

  for (int kt = 0; kt <= ktmax_b; ++kt) {
    __syncthreads();                 // all waves done PV(kt-1): sV free; sK[cur^1] free

    stageV(kt);                      // must land before PV(kt)
    const bool more = (kt < ktmax_b);
    if (more) stageK(kt + 1, cur ^ 1);

    if (kt <= ktmax_w) {
      // ---- wait K(kt) only ----
      if (more) { asm volatile("s_waitcnt vmcnt(6)" ::: "memory"); }
      else      { asm volatile("s_waitcnt vmcnt(3)" ::: "memory"); }

      // ---- QK^T (q pre-scaled; scores in log2 domain) ----
      f32x4 sc[2][2];
#pragma unroll
      for (int rf = 0; rf < 2; ++rf)
#pragma unroll
        for (int c = 0; c < 2; ++c) sc[rf][c] = f32x4{0.f, 0.f, 0.f, 0.f};
#pragma unroll
      for (int c = 0; c < 2; ++c) {
        const int row = c * 16 + lr;
        const int rx  = row & 7;
        const bf16_t* kr = &sK[cur][0] + row * DH_;
#pragma unroll
        for (int ks = 0; ks < 6; ++ks) {
          bf16x8 kf = *reinterpret_cast<const bf16x8*>(kr + (((ks * 4 + lg) ^ rx) << 3));
          sc[0][c] = __builtin_amdgcn_mfma_f32_16x16x32_bf16(qf[0][ks], kf, sc[0][c], 0, 0, 0);
          sc[1][c] = __builtin_amdgcn_mfma_f32_16x16x32_bf16(qf[1][ks], kf, sc[1][c], 0, 0, 0);
        }
      }

      // ---- causal mask only on the wave-diagonal iteration ----
      if (kt == ktmax_w) {
#pragma unroll
        for (int rf = 0; rf < 2; ++rf)
#pragma unroll
          for (int c = 0; c < 2; ++c)
#pragma unroll
            for (int r = 0; r < 4; ++r)
              if ((kt * 32 + c * 16 + lr) > (wrow0 + rf * 16 + lg * 4 + r))
                sc[rf][c][r] = -1e30f;
      }

      // ---- defer-max check ----
      int ok = 1;
      float lmax[2][4];
#pragma unroll
      for (int rf = 0; rf < 2; ++rf)
#pragma unroll
        for (int r = 0; r < 4; ++r) {
          lmax[rf][r] = fmaxf(sc[rf][0][r], sc[rf][1][r]);
          ok &= (lmax[rf][r] <= m[rf][r] + 8.0f);
        }
      if (!__all(ok)) {
#pragma unroll
        for (int rf = 0; rf < 2; ++rf) {
          float rmax[4], alpha[4];
#pragma unroll
          for (int r = 0; r < 4; ++r) rmax[r] = lmax[rf][r];
#pragma unroll
          for (int off = 1; off < 16; off <<= 1) {
#pragma unroll
            for (int r = 0; r < 4; ++r) rmax[r] = fmaxf(rmax[r], __shfl_xor(rmax[r], off));
          }
#pragma unroll
          for (int r = 0; r < 4; ++r) {
            float mn = fmaxf(m[rf][r], rmax[r]);
            alpha[r] = EXP2(m[rf][r] - mn);
            m[rf][r] = mn;
          }
#pragma unroll
          for (int c = 0; c < 13; ++c)
#pragma unroll
            for (int r = 0; r < 4; ++r) acc[rf][c][r] *= alpha[r];
        }
      }

      // ---- P = exp2(sc - m) -> per-wave LDS ----
#pragma unroll
      for (int rf = 0; rf < 2; ++rf)
#pragma unroll
        for (int c = 0; c < 2; ++c)
#pragma unroll
          for (int r = 0; r < 4; ++r)
            sP[w][rf * 16 + lg * 4 + r][c * 16 + lr] = (bf16_t)EXP2(sc[rf][c][r] - m[rf][r]);

      // ---- wait V(kt) only (K(kt+1) keeps riding) ----
      if (more) { asm volatile("s_waitcnt vmcnt(3)" ::: "memory"); }
      else      { asm volatile("s_waitcnt vmcnt(0)" ::: "memory"); }

      // ---- PV + denominator ----
      bf16x8 pf[2];
      pf[0] = *reinterpret_cast<const bf16x8*>(&sP[w][lr][lg * 8]);
      pf[1] = *reinterpret_cast<const bf16x8*>(&sP[w][16 + lr][lg * 8]);
#pragma unroll
      for (int c2 = 0; c2 < 12; ++c2) {
        const int row = c2 * 16 + lr;
        bf16x8 vf = *reinterpret_cast<const bf16x8*>(
            sV + row * KB32 + ((lg ^ (row & 3)) << 3));
        acc[0][c2] = __builtin_amdgcn_mfma_f32_16x16x32_bf16(pf[0], vf, acc[0][c2], 0, 0, 0);
        acc[1][c2] = __builtin_amdgcn_mfma_f32_16x16x32_bf16(pf[1], vf, acc[1][c2], 0, 0, 0);
      }
      acc[0][12] = __builtin_amdgcn_mfma_f32_16x16x32_bf16(pf[0], vones, acc[0][12], 0, 0, 0);
      acc[1][12] = __builtin_amdgcn_mfma_f32_16x16x32_bf16(pf[1], vones, acc[1][12], 0, 0, 0);
    }
    cur ^= 1;
  }

  // ---- epilogue ----
#pragma unroll
  for (int rf = 0; rf < 2; ++rf) {
    float rl[4];
#pragma unroll
    for (int r = 0; r < 4; ++r) rl[r] = 1.0f / __shfl(acc[rf][12][r], l & 48);
#pragma unroll
    for (int c2 = 0; c2 < 12; ++c2) {
#pragma unroll
      for (int r = 0; r < 4; ++r) {
        int i = wrow0 + rf * 16 + lg * 4 + r;
        size_t off = (size_t)(b * S_ + i) * QKD + h * DH_ + c2 * 16 + lr;
        attn[off] = (bf16_t)(acc[rf][c2][r] * rl[r]);
      }
    }
  }
}

// ---------------- launch ----------------
extern "C" void kernel_launch(void* const* d_in, const int* in_sizes, int n_in,
                              void* d_out, int out_size, void* d_ws, size_t ws_size,
                              hipStream_t stream) {
  const float* x        = (const float*)d_in[0];
  const float* w_qa     = (const float*)d_in[1];
  const float* q_norm_w = (const float*)d_in[2];
  const float* w_qb     = (const float*)d_in[3];
  const float* w_k      = (const float*)d_in[4];
  const float* w_v      = (const float*)d_in[5];
  const float* w_o      = (const float*)d_in[6];
  const float* attn_sink= (const float*)d_in[7];
  float* out = (float*)d_out;

  char* ws = (char*)d_ws;
  size_t off = 0;
  auto alloc = [&](size_t bytes) -> void* {
    void* p = ws + off;
    off += (bytes + 255) & ~(size_t)255;
    return p;
  };
  bf16_t* q_b  = (bf16_t*)alloc((size_t)NROWS * QKD * 2);
  bf16_t* k_b  = (bf16_t*)alloc((size_t)NROWS * DH_ * 2);
  bf16_t* vt_b = (bf16_t*)alloc((size_t)DH_ * NROWS * 2);
  bf16_t* wo_t = (bf16_t*)alloc((size_t)HID_ * QKD * 2);   // w_o^T [2048][3072]
  size_t temp_start = off;
  bf16_t* xb    = (bf16_t*)alloc((size_t)NROWS * HID_ * 2);
  bf16_t* wqa_t = (bf16_t*)alloc((size_t)QL_ * HID_ * 2);  // [512][2048]
  bf16_t* wqb_t = (bf16_t*)alloc((size_t)QKD * QL_ * 2);   // [3072][512]
  bf16_t* wkv_t = (bf16_t*)alloc((size_t)(2 * DH_) * HID_ * 2); // [384][2048]
  bf16_t* qa_b  = (bf16_t*)alloc((size_t)NROWS * QL_ * 2);
  bf16_t* attn_b = (bf16_t*)(ws + temp_start);             // overlays dead temps

  const float SCALE2 = 0.10411754646447386f;  // 192^-0.5 * log2(e)

  // all 5 weight transposes + x cast, one launch
  prep_all<<<dim3(11520), dim3(256), 0, stream>>>(
      w_qa, w_qb, w_k, w_v, w_o, x,
      wqa_t, wqb_t, wkv_t, wkv_t + (size_t)DH_ * HID_, wo_t, xb);

  // q_a = rmsnorm(x @ w_qa)   [64x128 tile: 256 blocks]
  gemm64x128_kernel<1><<<dim3(QL_ / 128, NROWS / 64), 256, 0, stream>>>(xb, wqa_t, qa_b, NROWS, QL_, HID_, 1.0f);
  rmsnorm_kernel<<<dim3(NROWS), dim3(64), 0, stream>>>(qa_b, q_norm_w);
  // q = rope((q_a @ w_qb)) * SCALE2  [128 tile, fused Q-RoPE: 768 blocks]
  gemm128_kernel<1, true><<<dim3(QKD / 128, NROWS / 128), 256, 0, stream>>>(qa_b, wqb_t, q_b, NROWS, QKD, QL_, SCALE2);
  // k (with fused K-RoPE) + v^T in one launch
  gemm_kv_kernel<<<dim3((2 * DH_) / BN, NROWS / BM), 256, 0, stream>>>(xb, wkv_t, k_b, vt_b);
  // attention (r12 core, 512 blocks)
  attn_kernel<<<dim3(512), dim3(256), 0, stream>>>(q_b, k_b, vt_b, attn_sink, attn_b);
  // out = attn @ w_o          [64x128 tile: 1024 blocks, 4/CU]
  gemm64x128_kernel<0><<<dim3(HID_ / 128, NROWS / 64), 256, 0, stream>>>(attn_b, wo_t, out, NROWS, HID_, QKD, 1.0f);
}

// Round 15
// 294.359 us; speedup vs baseline: 1.0708x; 1.0345x over previous
//
#include <hip/hip_runtime.h>
#include <hip/hip_bf16.h>

typedef __bf16 bf16_t;
typedef __bf16 bf16x8 __attribute__((ext_vector_type(8)));
typedef __bf16 bf16x4 __attribute__((ext_vector_type(4)));
typedef float  f32x4  __attribute__((ext_vector_type(4)));
typedef __attribute__((address_space(3))) unsigned int lds_u32_t;
typedef __attribute__((address_space(1))) const unsigned int glb_u32_t;

#define B_    2
#define S_    2048
#define HID_  2048
#define H_    16
#define DH_   192
#define DR_   64
#define DN_   128
#define QL_   512
#define NROWS (B_*S_)          // 4096
#define QKD   (H_*DH_)         // 3072

#if __has_builtin(__builtin_amdgcn_exp2f)
#define EXP2(x) __builtin_amdgcn_exp2f(x)
#else
#define EXP2(x) exp2f(x)
#endif

// XCD-aware bijective block swizzle (requires nwg % 8 == 0).
__device__ inline void xcd_remap(int& bx, int& by) {
  const int gx = gridDim.x;
  const int nwg = gx * gridDim.y;
  const int flat = by * gx + bx;
  const int q = nwg >> 3;
  const int nf = (flat & 7) * q + (flat >> 3);
  bx = nf % gx;
  by = nf / gx;
}

// ---------------- cast f32 -> bf16 (vec4) ----------------
__global__ void cast_f32_to_bf16(const float* __restrict__ in, bf16_t* __restrict__ out, int n4) {
  int i = blockIdx.x * blockDim.x + threadIdx.x;
  if (i >= n4) return;
  const float4 v = reinterpret_cast<const float4*>(in)[i];
  bf16x4 r;
  r[0] = (bf16_t)v.x; r[1] = (bf16_t)v.y; r[2] = (bf16_t)v.z; r[3] = (bf16_t)v.w;
  reinterpret_cast<bf16x4*>(out)[i] = r;
}

// ---------------- all 5 weight transposes in one launch ----------------
__global__ __launch_bounds__(256) void transpose_all(
    const float* __restrict__ i0, const float* __restrict__ i1,
    const float* __restrict__ i2, const float* __restrict__ i3,
    const float* __restrict__ i4,
    bf16_t* __restrict__ o0, bf16_t* __restrict__ o1, bf16_t* __restrict__ o2,
    bf16_t* __restrict__ o3, bf16_t* __restrict__ o4) {
  int id = blockIdx.x;
  const float* in; bf16_t* out; int R, C, lid;
  if (id < 1024)      { in = i0; out = o0; R = 2048; C = 512;  lid = id; }
  else if (id < 2560) { in = i1; out = o1; R = 512;  C = 3072; lid = id - 1024; }
  else if (id < 2944) { in = i2; out = o2; R = 2048; C = 192;  lid = id - 2560; }
  else if (id < 3328) { in = i3; out = o3; R = 2048; C = 192;  lid = id - 2944; }
  else                { in = i4; out = o4; R = 3072; C = 2048; lid = id - 3328; }
  const int cw = C >> 5;
  const int c0 = (lid % cw) * 32, r0 = (lid / cw) * 32;
  __shared__ float t[32][33];
  const int tx = threadIdx.x & 31;
  const int ty = threadIdx.x >> 5;
#pragma unroll
  for (int j = 0; j < 4; ++j)
    t[ty + j * 8][tx] = in[(size_t)(r0 + ty + j * 8) * C + c0 + tx];
  __syncthreads();
#pragma unroll
  for (int j = 0; j < 4; ++j)
    out[(size_t)(c0 + ty + j * 8) * R + r0 + tx] = (bf16_t)t[tx][ty + j * 8];
}

// ---------------- merged K/V GEMM (64x64 tile), B^T input ----------------
#define BM 64
#define BN 64
#define BK 64
#define LDT 72

__global__ __launch_bounds__(256) void gemm_kv_kernel(
    const bf16_t* __restrict__ A, const bf16_t* __restrict__ BT,
    bf16_t* __restrict__ Kout, bf16_t* __restrict__ VTout) {
  __shared__ __align__(16) bf16_t sA[BM][LDT];
  __shared__ __align__(16) bf16_t sB[BN][LDT];
  const int tid = threadIdx.x;
  const int w  = tid >> 6;
  const int l  = tid & 63;
  const int lg = l >> 4, lr = l & 15;
  int bx = blockIdx.x, by = blockIdx.y;
  xcd_remap(bx, by);
  const int m0 = by * BM, n0 = bx * BN;
  const int K = HID_;

  f32x4 acc[4];
#pragma unroll
  for (int c = 0; c < 4; ++c) acc[c] = f32x4{0.f, 0.f, 0.f, 0.f};

  for (int k0 = 0; k0 < K; k0 += BK) {
#pragma unroll
    for (int i = 0; i < 2; ++i) {
      int cid = tid + i * 256;
      int row = cid >> 3;
      int cb  = (cid & 7) * 8;
      *reinterpret_cast<uint4*>(&sA[row][cb]) =
          *reinterpret_cast<const uint4*>(&A[(size_t)(m0 + row) * K + k0 + cb]);
      *reinterpret_cast<uint4*>(&sB[row][cb]) =
          *reinterpret_cast<const uint4*>(&BT[(size_t)(n0 + row) * K + k0 + cb]);
    }
    __syncthreads();
#pragma unroll
    for (int ks = 0; ks < 2; ++ks) {
      bf16x8 af = *reinterpret_cast<const bf16x8*>(&sA[w * 16 + lr][ks * 32 + lg * 8]);
#pragma unroll
      for (int c = 0; c < 4; ++c) {
        bf16x8 bfr = *reinterpret_cast<const bf16x8*>(&sB[c * 16 + lr][ks * 32 + lg * 8]);
        acc[c] = __builtin_amdgcn_mfma_f32_16x16x32_bf16(af, bfr, acc[c], 0, 0, 0);
      }
    }
    __syncthreads();
  }
#pragma unroll
  for (int c = 0; c < 4; ++c) {
#pragma unroll
    for (int r = 0; r < 4; ++r) {
      int row = m0 + w * 16 + lg * 4 + r;
      int col = n0 + c * 16 + lr;
      float v = acc[c][r];
      if (col < DH_) Kout[(size_t)row * DH_ + col] = (bf16_t)v;
      else           VTout[(size_t)(col - DH_) * NROWS + row] = (bf16_t)v;
    }
  }
}

// ---------------- big bf16 MFMA GEMM (128x128x64 tile, m97 structure) --------
template<int OMODE>
__global__ __launch_bounds__(256) void gemm128_kernel(
    const bf16_t* __restrict__ A, const bf16_t* __restrict__ BT,
    void* __restrict__ C, int M, int N, int K, float oscale) {
  __shared__ __align__(16) bf16_t sA[128 * 64];
  __shared__ __align__(16) bf16_t sB[128 * 64];
  const int tid = threadIdx.x;
  const int w  = tid >> 6;
  const int l  = tid & 63;
  const int lg = l >> 4, lr = l & 15;
  const int wm = w >> 1, wn = w & 1;
  int bx = blockIdx.x, by = blockIdx.y;
  xcd_remap(bx, by);
  const int m0 = by * 128, n0 = bx * 128;

  size_t aoff[4], boff[4];
  int ldsoff[4];
#pragma unroll
  for (int i = 0; i < 4; ++i) {
    int cid = i * 256 + tid;
    int row = cid >> 3, ch = cid & 7;
    int sch = ch ^ (row & 7);
    aoff[i] = (size_t)(m0 + row) * K + sch * 8;
    boff[i] = (size_t)(n0 + row) * K + sch * 8;
    ldsoff[i] = (i * 256 + w * 64) * 8;
  }

  f32x4 acc[4][4];
#pragma unroll
  for (int mi = 0; mi < 4; ++mi)
#pragma unroll
    for (int ni = 0; ni < 4; ++ni) acc[mi][ni] = f32x4{0.f, 0.f, 0.f, 0.f};

  for (int k0 = 0; k0 < K; k0 += 64) {
#pragma unroll
    for (int i = 0; i < 4; ++i) {
      __builtin_amdgcn_global_load_lds((glb_u32_t*)(A + aoff[i] + k0),
                                       (lds_u32_t*)(sA + ldsoff[i]), 16, 0, 0);
      __builtin_amdgcn_global_load_lds((glb_u32_t*)(BT + boff[i] + k0),
                                       (lds_u32_t*)(sB + ldsoff[i]), 16, 0, 0);
    }
    asm volatile("s_waitcnt vmcnt(0)" ::: "memory");
    __syncthreads();

#pragma unroll
    for (int ks = 0; ks < 2; ++ks) {
      bf16x8 af[4], bfr[4];
#pragma unroll
      for (int mi = 0; mi < 4; ++mi) {
        int row = wm * 64 + mi * 16 + lr;
        af[mi] = *reinterpret_cast<const bf16x8*>(
            sA + row * 64 + (((ks * 4 + lg) ^ (row & 7)) << 3));
      }
#pragma unroll
      for (int ni = 0; ni < 4; ++ni) {
        int row = wn * 64 + ni * 16 + lr;
        bfr[ni] = *reinterpret_cast<const bf16x8*>(
            sB + row * 64 + (((ks * 4 + lg) ^ (row & 7)) << 3));
      }
#pragma unroll
      for (int mi = 0; mi < 4; ++mi)
#pragma unroll
        for (int ni = 0; ni < 4; ++ni)
          acc[mi][ni] = __builtin_amdgcn_mfma_f32_16x16x32_bf16(af[mi], bfr[ni], acc[mi][ni], 0, 0, 0);
    }
    __syncthreads();
  }

#pragma unroll
  for (int mi = 0; mi < 4; ++mi) {
#pragma unroll
    for (int ni = 0; ni < 4; ++ni) {
#pragma unroll
      for (int r = 0; r < 4; ++r) {
        int row = m0 + wm * 64 + mi * 16 + lg * 4 + r;
        int col = n0 + wn * 64 + ni * 16 + lr;
        float v = acc[mi][ni][r];
        if (OMODE == 0) ((float*)C)[(size_t)row * N + col]  = v;
        else            ((bf16_t*)C)[(size_t)row * N + col] = (bf16_t)(v * oscale);
      }
    }
  }
}

// ---------------- 64x128x64-tile GEMM (m97 structure), B^T input --------------
template<int OMODE>
__global__ __launch_bounds__(256) void gemm64x128_kernel(
    const bf16_t* __restrict__ A, const bf16_t* __restrict__ BT,
    void* __restrict__ C, int M, int N, int K, float oscale) {
  __shared__ __align__(16) bf16_t sA[64 * 64];    // 8KB
  __shared__ __align__(16) bf16_t sB[128 * 64];   // 16KB
  const int tid = threadIdx.x;
  const int w  = tid >> 6;
  const int l  = tid & 63;
  const int lg = l >> 4, lr = l & 15;
  const int wm = w >> 1, wn = w & 1;
  int bx = blockIdx.x, by = blockIdx.y;
  xcd_remap(bx, by);
  const int m0 = by * 64, n0 = bx * 128;

  size_t aoff[2], boff[4];
  int ldsa[2], ldsb[4];
#pragma unroll
  for (int i = 0; i < 2; ++i) {
    int cid = i * 256 + tid;
    int row = cid >> 3, ch = cid & 7;
    aoff[i] = (size_t)(m0 + row) * K + (ch ^ (row & 7)) * 8;
    ldsa[i] = (i * 256 + w * 64) * 8;
  }
#pragma unroll
  for (int i = 0; i < 4; ++i) {
    int cid = i * 256 + tid;
    int row = cid >> 3, ch = cid & 7;
    boff[i] = (size_t)(n0 + row) * K + (ch ^ (row & 7)) * 8;
    ldsb[i] = (i * 256 + w * 64) * 8;
  }

  f32x4 acc[2][4];
#pragma unroll
  for (int mi = 0; mi < 2; ++mi)
#pragma unroll
    for (int ni = 0; ni < 4; ++ni) acc[mi][ni] = f32x4{0.f, 0.f, 0.f, 0.f};

  for (int k0 = 0; k0 < K; k0 += 64) {
#pragma unroll
    for (int i = 0; i < 2; ++i)
      __builtin_amdgcn_global_load_lds((glb_u32_t*)(A + aoff[i] + k0),
                                       (lds_u32_t*)(sA + ldsa[i]), 16, 0, 0);
#pragma unroll
    for (int i = 0; i < 4; ++i)
      __builtin_amdgcn_global_load_lds((glb_u32_t*)(BT + boff[i] + k0),
                                       (lds_u32_t*)(sB + ldsb[i]), 16, 0, 0);
    asm volatile("s_waitcnt vmcnt(0)" ::: "memory");
    __syncthreads();

#pragma unroll
    for (int ks = 0; ks < 2; ++ks) {
      bf16x8 af[2], bfr[4];
#pragma unroll
      for (int mi = 0; mi < 2; ++mi) {
        int row = wm * 32 + mi * 16 + lr;
        af[mi] = *reinterpret_cast<const bf16x8*>(
            sA + row * 64 + (((ks * 4 + lg) ^ (row & 7)) << 3));
      }
#pragma unroll
      for (int ni = 0; ni < 4; ++ni) {
        int row = wn * 64 + ni * 16 + lr;
        bfr[ni] = *reinterpret_cast<const bf16x8*>(
            sB + row * 64 + (((ks * 4 + lg) ^ (row & 7)) << 3));
      }
#pragma unroll
      for (int mi = 0; mi < 2; ++mi)
#pragma unroll
        for (int ni = 0; ni < 4; ++ni)
          acc[mi][ni] = __builtin_amdgcn_mfma_f32_16x16x32_bf16(af[mi], bfr[ni], acc[mi][ni], 0, 0, 0);
    }
    __syncthreads();
  }

#pragma unroll
  for (int mi = 0; mi < 2; ++mi) {
#pragma unroll
    for (int ni = 0; ni < 4; ++ni) {
#pragma unroll
      for (int r = 0; r < 4; ++r) {
        int row = m0 + wm * 32 + mi * 16 + lg * 4 + r;
        int col = n0 + wn * 64 + ni * 16 + lr;
        float v = acc[mi][ni][r];
        if (OMODE == 0) ((float*)C)[(size_t)row * N + col]  = v;
        else            ((bf16_t*)C)[(size_t)row * N + col] = (bf16_t)(v * oscale);
      }
    }
  }
}

// ---------------- RMSNorm (in-place, one wave per row of 512) ----------------
__global__ __launch_bounds__(64) void rmsnorm_kernel(bf16_t* __restrict__ qa,
                                                     const float* __restrict__ wnorm) {
  int row = blockIdx.x;
  int l = threadIdx.x;
  bf16x8 v = *reinterpret_cast<const bf16x8*>(&qa[(size_t)row * QL_ + l * 8]);
  float f[8];
  float ss = 0.f;
#pragma unroll
  for (int e = 0; e < 8; ++e) { f[e] = (float)v[e]; ss += f[e] * f[e]; }
#pragma unroll
  for (int off = 32; off >= 1; off >>= 1) ss += __shfl_xor(ss, off);
  float rstd = rsqrtf(ss * (1.0f / 512.0f) + 1e-6f);
  bf16x8 o;
#pragma unroll
  for (int e = 0; e < 8; ++e) o[e] = (bf16_t)(f[e] * rstd * wnorm[l * 8 + e]);
  *reinterpret_cast<bf16x8*>(&qa[(size_t)row * QL_ + l * 8]) = o;
}

// ---------------- RoPE (q and k fused in one launch) ----------------
__global__ void rope_kernel(bf16_t* __restrict__ q, bf16_t* __restrict__ k) {
  int idx = blockIdx.x * blockDim.x + threadIdx.x;
  const int NQ = NROWS * H_ * 32;
  if (idx < NQ) {
    int d   = idx & 31;
    int h   = (idx >> 5) & 15;
    int row = idx >> 9;
    int s = row & (S_ - 1);
    float freq = (float)s * expf(-(float)d * (9.210340371976184f / 32.0f));
    float sn, cs;
    sincosf(freq, &sn, &cs);
    size_t base = (size_t)row * QKD + h * DH_ + DN_ + d;
    float q1 = (float)q[base], q2 = (float)q[base + 32];
    q[base]      = (bf16_t)(q1 * cs - q2 * sn);
    q[base + 32] = (bf16_t)(q2 * cs + q1 * sn);
  } else {
    int i2 = idx - NQ;
    if (i2 >= NROWS * 32) return;
    int d   = i2 & 31;
    int row = i2 >> 5;
    int s = row & (S_ - 1);
    float freq = (float)s * expf(-(float)d * (9.210340371976184f / 32.0f));
    float sn, cs;
    sincosf(freq, &sn, &cs);
    size_t base = (size_t)row * DH_ + DN_ + d;
    float k1 = (float)k[base], k2 = (float)k[base + 32];
    k[base]      = (bf16_t)(k1 * cs - k2 * sn);
    k[base + 32] = (bf16_t)(k2 * cs + k1 * sn);
  }
}

// ---------------- causal flash attention with sink (r12 core + setprio) ------
// 4 waves x 32 rows. K dbuf (24KB) + V single (12KB) + sP (10KB) = 46KB.
// One barrier/iter, counted vmcnt. Ones-column denominator; defer-max THR=8;
// q pre-scaled by 192^-0.5*log2e; wave-uniform diag branch.
// T5: s_setprio(1) around the QKT and PV MFMA clusters.
#define KB32  32
#define SPLD  40

__global__ __launch_bounds__(256, 2) void attn_kernel(
    const bf16_t* __restrict__ q, const bf16_t* __restrict__ k,
    const bf16_t* __restrict__ vt, const float* __restrict__ sink,
    bf16_t* __restrict__ attn) {
  __shared__ __align__(16) bf16_t sK[2][KB32 * DH_];   // 24KB dbuf
  __shared__ __align__(16) bf16_t sV[DH_ * KB32];      // 12KB single
  __shared__ __align__(16) bf16_t sP[4][32][SPLD];     // 10KB
  const int tid = threadIdx.x;
  const int w  = tid >> 6;
  const int l  = tid & 63;
  const int lg = l >> 4, lr = l & 15;
  const int qx = blockIdx.x >> 5;
  const int qt = (qx < 8) ? (15 - qx) : (qx - 8);  // heavy first
  const int bh = blockIdx.x & 31;
  const int b  = bh >> 4, h = bh & 15;
  const int wrow0 = qt * 128 + w * 32;
  const int ktmax_w = 4 * qt + w;
  const int ktmax_b = 4 * qt + 3;

  const bf16_t* kb  = k  + (size_t)(b * S_) * DH_;
  const bf16_t* vtb = vt + (size_t)(b * S_);

  int koff[3], voff[3], ldst[3];
#pragma unroll
  for (int i = 0; i < 3; ++i) {
    int g = i * 256 + tid;
    int krow = g / 24, kch = g - krow * 24;
    koff[i] = krow * DH_ + ((kch ^ (krow & 7)) << 3);
    int vrow = g >> 2, vch = g & 3;
    voff[i] = vrow * NROWS + ((vch ^ (vrow & 3)) << 3);
    ldst[i] = (i * 256 + w * 64) * 8;
  }

  auto stageK = [&](int kt, int bu) {
    const bf16_t* ksrc = kb + (size_t)kt * KB32 * DH_;
#pragma unroll
    for (int i = 0; i < 3; ++i)
      __builtin_amdgcn_global_load_lds((glb_u32_t*)(ksrc + koff[i]),
                                       (lds_u32_t*)(&sK[bu][0] + ldst[i]), 16, 0, 0);
  };
  auto stageV = [&](int kt) {
    const bf16_t* vsrc = vtb + kt * KB32;
#pragma unroll
    for (int i = 0; i < 3; ++i)
      __builtin_amdgcn_global_load_lds((glb_u32_t*)(vsrc + voff[i]),
                                       (lds_u32_t*)(sV + ldst[i]), 16, 0, 0);
  };

  bf16x8 qf[2][6];
#pragma unroll
  for (int rf = 0; rf < 2; ++rf) {
    size_t rowoff = (size_t)(b * S_ + wrow0 + rf * 16 + lr) * QKD + h * DH_;
#pragma unroll
    for (int ks = 0; ks < 6; ++ks)
      qf[rf][ks] = *reinterpret_cast<const bf16x8*>(&q[rowoff + ks * 32 + lg * 8]);
  }

  bf16x8 vones;
#pragma unroll
  for (int e = 0; e < 8; ++e) vones[e] = (bf16_t)((lr == 0) ? 1.0f : 0.0f);

  f32x4 acc[2][13];
#pragma unroll
  for (int rf = 0; rf < 2; ++rf) {
#pragma unroll
    for (int c = 0; c < 12; ++c) acc[rf][c] = f32x4{0.f, 0.f, 0.f, 0.f};
    float init = (lr == 0) ? 1.0f : 0.0f;
    acc[rf][12] = f32x4{init, init, init, init};
  }

  const float L2E = 1.4426950408889634f;
  float m[2][4];
  float sk2 = sink[h] * L2E;
#pragma unroll
  for (int rf = 0; rf < 2; ++rf)
#pragma unroll
    for (int r = 0; r < 4; ++r) m[rf][r] = sk2;

  stageK(0, 0);
  int cur = 0;

  for (int kt = 0; kt <= ktmax_b; ++kt) {
    __syncthreads();                 // all waves done PV(kt-1): sV free; sK[cur^1] free

    stageV(kt);                      // must land before PV(kt)
    const bool more = (kt < ktmax_b);
    if (more) stageK(kt + 1, cur ^ 1);

    if (kt <= ktmax_w) {
      // ---- wait K(kt) only ----
      if (more) { asm volatile("s_waitcnt vmcnt(6)" ::: "memory"); }
      else      { asm volatile("s_waitcnt vmcnt(3)" ::: "memory"); }

      // ---- QK^T (q pre-scaled; scores in log2 domain) ----
      f32x4 sc[2][2];
#pragma unroll
      for (int rf = 0; rf < 2; ++rf)
#pragma unroll
        for (int c = 0; c < 2; ++c) sc[rf][c] = f32x4{0.f, 0.f, 0.f, 0.f};
      __builtin_amdgcn_s_setprio(1);
#pragma unroll
      for (int c = 0; c < 2; ++c) {
        const int row = c * 16 + lr;
        const int rx  = row & 7;
        const bf16_t* kr = &sK[cur][0] + row * DH_;
#pragma unroll
        for (int ks = 0; ks < 6; ++ks) {
          bf16x8 kf = *reinterpret_cast<const bf16x8*>(kr + (((ks * 4 + lg) ^ rx) << 3));
          sc[0][c] = __builtin_amdgcn_mfma_f32_16x16x32_bf16(qf[0][ks], kf, sc[0][c], 0, 0, 0);
          sc[1][c] = __builtin_amdgcn_mfma_f32_16x16x32_bf16(qf[1][ks], kf, sc[1][c], 0, 0, 0);
        }
      }
      __builtin_amdgcn_s_setprio(0);

      // ---- causal mask only on the wave-diagonal iteration ----
      if (kt == ktmax_w) {
#pragma unroll
        for (int rf = 0; rf < 2; ++rf)
#pragma unroll
          for (int c = 0; c < 2; ++c)
#pragma unroll
            for (int r = 0; r < 4; ++r)
              if ((kt * 32 + c * 16 + lr) > (wrow0 + rf * 16 + lg * 4 + r))
                sc[rf][c][r] = -1e30f;
      }

      // ---- defer-max check ----
      int ok = 1;
      float lmax[2][4];
#pragma unroll
      for (int rf = 0; rf < 2; ++rf)
#pragma unroll
        for (int r = 0; r < 4; ++r) {
          lmax[rf][r] = fmaxf(sc[rf][0][r], sc[rf][1][r]);
          ok &= (lmax[rf][r] <= m[rf][r] + 8.0f);
        }
      if (!__all(ok)) {
#pragma unroll
        for (int rf = 0; rf < 2; ++rf) {
          float rmax[4], alpha[4];
#pragma unroll
          for (int r = 0; r < 4; ++r) rmax[r] = lmax[rf][r];
#pragma unroll
          for (int off = 1; off < 16; off <<= 1) {
#pragma unroll
            for (int r = 0; r < 4; ++r) rmax[r] = fmaxf(rmax[r], __shfl_xor(rmax[r], off));
          }
#pragma unroll
          for (int r = 0; r < 4; ++r) {
            float mn = fmaxf(m[rf][r], rmax[r]);
            alpha[r] = EXP2(m[rf][r] - mn);
            m[rf][r] = mn;
          }
#pragma unroll
          for (int c = 0; c < 13; ++c)
#pragma unroll
            for (int r = 0; r < 4; ++r) acc[rf][c][r] *= alpha[r];
        }
      }

      // ---- P = exp2(sc - m) -> per-wave LDS ----
#pragma unroll
      for (int rf = 0; rf < 2; ++rf)
#pragma unroll
        for (int c = 0; c < 2; ++c)
#pragma unroll
          for (int r = 0; r < 4; ++r)
            sP[w][rf * 16 + lg * 4 + r][c * 16 + lr] = (bf16_t)EXP2(sc[rf][c][r] - m[rf][r]);

      // ---- wait V(kt) only (K(kt+1) keeps riding) ----
      if (more) { asm volatile("s_waitcnt vmcnt(3)" ::: "memory"); }
      else      { asm volatile("s_waitcnt vmcnt(0)" ::: "memory"); }

      // ---- PV + denominator ----
      bf16x8 pf[2];
      pf[0] = *reinterpret_cast<const bf16x8*>(&sP[w][lr][lg * 8]);
      pf[1] = *reinterpret_cast<const bf16x8*>(&sP[w][16 + lr][lg * 8]);
      __builtin_amdgcn_s_setprio(1);
#pragma unroll
      for (int c2 = 0; c2 < 12; ++c2) {
        const int row = c2 * 16 + lr;
        bf16x8 vf = *reinterpret_cast<const bf16x8*>(
            sV + row * KB32 + ((lg ^ (row & 3)) << 3));
        acc[0][c2] = __builtin_amdgcn_mfma_f32_16x16x32_bf16(pf[0], vf, acc[0][c2], 0, 0, 0);
        acc[1][c2] = __builtin_amdgcn_mfma_f32_16x16x32_bf16(pf[1], vf, acc[1][c2], 0, 0, 0);
      }
      acc[0][12] = __builtin_amdgcn_mfma_f32_16x16x32_bf16(pf[0], vones, acc[0][12], 0, 0, 0);
      acc[1][12] = __builtin_amdgcn_mfma_f32_16x16x32_bf16(pf[1], vones, acc[1][12], 0, 0, 0);
      __builtin_amdgcn_s_setprio(0);
    }
    cur ^= 1;
  }

  // ---- epilogue ----
#pragma unroll
  for (int rf = 0; rf < 2; ++rf) {
    float rl[4];
#pragma unroll
    for (int r = 0; r < 4; ++r) rl[r] = 1.0f / __shfl(acc[rf][12][r], l & 48);
#pragma unroll
    for (int c2 = 0; c2 < 12; ++c2) {
#pragma unroll
      for (int r = 0; r < 4; ++r) {
        int i = wrow0 + rf * 16 + lg * 4 + r;
        size_t off = (size_t)(b * S_ + i) * QKD + h * DH_ + c2 * 16 + lr;
        attn[off] = (bf16_t)(acc[rf][c2][r] * rl[r]);
      }
    }
  }
}

// ---------------- launch ----------------
extern "C" void kernel_launch(void* const* d_in, const int* in_sizes, int n_in,
                              void* d_out, int out_size, void* d_ws, size_t ws_size,
                              hipStream_t stream) {
  const float* x        = (const float*)d_in[0];
  const float* w_qa     = (const float*)d_in[1];
  const float* q_norm_w = (const float*)d_in[2];
  const float* w_qb     = (const float*)d_in[3];
  const float* w_k      = (const float*)d_in[4];
  const float* w_v      = (const float*)d_in[5];
  const float* w_o      = (const float*)d_in[6];
  const float* attn_sink= (const float*)d_in[7];
  float* out = (float*)d_out;

  char* ws = (char*)d_ws;
  size_t off = 0;
  auto alloc = [&](size_t bytes) -> void* {
    void* p = ws + off;
    off += (bytes + 255) & ~(size_t)255;
    return p;
  };
  bf16_t* q_b  = (bf16_t*)alloc((size_t)NROWS * QKD * 2);
  bf16_t* k_b  = (bf16_t*)alloc((size_t)NROWS * DH_ * 2);
  bf16_t* vt_b = (bf16_t*)alloc((size_t)DH_ * NROWS * 2);
  bf16_t* wo_t = (bf16_t*)alloc((size_t)HID_ * QKD * 2);   // w_o^T [2048][3072]
  size_t temp_start = off;
  bf16_t* xb    = (bf16_t*)alloc((size_t)NROWS * HID_ * 2);
  bf16_t* wqa_t = (bf16_t*)alloc((size_t)QL_ * HID_ * 2);  // [512][2048]
  bf16_t* wqb_t = (bf16_t*)alloc((size_t)QKD * QL_ * 2);   // [3072][512]
  bf16_t* wkv_t = (bf16_t*)alloc((size_t)(2 * DH_) * HID_ * 2); // [384][2048]
  bf16_t* qa_b  = (bf16_t*)alloc((size_t)NROWS * QL_ * 2);
  bf16_t* attn_b = (bf16_t*)(ws + temp_start);             // overlays dead temps

  const float SCALE2 = 0.10411754646447386f;  // 192^-0.5 * log2(e)

  int n4x = (int)((size_t)NROWS * HID_ / 4);
  cast_f32_to_bf16<<<dim3((n4x + 255) / 256), dim3(256), 0, stream>>>(x, xb, n4x);
  transpose_all<<<dim3(9472), dim3(256), 0, stream>>>(
      w_qa, w_qb, w_k, w_v, w_o,
      wqa_t, wqb_t, wkv_t, wkv_t + (size_t)DH_ * HID_, wo_t);

  // q_a = rmsnorm(x @ w_qa)   [64x128 tile: 256 blocks]
  gemm64x128_kernel<1><<<dim3(QL_ / 128, NROWS / 64), 256, 0, stream>>>(xb, wqa_t, qa_b, NROWS, QL_, HID_, 1.0f);
  rmsnorm_kernel<<<dim3(NROWS), dim3(64), 0, stream>>>(qa_b, q_norm_w);
  // q = (q_a @ w_qb) * SCALE2  [128 tile: 768 blocks]
  gemm128_kernel<1><<<dim3(QKD / 128, NROWS / 128), 256, 0, stream>>>(qa_b, wqb_t, q_b, NROWS, QKD, QL_, SCALE2);
  // k + v^T in one launch
  gemm_kv_kernel<<<dim3((2 * DH_) / BN, NROWS / BM), 256, 0, stream>>>(xb, wkv_t, k_b, vt_b);
  // fused rope (q then k)
  {
    int total = NROWS * (H_ + 1) * 32;
    rope_kernel<<<dim3((total + 255) / 256), dim3(256), 0, stream>>>(q_b, k_b);
  }
  attn_kernel<<<dim3(512), dim3(256), 0, stream>>>(q_b, k_b, vt_b, attn_sink, attn_b);
  // out = attn @ w_o          [64x128 tile: 1024 blocks, 4/CU]
  gemm64x128_kernel<0><<<dim3(HID_ / 128, NROWS / 64), 256, 0, stream>>>(attn_b, wo_t, out, NROWS, HID_, QKD, 1.0f);
}

// Round 16
// 287.312 us; speedup vs baseline: 1.0971x; 1.0245x over previous
//
#include <hip/hip_runtime.h>
#include <hip/hip_bf16.h>

typedef __bf16 bf16_t;
typedef __bf16 bf16x8 __attribute__((ext_vector_type(8)));
typedef __bf16 bf16x4 __attribute__((ext_vector_type(4)));
typedef float  f32x4  __attribute__((ext_vector_type(4)));
typedef __attribute__((address_space(3))) unsigned int lds_u32_t;
typedef __attribute__((address_space(1))) const unsigned int glb_u32_t;

#define B_    2
#define S_    2048
#define HID_  2048
#define H_    16
#define DH_   192
#define DR_   64
#define DN_   128
#define QL_   512
#define NROWS (B_*S_)          // 4096
#define QKD   (H_*DH_)         // 3072

#if __has_builtin(__builtin_amdgcn_exp2f)
#define EXP2(x) __builtin_amdgcn_exp2f(x)
#else
#define EXP2(x) exp2f(x)
#endif

// XCD-aware bijective block swizzle (requires nwg % 8 == 0).
__device__ inline void xcd_remap(int& bx, int& by) {
  const int gx = gridDim.x;
  const int nwg = gx * gridDim.y;
  const int flat = by * gx + bx;
  const int q = nwg >> 3;
  const int nf = (flat & 7) * q + (flat >> 3);
  bx = nf % gx;
  by = nf / gx;
}

// ---------------- cast f32 -> bf16 (vec4) ----------------
__global__ void cast_f32_to_bf16(const float* __restrict__ in, bf16_t* __restrict__ out, int n4) {
  int i = blockIdx.x * blockDim.x + threadIdx.x;
  if (i >= n4) return;
  const float4 v = reinterpret_cast<const float4*>(in)[i];
  bf16x4 r;
  r[0] = (bf16_t)v.x; r[1] = (bf16_t)v.y; r[2] = (bf16_t)v.z; r[3] = (bf16_t)v.w;
  reinterpret_cast<bf16x4*>(out)[i] = r;
}

// ---------------- all 5 weight transposes in one launch ----------------
__global__ __launch_bounds__(256) void transpose_all(
    const float* __restrict__ i0, const float* __restrict__ i1,
    const float* __restrict__ i2, const float* __restrict__ i3,
    const float* __restrict__ i4,
    bf16_t* __restrict__ o0, bf16_t* __restrict__ o1, bf16_t* __restrict__ o2,
    bf16_t* __restrict__ o3, bf16_t* __restrict__ o4) {
  int id = blockIdx.x;
  const float* in; bf16_t* out; int R, C, lid;
  if (id < 1024)      { in = i0; out = o0; R = 2048; C = 512;  lid = id; }
  else if (id < 2560) { in = i1; out = o1; R = 512;  C = 3072; lid = id - 1024; }
  else if (id < 2944) { in = i2; out = o2; R = 2048; C = 192;  lid = id - 2560; }
  else if (id < 3328) { in = i3; out = o3; R = 2048; C = 192;  lid = id - 2944; }
  else                { in = i4; out = o4; R = 3072; C = 2048; lid = id - 3328; }
  const int cw = C >> 5;
  const int c0 = (lid % cw) * 32, r0 = (lid / cw) * 32;
  __shared__ float t[32][33];
  const int tx = threadIdx.x & 31;
  const int ty = threadIdx.x >> 5;
#pragma unroll
  for (int j = 0; j < 4; ++j)
    t[ty + j * 8][tx] = in[(size_t)(r0 + ty + j * 8) * C + c0 + tx];
  __syncthreads();
#pragma unroll
  for (int j = 0; j < 4; ++j)
    out[(size_t)(c0 + ty + j * 8) * R + r0 + tx] = (bf16_t)t[tx][ty + j * 8];
}

// ---------------- merged K/V GEMM (64x64 tile), B^T input ----------------
#define BM 64
#define BN 64
#define BK 64
#define LDT 72

__global__ __launch_bounds__(256) void gemm_kv_kernel(
    const bf16_t* __restrict__ A, const bf16_t* __restrict__ BT,
    bf16_t* __restrict__ Kout, bf16_t* __restrict__ VTout) {
  __shared__ __align__(16) bf16_t sA[BM][LDT];
  __shared__ __align__(16) bf16_t sB[BN][LDT];
  const int tid = threadIdx.x;
  const int w  = tid >> 6;
  const int l  = tid & 63;
  const int lg = l >> 4, lr = l & 15;
  int bx = blockIdx.x, by = blockIdx.y;
  xcd_remap(bx, by);
  const int m0 = by * BM, n0 = bx * BN;
  const int K = HID_;

  f32x4 acc[4];
#pragma unroll
  for (int c = 0; c < 4; ++c) acc[c] = f32x4{0.f, 0.f, 0.f, 0.f};

  for (int k0 = 0; k0 < K; k0 += BK) {
#pragma unroll
    for (int i = 0; i < 2; ++i) {
      int cid = tid + i * 256;
      int row = cid >> 3;
      int cb  = (cid & 7) * 8;
      *reinterpret_cast<uint4*>(&sA[row][cb]) =
          *reinterpret_cast<const uint4*>(&A[(size_t)(m0 + row) * K + k0 + cb]);
      *reinterpret_cast<uint4*>(&sB[row][cb]) =
          *reinterpret_cast<const uint4*>(&BT[(size_t)(n0 + row) * K + k0 + cb]);
    }
    __syncthreads();
#pragma unroll
    for (int ks = 0; ks < 2; ++ks) {
      bf16x8 af = *reinterpret_cast<const bf16x8*>(&sA[w * 16 + lr][ks * 32 + lg * 8]);
#pragma unroll
      for (int c = 0; c < 4; ++c) {
        bf16x8 bfr = *reinterpret_cast<const bf16x8*>(&sB[c * 16 + lr][ks * 32 + lg * 8]);
        acc[c] = __builtin_amdgcn_mfma_f32_16x16x32_bf16(af, bfr, acc[c], 0, 0, 0);
      }
    }
    __syncthreads();
  }
#pragma unroll
  for (int c = 0; c < 4; ++c) {
#pragma unroll
    for (int r = 0; r < 4; ++r) {
      int row = m0 + w * 16 + lg * 4 + r;
      int col = n0 + c * 16 + lr;
      float v = acc[c][r];
      if (col < DH_) Kout[(size_t)row * DH_ + col] = (bf16_t)v;
      else           VTout[(size_t)(col - DH_) * NROWS + row] = (bf16_t)v;
    }
  }
}

// ---------------- big bf16 MFMA GEMM (128x128x64 tile, m97 structure) --------
template<int OMODE>
__global__ __launch_bounds__(256) void gemm128_kernel(
    const bf16_t* __restrict__ A, const bf16_t* __restrict__ BT,
    void* __restrict__ C, int M, int N, int K, float oscale) {
  __shared__ __align__(16) bf16_t sA[128 * 64];
  __shared__ __align__(16) bf16_t sB[128 * 64];
  const int tid = threadIdx.x;
  const int w  = tid >> 6;
  const int l  = tid & 63;
  const int lg = l >> 4, lr = l & 15;
  const int wm = w >> 1, wn = w & 1;
  int bx = blockIdx.x, by = blockIdx.y;
  xcd_remap(bx, by);
  const int m0 = by * 128, n0 = bx * 128;

  size_t aoff[4], boff[4];
  int ldsoff[4];
#pragma unroll
  for (int i = 0; i < 4; ++i) {
    int cid = i * 256 + tid;
    int row = cid >> 3, ch = cid & 7;
    int sch = ch ^ (row & 7);
    aoff[i] = (size_t)(m0 + row) * K + sch * 8;
    boff[i] = (size_t)(n0 + row) * K + sch * 8;
    ldsoff[i] = (i * 256 + w * 64) * 8;
  }

  f32x4 acc[4][4];
#pragma unroll
  for (int mi = 0; mi < 4; ++mi)
#pragma unroll
    for (int ni = 0; ni < 4; ++ni) acc[mi][ni] = f32x4{0.f, 0.f, 0.f, 0.f};

  for (int k0 = 0; k0 < K; k0 += 64) {
#pragma unroll
    for (int i = 0; i < 4; ++i) {
      __builtin_amdgcn_global_load_lds((glb_u32_t*)(A + aoff[i] + k0),
                                       (lds_u32_t*)(sA + ldsoff[i]), 16, 0, 0);
      __builtin_amdgcn_global_load_lds((glb_u32_t*)(BT + boff[i] + k0),
                                       (lds_u32_t*)(sB + ldsoff[i]), 16, 0, 0);
    }
    asm volatile("s_waitcnt vmcnt(0)" ::: "memory");
    __syncthreads();

#pragma unroll
    for (int ks = 0; ks < 2; ++ks) {
      bf16x8 af[4], bfr[4];
#pragma unroll
      for (int mi = 0; mi < 4; ++mi) {
        int row = wm * 64 + mi * 16 + lr;
        af[mi] = *reinterpret_cast<const bf16x8*>(
            sA + row * 64 + (((ks * 4 + lg) ^ (row & 7)) << 3));
      }
#pragma unroll
      for (int ni = 0; ni < 4; ++ni) {
        int row = wn * 64 + ni * 16 + lr;
        bfr[ni] = *reinterpret_cast<const bf16x8*>(
            sB + row * 64 + (((ks * 4 + lg) ^ (row & 7)) << 3));
      }
#pragma unroll
      for (int mi = 0; mi < 4; ++mi)
#pragma unroll
        for (int ni = 0; ni < 4; ++ni)
          acc[mi][ni] = __builtin_amdgcn_mfma_f32_16x16x32_bf16(af[mi], bfr[ni], acc[mi][ni], 0, 0, 0);
    }
    __syncthreads();
  }

#pragma unroll
  for (int mi = 0; mi < 4; ++mi) {
#pragma unroll
    for (int ni = 0; ni < 4; ++ni) {
#pragma unroll
      for (int r = 0; r < 4; ++r) {
        int row = m0 + wm * 64 + mi * 16 + lg * 4 + r;
        int col = n0 + wn * 64 + ni * 16 + lr;
        float v = acc[mi][ni][r];
        if (OMODE == 0) ((float*)C)[(size_t)row * N + col]  = v;
        else            ((bf16_t*)C)[(size_t)row * N + col] = (bf16_t)(v * oscale);
      }
    }
  }
}

// ---------------- 64x128x64-tile GEMM (m97 structure), B^T input --------------
template<int OMODE>
__global__ __launch_bounds__(256) void gemm64x128_kernel(
    const bf16_t* __restrict__ A, const bf16_t* __restrict__ BT,
    void* __restrict__ C, int M, int N, int K, float oscale) {
  __shared__ __align__(16) bf16_t sA[64 * 64];    // 8KB
  __shared__ __align__(16) bf16_t sB[128 * 64];   // 16KB
  const int tid = threadIdx.x;
  const int w  = tid >> 6;
  const int l  = tid & 63;
  const int lg = l >> 4, lr = l & 15;
  const int wm = w >> 1, wn = w & 1;
  int bx = blockIdx.x, by = blockIdx.y;
  xcd_remap(bx, by);
  const int m0 = by * 64, n0 = bx * 128;

  size_t aoff[2], boff[4];
  int ldsa[2], ldsb[4];
#pragma unroll
  for (int i = 0; i < 2; ++i) {
    int cid = i * 256 + tid;
    int row = cid >> 3, ch = cid & 7;
    aoff[i] = (size_t)(m0 + row) * K + (ch ^ (row & 7)) * 8;
    ldsa[i] = (i * 256 + w * 64) * 8;
  }
#pragma unroll
  for (int i = 0; i < 4; ++i) {
    int cid = i * 256 + tid;
    int row = cid >> 3, ch = cid & 7;
    boff[i] = (size_t)(n0 + row) * K + (ch ^ (row & 7)) * 8;
    ldsb[i] = (i * 256 + w * 64) * 8;
  }

  f32x4 acc[2][4];
#pragma unroll
  for (int mi = 0; mi < 2; ++mi)
#pragma unroll
    for (int ni = 0; ni < 4; ++ni) acc[mi][ni] = f32x4{0.f, 0.f, 0.f, 0.f};

  for (int k0 = 0; k0 < K; k0 += 64) {
#pragma unroll
    for (int i = 0; i < 2; ++i)
      __builtin_amdgcn_global_load_lds((glb_u32_t*)(A + aoff[i] + k0),
                                       (lds_u32_t*)(sA + ldsa[i]), 16, 0, 0);
#pragma unroll
    for (int i = 0; i < 4; ++i)
      __builtin_amdgcn_global_load_lds((glb_u32_t*)(BT + boff[i] + k0),
                                       (lds_u32_t*)(sB + ldsb[i]), 16, 0, 0);
    asm volatile("s_waitcnt vmcnt(0)" ::: "memory");
    __syncthreads();

#pragma unroll
    for (int ks = 0; ks < 2; ++ks) {
      bf16x8 af[2], bfr[4];
#pragma unroll
      for (int mi = 0; mi < 2; ++mi) {
        int row = wm * 32 + mi * 16 + lr;
        af[mi] = *reinterpret_cast<const bf16x8*>(
            sA + row * 64 + (((ks * 4 + lg) ^ (row & 7)) << 3));
      }
#pragma unroll
      for (int ni = 0; ni < 4; ++ni) {
        int row = wn * 64 + ni * 16 + lr;
        bfr[ni] = *reinterpret_cast<const bf16x8*>(
            sB + row * 64 + (((ks * 4 + lg) ^ (row & 7)) << 3));
      }
#pragma unroll
      for (int mi = 0; mi < 2; ++mi)
#pragma unroll
        for (int ni = 0; ni < 4; ++ni)
          acc[mi][ni] = __builtin_amdgcn_mfma_f32_16x16x32_bf16(af[mi], bfr[ni], acc[mi][ni], 0, 0, 0);
    }
    __syncthreads();
  }

#pragma unroll
  for (int mi = 0; mi < 2; ++mi) {
#pragma unroll
    for (int ni = 0; ni < 4; ++ni) {
#pragma unroll
      for (int r = 0; r < 4; ++r) {
        int row = m0 + wm * 32 + mi * 16 + lg * 4 + r;
        int col = n0 + wn * 64 + ni * 16 + lr;
        float v = acc[mi][ni][r];
        if (OMODE == 0) ((float*)C)[(size_t)row * N + col]  = v;
        else            ((bf16_t*)C)[(size_t)row * N + col] = (bf16_t)(v * oscale);
      }
    }
  }
}

// ---------------- RMSNorm (in-place, one wave per row of 512) ----------------
__global__ __launch_bounds__(64) void rmsnorm_kernel(bf16_t* __restrict__ qa,
                                                     const float* __restrict__ wnorm) {
  int row = blockIdx.x;
  int l = threadIdx.x;
  bf16x8 v = *reinterpret_cast<const bf16x8*>(&qa[(size_t)row * QL_ + l * 8]);
  float f[8];
  float ss = 0.f;
#pragma unroll
  for (int e = 0; e < 8; ++e) { f[e] = (float)v[e]; ss += f[e] * f[e]; }
#pragma unroll
  for (int off = 32; off >= 1; off >>= 1) ss += __shfl_xor(ss, off);
  float rstd = rsqrtf(ss * (1.0f / 512.0f) + 1e-6f);
  bf16x8 o;
#pragma unroll
  for (int e = 0; e < 8; ++e) o[e] = (bf16_t)(f[e] * rstd * wnorm[l * 8 + e]);
  *reinterpret_cast<bf16x8*>(&qa[(size_t)row * QL_ + l * 8]) = o;
}

// ---------------- RoPE (q and k fused in one launch) ----------------
__global__ void rope_kernel(bf16_t* __restrict__ q, bf16_t* __restrict__ k) {
  int idx = blockIdx.x * blockDim.x + threadIdx.x;
  const int NQ = NROWS * H_ * 32;
  if (idx < NQ) {
    int d   = idx & 31;
    int h   = (idx >> 5) & 15;
    int row = idx >> 9;
    int s = row & (S_ - 1);
    float freq = (float)s * expf(-(float)d * (9.210340371976184f / 32.0f));
    float sn, cs;
    sincosf(freq, &sn, &cs);
    size_t base = (size_t)row * QKD + h * DH_ + DN_ + d;
    float q1 = (float)q[base], q2 = (float)q[base + 32];
    q[base]      = (bf16_t)(q1 * cs - q2 * sn);
    q[base + 32] = (bf16_t)(q2 * cs + q1 * sn);
  } else {
    int i2 = idx - NQ;
    if (i2 >= NROWS * 32) return;
    int d   = i2 & 31;
    int row = i2 >> 5;
    int s = row & (S_ - 1);
    float freq = (float)s * expf(-(float)d * (9.210340371976184f / 32.0f));
    float sn, cs;
    sincosf(freq, &sn, &cs);
    size_t base = (size_t)row * DH_ + DN_ + d;
    float k1 = (float)k[base], k2 = (float)k[base + 32];
    k[base]      = (bf16_t)(k1 * cs - k2 * sn);
    k[base + 32] = (bf16_t)(k2 * cs + k1 * sn);
  }
}

// ---------------- causal flash attention with sink (r12 core + setprio) ------
#define KB32  32
#define SPLD  40

__global__ __launch_bounds__(256, 2) void attn_kernel(
    const bf16_t* __restrict__ q, const bf16_t* __restrict__ k,
    const bf16_t* __restrict__ vt, const float* __restrict__ sink,
    bf16_t* __restrict__ attn) {
  __shared__ __align__(16) bf16_t sK[2][KB32 * DH_];   // 24KB dbuf
  __shared__ __align__(16) bf16_t sV[DH_ * KB32];      // 12KB single
  __shared__ __align__(16) bf16_t sP[4][32][SPLD];     // 10KB
  const int tid = threadIdx.x;
  const int w  = tid >> 6;
  const int l  = tid & 63;
  const int lg = l >> 4, lr = l & 15;
  const int qx = blockIdx.x >> 5;
  const int qt = (qx < 8) ? (15 - qx) : (qx - 8);  // heavy first
  const int bh = blockIdx.x & 31;
  const int b  = bh >> 4, h = bh & 15;
  const int wrow0 = qt * 128 + w * 32;
  const int ktmax_w = 4 * qt + w;
  const int ktmax_b = 4 * qt + 3;

  const bf16_t* kb  = k  + (size_t)(b * S_) * DH_;
  const bf16_t* vtb = vt + (size_t)(b * S_);

  int koff[3], voff[3], ldst[3];
#pragma unroll
  for (int i = 0; i < 3; ++i) {
    int g = i * 256 + tid;
    int krow = g / 24, kch = g - krow * 24;
    koff[i] = krow * DH_ + ((kch ^ (krow & 7)) << 3);
    int vrow = g >> 2, vch = g & 3;
    voff[i] = vrow * NROWS + ((vch ^ (vrow & 3)) << 3);
    ldst[i] = (i * 256 + w * 64) * 8;
  }

  auto stageK = [&](int kt, int bu) {
    const bf16_t* ksrc = kb + (size_t)kt * KB32 * DH_;
#pragma unroll
    for (int i = 0; i < 3; ++i)
      __builtin_amdgcn_global_load_lds((glb_u32_t*)(ksrc + koff[i]),
                                       (lds_u32_t*)(&sK[bu][0] + ldst[i]), 16, 0, 0);
  };
  auto stageV = [&](int kt) {
    const bf16_t* vsrc = vtb + kt * KB32;
#pragma unroll
    for (int i = 0; i < 3; ++i)
      __builtin_amdgcn_global_load_lds((glb_u32_t*)(vsrc + voff[i]),
                                       (lds_u32_t*)(sV + ldst[i]), 16, 0, 0);
  };

  bf16x8 qf[2][6];
#pragma unroll
  for (int rf = 0; rf < 2; ++rf) {
    size_t rowoff = (size_t)(b * S_ + wrow0 + rf * 16 + lr) * QKD + h * DH_;
#pragma unroll
    for (int ks = 0; ks < 6; ++ks)
      qf[rf][ks] = *reinterpret_cast<const bf16x8*>(&q[rowoff + ks * 32 + lg * 8]);
  }

  bf16x8 vones;
#pragma unroll
  for (int e = 0; e < 8; ++e) vones[e] = (bf16_t)((lr == 0) ? 1.0f : 0.0f);

  f32x4 acc[2][13];
#pragma unroll
  for (int rf = 0; rf < 2; ++rf) {
#pragma unroll
    for (int c = 0; c < 12; ++c) acc[rf][c] = f32x4{0.f, 0.f, 0.f, 0.f};
    float init = (lr == 0) ? 1.0f : 0.0f;
    acc[rf][12] = f32x4{init, init, init, init};
  }

  const float L2E = 1.4426950408889634f;
  float m[2][4];
  float sk2 = sink[h] * L2E;
#pragma unroll
  for (int rf = 0; rf < 2; ++rf)
#pragma unroll
    for (int r = 0; r < 4; ++r) m[rf][r] = sk2;

  stageK(0, 0);
  int cur = 0;

  for (int kt = 0; kt <= ktmax_b; ++kt) {
    __syncthreads();                 // all waves done PV(kt-1): sV free; sK[cur^1] free

    stageV(kt);                      // must land before PV(kt)
    const bool more = (kt < ktmax_b);
    if (more) stageK(kt + 1, cur ^ 1);

    if (kt <= ktmax_w) {
      if (more) { asm volatile("s_waitcnt vmcnt(6)" ::: "memory"); }
      else      { asm volatile("s_waitcnt vmcnt(3)" ::: "memory"); }

      f32x4 sc[2][2];
#pragma unroll
      for (int rf = 0; rf < 2; ++rf)
#pragma unroll
        for (int c = 0; c < 2; ++c) sc[rf][c] = f32x4{0.f, 0.f, 0.f, 0.f};
      __builtin_amdgcn_s_setprio(1);
#pragma unroll
      for (int c = 0; c < 2; ++c) {
        const int row = c * 16 + lr;
        const int rx  = row & 7;
        const bf16_t* kr = &sK[cur][0] + row * DH_;
#pragma unroll
        for (int ks = 0; ks < 6; ++ks) {
          bf16x8 kf = *reinterpret_cast<const bf16x8*>(kr + (((ks * 4 + lg) ^ rx) << 3));
          sc[0][c] = __builtin_amdgcn_mfma_f32_16x16x32_bf16(qf[0][ks], kf, sc[0][c], 0, 0, 0);
          sc[1][c] = __builtin_amdgcn_mfma_f32_16x16x32_bf16(qf[1][ks], kf, sc[1][c], 0, 0, 0);
        }
      }
      __builtin_amdgcn_s_setprio(0);

      if (kt == ktmax_w) {
#pragma unroll
        for (int rf = 0; rf < 2; ++rf)
#pragma unroll
          for (int c = 0; c < 2; ++c)
#pragma unroll
            for (int r = 0; r < 4; ++r)
              if ((kt * 32 + c * 16 + lr) > (wrow0 + rf * 16 + lg * 4 + r))
                sc[rf][c][r] = -1e30f;
      }

      int ok = 1;
      float lmax[2][4];
#pragma unroll
      for (int rf = 0; rf < 2; ++rf)
#pragma unroll
        for (int r = 0; r < 4; ++r) {
          lmax[rf][r] = fmaxf(sc[rf][0][r], sc[rf][1][r]);
          ok &= (lmax[rf][r] <= m[rf][r] + 8.0f);
        }
      if (!__all(ok)) {
#pragma unroll
        for (int rf = 0; rf < 2; ++rf) {
          float rmax[4], alpha[4];
#pragma unroll
          for (int r = 0; r < 4; ++r) rmax[r] = lmax[rf][r];
#pragma unroll
          for (int off = 1; off < 16; off <<= 1) {
#pragma unroll
            for (int r = 0; r < 4; ++r) rmax[r] = fmaxf(rmax[r], __shfl_xor(rmax[r], off));
          }
#pragma unroll
          for (int r = 0; r < 4; ++r) {
            float mn = fmaxf(m[rf][r], rmax[r]);
            alpha[r] = EXP2(m[rf][r] - mn);
            m[rf][r] = mn;
          }
#pragma unroll
          for (int c = 0; c < 13; ++c)
#pragma unroll
            for (int r = 0; r < 4; ++r) acc[rf][c][r] *= alpha[r];
        }
      }

#pragma unroll
      for (int rf = 0; rf < 2; ++rf)
#pragma unroll
        for (int c = 0; c < 2; ++c)
#pragma unroll
          for (int r = 0; r < 4; ++r)
            sP[w][rf * 16 + lg * 4 + r][c * 16 + lr] = (bf16_t)EXP2(sc[rf][c][r] - m[rf][r]);

      if (more) { asm volatile("s_waitcnt vmcnt(3)" ::: "memory"); }
      else      { asm volatile("s_waitcnt vmcnt(0)" ::: "memory"); }

      bf16x8 pf[2];
      pf[0] = *reinterpret_cast<const bf16x8*>(&sP[w][lr][lg * 8]);
      pf[1] = *reinterpret_cast<const bf16x8*>(&sP[w][16 + lr][lg * 8]);
      __builtin_amdgcn_s_setprio(1);
#pragma unroll
      for (int c2 = 0; c2 < 12; ++c2) {
        const int row = c2 * 16 + lr;
        bf16x8 vf = *reinterpret_cast<const bf16x8*>(
            sV + row * KB32 + ((lg ^ (row & 3)) << 3));
        acc[0][c2] = __builtin_amdgcn_mfma_f32_16x16x32_bf16(pf[0], vf, acc[0][c2], 0, 0, 0);
        acc[1][c2] = __builtin_amdgcn_mfma_f32_16x16x32_bf16(pf[1], vf, acc[1][c2], 0, 0, 0);
      }
      acc[0][12] = __builtin_amdgcn_mfma_f32_16x16x32_bf16(pf[0], vones, acc[0][12], 0, 0, 0);
      acc[1][12] = __builtin_amdgcn_mfma_f32_16x16x32_bf16(pf[1], vones, acc[1][12], 0, 0, 0);
      __builtin_amdgcn_s_setprio(0);
    }
    cur ^= 1;
  }

  // ---- epilogue ----
#pragma unroll
  for (int rf = 0; rf < 2; ++rf) {
    float rl[4];
#pragma unroll
    for (int r = 0; r < 4; ++r) rl[r] = 1.0f / __shfl(acc[rf][12][r], l & 48);
#pragma unroll
    for (int c2 = 0; c2 < 12; ++c2) {
#pragma unroll
      for (int r = 0; r < 4; ++r) {
        int i = wrow0 + rf * 16 + lg * 4 + r;
        size_t off = (size_t)(b * S_ + i) * QKD + h * DH_ + c2 * 16 + lr;
        attn[off] = (bf16_t)(acc[rf][c2][r] * rl[r]);
      }
    }
  }
}

// ---------------- launch ----------------
extern "C" void kernel_launch(void* const* d_in, const int* in_sizes, int n_in,
                              void* d_out, int out_size, void* d_ws, size_t ws_size,
                              hipStream_t stream) {
  const float* x        = (const float*)d_in[0];
  const float* w_qa     = (const float*)d_in[1];
  const float* q_norm_w = (const float*)d_in[2];
  const float* w_qb     = (const float*)d_in[3];
  const float* w_k      = (const float*)d_in[4];
  const float* w_v      = (const float*)d_in[5];
  const float* w_o      = (const float*)d_in[6];
  const float* attn_sink= (const float*)d_in[7];
  float* out = (float*)d_out;

  char* ws = (char*)d_ws;
  size_t off = 0;
  auto alloc = [&](size_t bytes) -> void* {
    void* p = ws + off;
    off += (bytes + 255) & ~(size_t)255;
    return p;
  };
  bf16_t* q_b  = (bf16_t*)alloc((size_t)NROWS * QKD * 2);
  bf16_t* k_b  = (bf16_t*)alloc((size_t)NROWS * DH_ * 2);
  bf16_t* vt_b = (bf16_t*)alloc((size_t)DH_ * NROWS * 2);
  bf16_t* wo_t = (bf16_t*)alloc((size_t)HID_ * QKD * 2);   // w_o^T [2048][3072]
  size_t temp_start = off;
  bf16_t* xb    = (bf16_t*)alloc((size_t)NROWS * HID_ * 2);
  bf16_t* wqa_t = (bf16_t*)alloc((size_t)QL_ * HID_ * 2);  // [512][2048]
  bf16_t* wqb_t = (bf16_t*)alloc((size_t)QKD * QL_ * 2);   // [3072][512]
  bf16_t* wkv_t = (bf16_t*)alloc((size_t)(2 * DH_) * HID_ * 2); // [384][2048]
  bf16_t* qa_b  = (bf16_t*)alloc((size_t)NROWS * QL_ * 2);
  bf16_t* attn_b = (bf16_t*)(ws + temp_start);             // overlays dead temps

  const float SCALE2 = 0.10411754646447386f;  // 192^-0.5 * log2(e)

  int n4x = (int)((size_t)NROWS * HID_ / 4);
  cast_f32_to_bf16<<<dim3((n4x + 255) / 256), dim3(256), 0, stream>>>(x, xb, n4x);
  transpose_all<<<dim3(9472), dim3(256), 0, stream>>>(
      w_qa, w_qb, w_k, w_v, w_o,
      wqa_t, wqb_t, wkv_t, wkv_t + (size_t)DH_ * HID_, wo_t);

  // q_a = rmsnorm(x @ w_qa)   [64x128 tile: 256 blocks]
  gemm64x128_kernel<1><<<dim3(QL_ / 128, NROWS / 64), 256, 0, stream>>>(xb, wqa_t, qa_b, NROWS, QL_, HID_, 1.0f);
  rmsnorm_kernel<<<dim3(NROWS), dim3(64), 0, stream>>>(qa_b, q_norm_w);
  // q = (q_a @ w_qb) * SCALE2  [128 tile: 768 blocks]
  gemm128_kernel<1><<<dim3(QKD / 128, NROWS / 128), 256, 0, stream>>>(qa_b, wqb_t, q_b, NROWS, QKD, QL_, SCALE2);
  // k + v^T in one launch
  gemm_kv_kernel<<<dim3((2 * DH_) / BN, NROWS / BM), 256, 0, stream>>>(xb, wkv_t, k_b, vt_b);
  // fused rope (q then k)
  {
    int total = NROWS * (H_ + 1) * 32;
    rope_kernel<<<dim3((total + 255) / 256), dim3(256), 0, stream>>>(q_b, k_b);
  }
  attn_kernel<<<dim3(512), dim3(256), 0, stream>>>(q_b, k_b, vt_b, attn_sink, attn_b);
  // out = attn @ w_o          [128x128 tile: 512 blocks — LDS-efficient m97 structure]
  gemm128_kernel<0><<<dim3(HID_ / 128, NROWS / 128), 256, 0, stream>>>(attn_b, wo_t, out, NROWS, HID_, QKD, 1.0f);
}

// Round 17
// 257.479 us; speedup vs baseline: 1.2242x; 1.1159x over previous
//
#include <hip/hip_runtime.h>
#include <hip/hip_bf16.h>

typedef __bf16 bf16_t;
typedef __bf16 bf16x8 __attribute__((ext_vector_type(8)));
typedef __bf16 bf16x4 __attribute__((ext_vector_type(4)));
typedef float  f32x4  __attribute__((ext_vector_type(4)));
typedef __attribute__((address_space(3))) unsigned int lds_u32_t;
typedef __attribute__((address_space(1))) const unsigned int glb_u32_t;

#define B_    2
#define S_    2048
#define HID_  2048
#define H_    16
#define DH_   192
#define DR_   64
#define DN_   128
#define QL_   512
#define NROWS (B_*S_)          // 4096
#define QKD   (H_*DH_)         // 3072

#if __has_builtin(__builtin_amdgcn_exp2f)
#define EXP2(x) __builtin_amdgcn_exp2f(x)
#else
#define EXP2(x) exp2f(x)
#endif

// XCD-aware bijective block swizzle (requires nwg % 8 == 0).
__device__ inline void xcd_remap(int& bx, int& by) {
  const int gx = gridDim.x;
  const int nwg = gx * gridDim.y;
  const int flat = by * gx + bx;
  const int q = nwg >> 3;
  const int nf = (flat & 7) * q + (flat >> 3);
  bx = nf % gx;
  by = nf / gx;
}

// ---------------- cast f32 -> bf16 (vec4) ----------------
__global__ void cast_f32_to_bf16(const float* __restrict__ in, bf16_t* __restrict__ out, int n4) {
  int i = blockIdx.x * blockDim.x + threadIdx.x;
  if (i >= n4) return;
  const float4 v = reinterpret_cast<const float4*>(in)[i];
  bf16x4 r;
  r[0] = (bf16_t)v.x; r[1] = (bf16_t)v.y; r[2] = (bf16_t)v.z; r[3] = (bf16_t)v.w;
  reinterpret_cast<bf16x4*>(out)[i] = r;
}

// ---------------- all 5 weight transposes in one launch ----------------
__global__ __launch_bounds__(256) void transpose_all(
    const float* __restrict__ i0, const float* __restrict__ i1,
    const float* __restrict__ i2, const float* __restrict__ i3,
    const float* __restrict__ i4,
    bf16_t* __restrict__ o0, bf16_t* __restrict__ o1, bf16_t* __restrict__ o2,
    bf16_t* __restrict__ o3, bf16_t* __restrict__ o4) {
  int id = blockIdx.x;
  const float* in; bf16_t* out; int R, C, lid;
  if (id < 1024)      { in = i0; out = o0; R = 2048; C = 512;  lid = id; }
  else if (id < 2560) { in = i1; out = o1; R = 512;  C = 3072; lid = id - 1024; }
  else if (id < 2944) { in = i2; out = o2; R = 2048; C = 192;  lid = id - 2560; }
  else if (id < 3328) { in = i3; out = o3; R = 2048; C = 192;  lid = id - 2944; }
  else                { in = i4; out = o4; R = 3072; C = 2048; lid = id - 3328; }
  const int cw = C >> 5;
  const int c0 = (lid % cw) * 32, r0 = (lid / cw) * 32;
  __shared__ float t[32][33];
  const int tx = threadIdx.x & 31;
  const int ty = threadIdx.x >> 5;
#pragma unroll
  for (int j = 0; j < 4; ++j)
    t[ty + j * 8][tx] = in[(size_t)(r0 + ty + j * 8) * C + c0 + tx];
  __syncthreads();
#pragma unroll
  for (int j = 0; j < 4; ++j)
    out[(size_t)(c0 + ty + j * 8) * R + r0 + tx] = (bf16_t)t[tx][ty + j * 8];
}

// ---------------- merged K/V GEMM (64x64 tile, m97 staging), B^T input -------
// A[4096][2048] * wkv^T[384][2048]^T -> cols 0..191: K row-major;
// cols 192..383: V^T. 4 waves 2x2, each 32x32. global_load_lds + XOR swizzle.
#define BM 64
#define BN 64

__global__ __launch_bounds__(256) void gemm_kv_kernel(
    const bf16_t* __restrict__ A, const bf16_t* __restrict__ BT,
    bf16_t* __restrict__ Kout, bf16_t* __restrict__ VTout) {
  __shared__ __align__(16) bf16_t sA[64 * 64];   // 8KB, swizzled chunks
  __shared__ __align__(16) bf16_t sB[64 * 64];   // 8KB
  const int tid = threadIdx.x;
  const int w  = tid >> 6;
  const int l  = tid & 63;
  const int lg = l >> 4, lr = l & 15;
  const int wm = w >> 1, wn = w & 1;             // 2x2 waves, 32x32 each
  int bx = blockIdx.x, by = blockIdx.y;
  xcd_remap(bx, by);
  const int m0 = by * BM, n0 = bx * BN;
  const int K = HID_;

  size_t aoff[2], boff[2];
  int ldso[2];
#pragma unroll
  for (int i = 0; i < 2; ++i) {
    int cid = i * 256 + tid;            // 0..511 chunk id
    int row = cid >> 3, ch = cid & 7;
    int sch = ch ^ (row & 7);
    aoff[i] = (size_t)(m0 + row) * K + sch * 8;
    boff[i] = (size_t)(n0 + row) * K + sch * 8;
    ldso[i] = (i * 256 + w * 64) * 8;   // wave-uniform base (elems)
  }

  f32x4 acc[2][2];
#pragma unroll
  for (int mi = 0; mi < 2; ++mi)
#pragma unroll
    for (int ni = 0; ni < 2; ++ni) acc[mi][ni] = f32x4{0.f, 0.f, 0.f, 0.f};

  for (int k0 = 0; k0 < K; k0 += 64) {
#pragma unroll
    for (int i = 0; i < 2; ++i) {
      __builtin_amdgcn_global_load_lds((glb_u32_t*)(A + aoff[i] + k0),
                                       (lds_u32_t*)(sA + ldso[i]), 16, 0, 0);
      __builtin_amdgcn_global_load_lds((glb_u32_t*)(BT + boff[i] + k0),
                                       (lds_u32_t*)(sB + ldso[i]), 16, 0, 0);
    }
    asm volatile("s_waitcnt vmcnt(0)" ::: "memory");
    __syncthreads();

#pragma unroll
    for (int ks = 0; ks < 2; ++ks) {
      bf16x8 af[2], bfr[2];
#pragma unroll
      for (int mi = 0; mi < 2; ++mi) {
        int row = wm * 32 + mi * 16 + lr;
        af[mi] = *reinterpret_cast<const bf16x8*>(
            sA + row * 64 + (((ks * 4 + lg) ^ (row & 7)) << 3));
      }
#pragma unroll
      for (int ni = 0; ni < 2; ++ni) {
        int row = wn * 32 + ni * 16 + lr;
        bfr[ni] = *reinterpret_cast<const bf16x8*>(
            sB + row * 64 + (((ks * 4 + lg) ^ (row & 7)) << 3));
      }
#pragma unroll
      for (int mi = 0; mi < 2; ++mi)
#pragma unroll
        for (int ni = 0; ni < 2; ++ni)
          acc[mi][ni] = __builtin_amdgcn_mfma_f32_16x16x32_bf16(af[mi], bfr[ni], acc[mi][ni], 0, 0, 0);
    }
    __syncthreads();
  }

#pragma unroll
  for (int mi = 0; mi < 2; ++mi) {
#pragma unroll
    for (int ni = 0; ni < 2; ++ni) {
#pragma unroll
      for (int r = 0; r < 4; ++r) {
        int row = m0 + wm * 32 + mi * 16 + lg * 4 + r;
        int col = n0 + wn * 32 + ni * 16 + lr;
        float v = acc[mi][ni][r];
        if (col < DH_) Kout[(size_t)row * DH_ + col] = (bf16_t)v;
        else           VTout[(size_t)(col - DH_) * NROWS + row] = (bf16_t)v;
      }
    }
  }
}

// ---------------- big bf16 MFMA GEMM (128x128x64 tile, m97 structure) --------
template<int OMODE>
__global__ __launch_bounds__(256) void gemm128_kernel(
    const bf16_t* __restrict__ A, const bf16_t* __restrict__ BT,
    void* __restrict__ C, int M, int N, int K, float oscale) {
  __shared__ __align__(16) bf16_t sA[128 * 64];
  __shared__ __align__(16) bf16_t sB[128 * 64];
  const int tid = threadIdx.x;
  const int w  = tid >> 6;
  const int l  = tid & 63;
  const int lg = l >> 4, lr = l & 15;
  const int wm = w >> 1, wn = w & 1;
  int bx = blockIdx.x, by = blockIdx.y;
  xcd_remap(bx, by);
  const int m0 = by * 128, n0 = bx * 128;

  size_t aoff[4], boff[4];
  int ldsoff[4];
#pragma unroll
  for (int i = 0; i < 4; ++i) {
    int cid = i * 256 + tid;
    int row = cid >> 3, ch = cid & 7;
    int sch = ch ^ (row & 7);
    aoff[i] = (size_t)(m0 + row) * K + sch * 8;
    boff[i] = (size_t)(n0 + row) * K + sch * 8;
    ldsoff[i] = (i * 256 + w * 64) * 8;
  }

  f32x4 acc[4][4];
#pragma unroll
  for (int mi = 0; mi < 4; ++mi)
#pragma unroll
    for (int ni = 0; ni < 4; ++ni) acc[mi][ni] = f32x4{0.f, 0.f, 0.f, 0.f};

  for (int k0 = 0; k0 < K; k0 += 64) {
#pragma unroll
    for (int i = 0; i < 4; ++i) {
      __builtin_amdgcn_global_load_lds((glb_u32_t*)(A + aoff[i] + k0),
                                       (lds_u32_t*)(sA + ldsoff[i]), 16, 0, 0);
      __builtin_amdgcn_global_load_lds((glb_u32_t*)(BT + boff[i] + k0),
                                       (lds_u32_t*)(sB + ldsoff[i]), 16, 0, 0);
    }
    asm volatile("s_waitcnt vmcnt(0)" ::: "memory");
    __syncthreads();

#pragma unroll
    for (int ks = 0; ks < 2; ++ks) {
      bf16x8 af[4], bfr[4];
#pragma unroll
      for (int mi = 0; mi < 4; ++mi) {
        int row = wm * 64 + mi * 16 + lr;
        af[mi] = *reinterpret_cast<const bf16x8*>(
            sA + row * 64 + (((ks * 4 + lg) ^ (row & 7)) << 3));
      }
#pragma unroll
      for (int ni = 0; ni < 4; ++ni) {
        int row = wn * 64 + ni * 16 + lr;
        bfr[ni] = *reinterpret_cast<const bf16x8*>(
            sB + row * 64 + (((ks * 4 + lg) ^ (row & 7)) << 3));
      }
#pragma unroll
      for (int mi = 0; mi < 4; ++mi)
#pragma unroll
        for (int ni = 0; ni < 4; ++ni)
          acc[mi][ni] = __builtin_amdgcn_mfma_f32_16x16x32_bf16(af[mi], bfr[ni], acc[mi][ni], 0, 0, 0);
    }
    __syncthreads();
  }

#pragma unroll
  for (int mi = 0; mi < 4; ++mi) {
#pragma unroll
    for (int ni = 0; ni < 4; ++ni) {
#pragma unroll
      for (int r = 0; r < 4; ++r) {
        int row = m0 + wm * 64 + mi * 16 + lg * 4 + r;
        int col = n0 + wn * 64 + ni * 16 + lr;
        float v = acc[mi][ni][r];
        if (OMODE == 0) ((float*)C)[(size_t)row * N + col]  = v;
        else            ((bf16_t*)C)[(size_t)row * N + col] = (bf16_t)(v * oscale);
      }
    }
  }
}

// ---------------- 64x128x64-tile GEMM (m97 structure), B^T input --------------
template<int OMODE>
__global__ __launch_bounds__(256) void gemm64x128_kernel(
    const bf16_t* __restrict__ A, const bf16_t* __restrict__ BT,
    void* __restrict__ C, int M, int N, int K, float oscale) {
  __shared__ __align__(16) bf16_t sA[64 * 64];    // 8KB
  __shared__ __align__(16) bf16_t sB[128 * 64];   // 16KB
  const int tid = threadIdx.x;
  const int w  = tid >> 6;
  const int l  = tid & 63;
  const int lg = l >> 4, lr = l & 15;
  const int wm = w >> 1, wn = w & 1;
  int bx = blockIdx.x, by = blockIdx.y;
  xcd_remap(bx, by);
  const int m0 = by * 64, n0 = bx * 128;

  size_t aoff[2], boff[4];
  int ldsa[2], ldsb[4];
#pragma unroll
  for (int i = 0; i < 2; ++i) {
    int cid = i * 256 + tid;
    int row = cid >> 3, ch = cid & 7;
    aoff[i] = (size_t)(m0 + row) * K + (ch ^ (row & 7)) * 8;
    ldsa[i] = (i * 256 + w * 64) * 8;
  }
#pragma unroll
  for (int i = 0; i < 4; ++i) {
    int cid = i * 256 + tid;
    int row = cid >> 3, ch = cid & 7;
    boff[i] = (size_t)(n0 + row) * K + (ch ^ (row & 7)) * 8;
    ldsb[i] = (i * 256 + w * 64) * 8;
  }

  f32x4 acc[2][4];
#pragma unroll
  for (int mi = 0; mi < 2; ++mi)
#pragma unroll
    for (int ni = 0; ni < 4; ++ni) acc[mi][ni] = f32x4{0.f, 0.f, 0.f, 0.f};

  for (int k0 = 0; k0 < K; k0 += 64) {
#pragma unroll
    for (int i = 0; i < 2; ++i)
      __builtin_amdgcn_global_load_lds((glb_u32_t*)(A + aoff[i] + k0),
                                       (lds_u32_t*)(sA + ldsa[i]), 16, 0, 0);
#pragma unroll
    for (int i = 0; i < 4; ++i)
      __builtin_amdgcn_global_load_lds((glb_u32_t*)(BT + boff[i] + k0),
                                       (lds_u32_t*)(sB + ldsb[i]), 16, 0, 0);
    asm volatile("s_waitcnt vmcnt(0)" ::: "memory");
    __syncthreads();

#pragma unroll
    for (int ks = 0; ks < 2; ++ks) {
      bf16x8 af[2], bfr[4];
#pragma unroll
      for (int mi = 0; mi < 2; ++mi) {
        int row = wm * 32 + mi * 16 + lr;
        af[mi] = *reinterpret_cast<const bf16x8*>(
            sA + row * 64 + (((ks * 4 + lg) ^ (row & 7)) << 3));
      }
#pragma unroll
      for (int ni = 0; ni < 4; ++ni) {
        int row = wn * 64 + ni * 16 + lr;
        bfr[ni] = *reinterpret_cast<const bf16x8*>(
            sB + row * 64 + (((ks * 4 + lg) ^ (row & 7)) << 3));
      }
#pragma unroll
      for (int mi = 0; mi < 2; ++mi)
#pragma unroll
        for (int ni = 0; ni < 4; ++ni)
          acc[mi][ni] = __builtin_amdgcn_mfma_f32_16x16x32_bf16(af[mi], bfr[ni], acc[mi][ni], 0, 0, 0);
    }
    __syncthreads();
  }

#pragma unroll
  for (int mi = 0; mi < 2; ++mi) {
#pragma unroll
    for (int ni = 0; ni < 4; ++ni) {
#pragma unroll
      for (int r = 0; r < 4; ++r) {
        int row = m0 + wm * 32 + mi * 16 + lg * 4 + r;
        int col = n0 + wn * 64 + ni * 16 + lr;
        float v = acc[mi][ni][r];
        if (OMODE == 0) ((float*)C)[(size_t)row * N + col]  = v;
        else            ((bf16_t*)C)[(size_t)row * N + col] = (bf16_t)(v * oscale);
      }
    }
  }
}

// ---------------- RMSNorm (in-place, one wave per row of 512) ----------------
__global__ __launch_bounds__(64) void rmsnorm_kernel(bf16_t* __restrict__ qa,
                                                     const float* __restrict__ wnorm) {
  int row = blockIdx.x;
  int l = threadIdx.x;
  bf16x8 v = *reinterpret_cast<const bf16x8*>(&qa[(size_t)row * QL_ + l * 8]);
  float f[8];
  float ss = 0.f;
#pragma unroll
  for (int e = 0; e < 8; ++e) { f[e] = (float)v[e]; ss += f[e] * f[e]; }
#pragma unroll
  for (int off = 32; off >= 1; off >>= 1) ss += __shfl_xor(ss, off);
  float rstd = rsqrtf(ss * (1.0f / 512.0f) + 1e-6f);
  bf16x8 o;
#pragma unroll
  for (int e = 0; e < 8; ++e) o[e] = (bf16_t)(f[e] * rstd * wnorm[l * 8 + e]);
  *reinterpret_cast<bf16x8*>(&qa[(size_t)row * QL_ + l * 8]) = o;
}

// ---------------- RoPE (q and k fused in one launch) ----------------
__global__ void rope_kernel(bf16_t* __restrict__ q, bf16_t* __restrict__ k) {
  int idx = blockIdx.x * blockDim.x + threadIdx.x;
  const int NQ = NROWS * H_ * 32;
  if (idx < NQ) {
    int d   = idx & 31;
    int h   = (idx >> 5) & 15;
    int row = idx >> 9;
    int s = row & (S_ - 1);
    float freq = (float)s * expf(-(float)d * (9.210340371976184f / 32.0f));
    float sn, cs;
    sincosf(freq, &sn, &cs);
    size_t base = (size_t)row * QKD + h * DH_ + DN_ + d;
    float q1 = (float)q[base], q2 = (float)q[base + 32];
    q[base]      = (bf16_t)(q1 * cs - q2 * sn);
    q[base + 32] = (bf16_t)(q2 * cs + q1 * sn);
  } else {
    int i2 = idx - NQ;
    if (i2 >= NROWS * 32) return;
    int d   = i2 & 31;
    int row = i2 >> 5;
    int s = row & (S_ - 1);
    float freq = (float)s * expf(-(float)d * (9.210340371976184f / 32.0f));
    float sn, cs;
    sincosf(freq, &sn, &cs);
    size_t base = (size_t)row * DH_ + DN_ + d;
    float k1 = (float)k[base], k2 = (float)k[base + 32];
    k[base]      = (bf16_t)(k1 * cs - k2 * sn);
    k[base + 32] = (bf16_t)(k2 * cs + k1 * sn);
  }
}

// ---------------- causal flash attention with sink (r12 core + setprio) ------
#define KB32  32
#define SPLD  40

__global__ __launch_bounds__(256, 2) void attn_kernel(
    const bf16_t* __restrict__ q, const bf16_t* __restrict__ k,
    const bf16_t* __restrict__ vt, const float* __restrict__ sink,
    bf16_t* __restrict__ attn) {
  __shared__ __align__(16) bf16_t sK[2][KB32 * DH_];   // 24KB dbuf
  __shared__ __align__(16) bf16_t sV[DH_ * KB32];      // 12KB single
  __shared__ __align__(16) bf16_t sP[4][32][SPLD];     // 10KB
  const int tid = threadIdx.x;
  const int w  = tid >> 6;
  const int l  = tid & 63;
  const int lg = l >> 4, lr = l & 15;
  const int qx = blockIdx.x >> 5;
  const int qt = (qx < 8) ? (15 - qx) : (qx - 8);  // heavy first
  const int bh = blockIdx.x & 31;
  const int b  = bh >> 4, h = bh & 15;
  const int wrow0 = qt * 128 + w * 32;
  const int ktmax_w = 4 * qt + w;
  const int ktmax_b = 4 * qt + 3;

  const bf16_t* kb  = k  + (size_t)(b * S_) * DH_;
  const bf16_t* vtb = vt + (size_t)(b * S_);

  int koff[3], voff[3], ldst[3];
#pragma unroll
  for (int i = 0; i < 3; ++i) {
    int g = i * 256 + tid;
    int krow = g / 24, kch = g - krow * 24;
    koff[i] = krow * DH_ + ((kch ^ (krow & 7)) << 3);
    int vrow = g >> 2, vch = g & 3;
    voff[i] = vrow * NROWS + ((vch ^ (vrow & 3)) << 3);
    ldst[i] = (i * 256 + w * 64) * 8;
  }

  auto stageK = [&](int kt, int bu) {
    const bf16_t* ksrc = kb + (size_t)kt * KB32 * DH_;
#pragma unroll
    for (int i = 0; i < 3; ++i)
      __builtin_amdgcn_global_load_lds((glb_u32_t*)(ksrc + koff[i]),
                                       (lds_u32_t*)(&sK[bu][0] + ldst[i]), 16, 0, 0);
  };
  auto stageV = [&](int kt) {
    const bf16_t* vsrc = vtb + kt * KB32;
#pragma unroll
    for (int i = 0; i < 3; ++i)
      __builtin_amdgcn_global_load_lds((glb_u32_t*)(vsrc + voff[i]),
                                       (lds_u32_t*)(sV + ldst[i]), 16, 0, 0);
  };

  bf16x8 qf[2][6];
#pragma unroll
  for (int rf = 0; rf < 2; ++rf) {
    size_t rowoff = (size_t)(b * S_ + wrow0 + rf * 16 + lr) * QKD + h * DH_;
#pragma unroll
    for (int ks = 0; ks < 6; ++ks)
      qf[rf][ks] = *reinterpret_cast<const bf16x8*>(&q[rowoff + ks * 32 + lg * 8]);
  }

  bf16x8 vones;
#pragma unroll
  for (int e = 0; e < 8; ++e) vones[e] = (bf16_t)((lr == 0) ? 1.0f : 0.0f);

  f32x4 acc[2][13];
#pragma unroll
  for (int rf = 0; rf < 2; ++rf) {
#pragma unroll
    for (int c = 0; c < 12; ++c) acc[rf][c] = f32x4{0.f, 0.f, 0.f, 0.f};
    float init = (lr == 0) ? 1.0f : 0.0f;
    acc[rf][12] = f32x4{init, init, init, init};
  }

  const float L2E = 1.4426950408889634f;
  float m[2][4];
  float sk2 = sink[h] * L2E;
#pragma unroll
  for (int rf = 0; rf < 2; ++rf)
#pragma unroll
    for (int r = 0; r < 4; ++r) m[rf][r] = sk2;

  stageK(0, 0);
  int cur = 0;

  for (int kt = 0; kt <= ktmax_b; ++kt) {
    __syncthreads();                 // all waves done PV(kt-1): sV free; sK[cur^1] free

    stageV(kt);                      // must land before PV(kt)
    const bool more = (kt < ktmax_b);
    if (more) stageK(kt + 1, cur ^ 1);

    if (kt <= ktmax_w) {
      if (more) { asm volatile("s_waitcnt vmcnt(6)" ::: "memory"); }
      else      { asm volatile("s_waitcnt vmcnt(3)" ::: "memory"); }

      f32x4 sc[2][2];
#pragma unroll
      for (int rf = 0; rf < 2; ++rf)
#pragma unroll
        for (int c = 0; c < 2; ++c) sc[rf][c] = f32x4{0.f, 0.f, 0.f, 0.f};
      __builtin_amdgcn_s_setprio(1);
#pragma unroll
      for (int c = 0; c < 2; ++c) {
        const int row = c * 16 + lr;
        const int rx  = row & 7;
        const bf16_t* kr = &sK[cur][0] + row * DH_;
#pragma unroll
        for (int ks = 0; ks < 6; ++ks) {
          bf16x8 kf = *reinterpret_cast<const bf16x8*>(kr + (((ks * 4 + lg) ^ rx) << 3));
          sc[0][c] = __builtin_amdgcn_mfma_f32_16x16x32_bf16(qf[0][ks], kf, sc[0][c], 0, 0, 0);
          sc[1][c] = __builtin_amdgcn_mfma_f32_16x16x32_bf16(qf[1][ks], kf, sc[1][c], 0, 0, 0);
        }
      }
      __builtin_amdgcn_s_setprio(0);

      if (kt == ktmax_w) {
#pragma unroll
        for (int rf = 0; rf < 2; ++rf)
#pragma unroll
          for (int c = 0; c < 2; ++c)
#pragma unroll
            for (int r = 0; r < 4; ++r)
              if ((kt * 32 + c * 16 + lr) > (wrow0 + rf * 16 + lg * 4 + r))
                sc[rf][c][r] = -1e30f;
      }

      int ok = 1;
      float lmax[2][4];
#pragma unroll
      for (int rf = 0; rf < 2; ++rf)
#pragma unroll
        for (int r = 0; r < 4; ++r) {
          lmax[rf][r] = fmaxf(sc[rf][0][r], sc[rf][1][r]);
          ok &= (lmax[rf][r] <= m[rf][r] + 8.0f);
        }
      if (!__all(ok)) {
#pragma unroll
        for (int rf = 0; rf < 2; ++rf) {
          float rmax[4], alpha[4];
#pragma unroll
          for (int r = 0; r < 4; ++r) rmax[r] = lmax[rf][r];
#pragma unroll
          for (int off = 1; off < 16; off <<= 1) {
#pragma unroll
            for (int r = 0; r < 4; ++r) rmax[r] = fmaxf(rmax[r], __shfl_xor(rmax[r], off));
          }
#pragma unroll
          for (int r = 0; r < 4; ++r) {
            float mn = fmaxf(m[rf][r], rmax[r]);
            alpha[r] = EXP2(m[rf][r] - mn);
            m[rf][r] = mn;
          }
#pragma unroll
          for (int c = 0; c < 13; ++c)
#pragma unroll
            for (int r = 0; r < 4; ++r) acc[rf][c][r] *= alpha[r];
        }
      }

#pragma unroll
      for (int rf = 0; rf < 2; ++rf)
#pragma unroll
        for (int c = 0; c < 2; ++c)
#pragma unroll
          for (int r = 0; r < 4; ++r)
            sP[w][rf * 16 + lg * 4 + r][c * 16 + lr] = (bf16_t)EXP2(sc[rf][c][r] - m[rf][r]);

      if (more) { asm volatile("s_waitcnt vmcnt(3)" ::: "memory"); }
      else      { asm volatile("s_waitcnt vmcnt(0)" ::: "memory"); }

      bf16x8 pf[2];
      pf[0] = *reinterpret_cast<const bf16x8*>(&sP[w][lr][lg * 8]);
      pf[1] = *reinterpret_cast<const bf16x8*>(&sP[w][16 + lr][lg * 8]);
      __builtin_amdgcn_s_setprio(1);
#pragma unroll
      for (int c2 = 0; c2 < 12; ++c2) {
        const int row = c2 * 16 + lr;
        bf16x8 vf = *reinterpret_cast<const bf16x8*>(
            sV + row * KB32 + ((lg ^ (row & 3)) << 3));
        acc[0][c2] = __builtin_amdgcn_mfma_f32_16x16x32_bf16(pf[0], vf, acc[0][c2], 0, 0, 0);
        acc[1][c2] = __builtin_amdgcn_mfma_f32_16x16x32_bf16(pf[1], vf, acc[1][c2], 0, 0, 0);
      }
      acc[0][12] = __builtin_amdgcn_mfma_f32_16x16x32_bf16(pf[0], vones, acc[0][12], 0, 0, 0);
      acc[1][12] = __builtin_amdgcn_mfma_f32_16x16x32_bf16(pf[1], vones, acc[1][12], 0, 0, 0);
      __builtin_amdgcn_s_setprio(0);
    }
    cur ^= 1;
  }

  // ---- epilogue ----
#pragma unroll
  for (int rf = 0; rf < 2; ++rf) {
    float rl[4];
#pragma unroll
    for (int r = 0; r < 4; ++r) rl[r] = 1.0f / __shfl(acc[rf][12][r], l & 48);
#pragma unroll
    for (int c2 = 0; c2 < 12; ++c2) {
#pragma unroll
      for (int r = 0; r < 4; ++r) {
        int i = wrow0 + rf * 16 + lg * 4 + r;
        size_t off = (size_t)(b * S_ + i) * QKD + h * DH_ + c2 * 16 + lr;
        attn[off] = (bf16_t)(acc[rf][c2][r] * rl[r]);
      }
    }
  }
}

// ---------------- launch ----------------
extern "C" void kernel_launch(void* const* d_in, const int* in_sizes, int n_in,
                              void* d_out, int out_size, void* d_ws, size_t ws_size,
                              hipStream_t stream) {
  const float* x        = (const float*)d_in[0];
  const float* w_qa     = (const float*)d_in[1];
  const float* q_norm_w = (const float*)d_in[2];
  const float* w_qb     = (const float*)d_in[3];
  const float* w_k      = (const float*)d_in[4];
  const float* w_v      = (const float*)d_in[5];
  const float* w_o      = (const float*)d_in[6];
  const float* attn_sink= (const float*)d_in[7];
  float* out = (float*)d_out;

  char* ws = (char*)d_ws;
  size_t off = 0;
  auto alloc = [&](size_t bytes) -> void* {
    void* p = ws + off;
    off += (bytes + 255) & ~(size_t)255;
    return p;
  };
  bf16_t* q_b  = (bf16_t*)alloc((size_t)NROWS * QKD * 2);
  bf16_t* k_b  = (bf16_t*)alloc((size_t)NROWS * DH_ * 2);
  bf16_t* vt_b = (bf16_t*)alloc((size_t)DH_ * NROWS * 2);
  bf16_t* wo_t = (bf16_t*)alloc((size_t)HID_ * QKD * 2);   // w_o^T [2048][3072]
  size_t temp_start = off;
  bf16_t* xb    = (bf16_t*)alloc((size_t)NROWS * HID_ * 2);
  bf16_t* wqa_t = (bf16_t*)alloc((size_t)QL_ * HID_ * 2);  // [512][2048]
  bf16_t* wqb_t = (bf16_t*)alloc((size_t)QKD * QL_ * 2);   // [3072][512]
  bf16_t* wkv_t = (bf16_t*)alloc((size_t)(2 * DH_) * HID_ * 2); // [384][2048]
  bf16_t* qa_b  = (bf16_t*)alloc((size_t)NROWS * QL_ * 2);
  bf16_t* attn_b = (bf16_t*)(ws + temp_start);             // overlays dead temps

  const float SCALE2 = 0.10411754646447386f;  // 192^-0.5 * log2(e)

  int n4x = (int)((size_t)NROWS * HID_ / 4);
  cast_f32_to_bf16<<<dim3((n4x + 255) / 256), dim3(256), 0, stream>>>(x, xb, n4x);
  transpose_all<<<dim3(9472), dim3(256), 0, stream>>>(
      w_qa, w_qb, w_k, w_v, w_o,
      wqa_t, wqb_t, wkv_t, wkv_t + (size_t)DH_ * HID_, wo_t);

  // q_a = rmsnorm(x @ w_qa)   [64x128 tile: 256 blocks]
  gemm64x128_kernel<1><<<dim3(QL_ / 128, NROWS / 64), 256, 0, stream>>>(xb, wqa_t, qa_b, NROWS, QL_, HID_, 1.0f);
  rmsnorm_kernel<<<dim3(NROWS), dim3(64), 0, stream>>>(qa_b, q_norm_w);
  // q = (q_a @ w_qb) * SCALE2  [128 tile: 768 blocks]
  gemm128_kernel<1><<<dim3(QKD / 128, NROWS / 128), 256, 0, stream>>>(qa_b, wqb_t, q_b, NROWS, QKD, QL_, SCALE2);
  // k + v^T in one launch    [64x64 m97 tile: 384 blocks]
  gemm_kv_kernel<<<dim3((2 * DH_) / BN, NROWS / BM), 256, 0, stream>>>(xb, wkv_t, k_b, vt_b);
  // fused rope (q then k)
  {
    int total = NROWS * (H_ + 1) * 32;
    rope_kernel<<<dim3((total + 255) / 256), dim3(256), 0, stream>>>(q_b, k_b);
  }
  attn_kernel<<<dim3(512), dim3(256), 0, stream>>>(q_b, k_b, vt_b, attn_sink, attn_b);
  // out = attn @ w_o          [128x128 tile: 512 blocks]
  gemm128_kernel<0><<<dim3(HID_ / 128, NROWS / 128), 256, 0, stream>>>(attn_b, wo_t, out, NROWS, HID_, QKD, 1.0f);
}

// Round 18
// 255.704 us; speedup vs baseline: 1.2327x; 1.0069x over previous
//
#include <hip/hip_runtime.h>
#include <hip/hip_bf16.h>

typedef __bf16 bf16_t;
typedef __bf16 bf16x8 __attribute__((ext_vector_type(8)));
typedef __bf16 bf16x4 __attribute__((ext_vector_type(4)));
typedef float  f32x4  __attribute__((ext_vector_type(4)));
typedef __attribute__((address_space(3))) unsigned int lds_u32_t;
typedef __attribute__((address_space(1))) const unsigned int glb_u32_t;

#define B_    2
#define S_    2048
#define HID_  2048
#define H_    16
#define DH_   192
#define DR_   64
#define DN_   128
#define QL_   512
#define NROWS (B_*S_)          // 4096
#define QKD   (H_*DH_)         // 3072

#if __has_builtin(__builtin_amdgcn_exp2f)
#define EXP2(x) __builtin_amdgcn_exp2f(x)
#else
#define EXP2(x) exp2f(x)
#endif

// XCD-aware bijective block swizzle (requires nwg % 8 == 0).
__device__ inline void xcd_remap(int& bx, int& by) {
  const int gx = gridDim.x;
  const int nwg = gx * gridDim.y;
  const int flat = by * gx + bx;
  const int q = nwg >> 3;
  const int nf = (flat & 7) * q + (flat >> 3);
  bx = nf % gx;
  by = nf / gx;
}

// ---------------- cast f32 -> bf16 (vec4) ----------------
__global__ void cast_f32_to_bf16(const float* __restrict__ in, bf16_t* __restrict__ out, int n4) {
  int i = blockIdx.x * blockDim.x + threadIdx.x;
  if (i >= n4) return;
  const float4 v = reinterpret_cast<const float4*>(in)[i];
  bf16x4 r;
  r[0] = (bf16_t)v.x; r[1] = (bf16_t)v.y; r[2] = (bf16_t)v.z; r[3] = (bf16_t)v.w;
  reinterpret_cast<bf16x4*>(out)[i] = r;
}

// ---------------- all 5 weight transposes in one launch ----------------
__global__ __launch_bounds__(256) void transpose_all(
    const float* __restrict__ i0, const float* __restrict__ i1,
    const float* __restrict__ i2, const float* __restrict__ i3,
    const float* __restrict__ i4,
    bf16_t* __restrict__ o0, bf16_t* __restrict__ o1, bf16_t* __restrict__ o2,
    bf16_t* __restrict__ o3, bf16_t* __restrict__ o4) {
  int id = blockIdx.x;
  const float* in; bf16_t* out; int R, C, lid;
  if (id < 1024)      { in = i0; out = o0; R = 2048; C = 512;  lid = id; }
  else if (id < 2560) { in = i1; out = o1; R = 512;  C = 3072; lid = id - 1024; }
  else if (id < 2944) { in = i2; out = o2; R = 2048; C = 192;  lid = id - 2560; }
  else if (id < 3328) { in = i3; out = o3; R = 2048; C = 192;  lid = id - 2944; }
  else                { in = i4; out = o4; R = 3072; C = 2048; lid = id - 3328; }
  const int cw = C >> 5;
  const int c0 = (lid % cw) * 32, r0 = (lid / cw) * 32;
  __shared__ float t[32][33];
  const int tx = threadIdx.x & 31;
  const int ty = threadIdx.x >> 5;
#pragma unroll
  for (int j = 0; j < 4; ++j)
    t[ty + j * 8][tx] = in[(size_t)(r0 + ty + j * 8) * C + c0 + tx];
  __syncthreads();
#pragma unroll
  for (int j = 0; j < 4; ++j)
    out[(size_t)(c0 + ty + j * 8) * R + r0 + tx] = (bf16_t)t[tx][ty + j * 8];
}

// ---------------- merged K/V GEMM (64x64 tile, m97 staging), B^T input -------
#define BM 64
#define BN 64

__global__ __launch_bounds__(256) void gemm_kv_kernel(
    const bf16_t* __restrict__ A, const bf16_t* __restrict__ BT,
    bf16_t* __restrict__ Kout, bf16_t* __restrict__ VTout) {
  __shared__ __align__(16) bf16_t sA[64 * 64];   // 8KB, swizzled chunks
  __shared__ __align__(16) bf16_t sB[64 * 64];   // 8KB
  const int tid = threadIdx.x;
  const int w  = tid >> 6;
  const int l  = tid & 63;
  const int lg = l >> 4, lr = l & 15;
  const int wm = w >> 1, wn = w & 1;             // 2x2 waves, 32x32 each
  int bx = blockIdx.x, by = blockIdx.y;
  xcd_remap(bx, by);
  const int m0 = by * BM, n0 = bx * BN;
  const int K = HID_;

  size_t aoff[2], boff[2];
  int ldso[2];
#pragma unroll
  for (int i = 0; i < 2; ++i) {
    int cid = i * 256 + tid;            // 0..511 chunk id
    int row = cid >> 3, ch = cid & 7;
    int sch = ch ^ (row & 7);
    aoff[i] = (size_t)(m0 + row) * K + sch * 8;
    boff[i] = (size_t)(n0 + row) * K + sch * 8;
    ldso[i] = (i * 256 + w * 64) * 8;   // wave-uniform base (elems)
  }

  f32x4 acc[2][2];
#pragma unroll
  for (int mi = 0; mi < 2; ++mi)
#pragma unroll
    for (int ni = 0; ni < 2; ++ni) acc[mi][ni] = f32x4{0.f, 0.f, 0.f, 0.f};

  for (int k0 = 0; k0 < K; k0 += 64) {
#pragma unroll
    for (int i = 0; i < 2; ++i) {
      __builtin_amdgcn_global_load_lds((glb_u32_t*)(A + aoff[i] + k0),
                                       (lds_u32_t*)(sA + ldso[i]), 16, 0, 0);
      __builtin_amdgcn_global_load_lds((glb_u32_t*)(BT + boff[i] + k0),
                                       (lds_u32_t*)(sB + ldso[i]), 16, 0, 0);
    }
    asm volatile("s_waitcnt vmcnt(0)" ::: "memory");
    __syncthreads();

#pragma unroll
    for (int ks = 0; ks < 2; ++ks) {
      bf16x8 af[2], bfr[2];
#pragma unroll
      for (int mi = 0; mi < 2; ++mi) {
        int row = wm * 32 + mi * 16 + lr;
        af[mi] = *reinterpret_cast<const bf16x8*>(
            sA + row * 64 + (((ks * 4 + lg) ^ (row & 7)) << 3));
      }
#pragma unroll
      for (int ni = 0; ni < 2; ++ni) {
        int row = wn * 32 + ni * 16 + lr;
        bfr[ni] = *reinterpret_cast<const bf16x8*>(
            sB + row * 64 + (((ks * 4 + lg) ^ (row & 7)) << 3));
      }
#pragma unroll
      for (int mi = 0; mi < 2; ++mi)
#pragma unroll
        for (int ni = 0; ni < 2; ++ni)
          acc[mi][ni] = __builtin_amdgcn_mfma_f32_16x16x32_bf16(af[mi], bfr[ni], acc[mi][ni], 0, 0, 0);
    }
    __syncthreads();
  }

#pragma unroll
  for (int mi = 0; mi < 2; ++mi) {
#pragma unroll
    for (int ni = 0; ni < 2; ++ni) {
#pragma unroll
      for (int r = 0; r < 4; ++r) {
        int row = m0 + wm * 32 + mi * 16 + lg * 4 + r;
        int col = n0 + wn * 32 + ni * 16 + lr;
        float v = acc[mi][ni][r];
        if (col < DH_) Kout[(size_t)row * DH_ + col] = (bf16_t)v;
        else           VTout[(size_t)(col - DH_) * NROWS + row] = (bf16_t)v;
      }
    }
  }
}

// ---------------- big bf16 MFMA GEMM (128x128x64 tile, m97 structure) --------
template<int OMODE>
__global__ __launch_bounds__(256) void gemm128_kernel(
    const bf16_t* __restrict__ A, const bf16_t* __restrict__ BT,
    void* __restrict__ C, int M, int N, int K, float oscale) {
  __shared__ __align__(16) bf16_t sA[128 * 64];
  __shared__ __align__(16) bf16_t sB[128 * 64];
  const int tid = threadIdx.x;
  const int w  = tid >> 6;
  const int l  = tid & 63;
  const int lg = l >> 4, lr = l & 15;
  const int wm = w >> 1, wn = w & 1;
  int bx = blockIdx.x, by = blockIdx.y;
  xcd_remap(bx, by);
  const int m0 = by * 128, n0 = bx * 128;

  size_t aoff[4], boff[4];
  int ldsoff[4];
#pragma unroll
  for (int i = 0; i < 4; ++i) {
    int cid = i * 256 + tid;
    int row = cid >> 3, ch = cid & 7;
    int sch = ch ^ (row & 7);
    aoff[i] = (size_t)(m0 + row) * K + sch * 8;
    boff[i] = (size_t)(n0 + row) * K + sch * 8;
    ldsoff[i] = (i * 256 + w * 64) * 8;
  }

  f32x4 acc[4][4];
#pragma unroll
  for (int mi = 0; mi < 4; ++mi)
#pragma unroll
    for (int ni = 0; ni < 4; ++ni) acc[mi][ni] = f32x4{0.f, 0.f, 0.f, 0.f};

  for (int k0 = 0; k0 < K; k0 += 64) {
#pragma unroll
    for (int i = 0; i < 4; ++i) {
      __builtin_amdgcn_global_load_lds((glb_u32_t*)(A + aoff[i] + k0),
                                       (lds_u32_t*)(sA + ldsoff[i]), 16, 0, 0);
      __builtin_amdgcn_global_load_lds((glb_u32_t*)(BT + boff[i] + k0),
                                       (lds_u32_t*)(sB + ldsoff[i]), 16, 0, 0);
    }
    asm volatile("s_waitcnt vmcnt(0)" ::: "memory");
    __syncthreads();

#pragma unroll
    for (int ks = 0; ks < 2; ++ks) {
      bf16x8 af[4], bfr[4];
#pragma unroll
      for (int mi = 0; mi < 4; ++mi) {
        int row = wm * 64 + mi * 16 + lr;
        af[mi] = *reinterpret_cast<const bf16x8*>(
            sA + row * 64 + (((ks * 4 + lg) ^ (row & 7)) << 3));
      }
#pragma unroll
      for (int ni = 0; ni < 4; ++ni) {
        int row = wn * 64 + ni * 16 + lr;
        bfr[ni] = *reinterpret_cast<const bf16x8*>(
            sB + row * 64 + (((ks * 4 + lg) ^ (row & 7)) << 3));
      }
#pragma unroll
      for (int mi = 0; mi < 4; ++mi)
#pragma unroll
        for (int ni = 0; ni < 4; ++ni)
          acc[mi][ni] = __builtin_amdgcn_mfma_f32_16x16x32_bf16(af[mi], bfr[ni], acc[mi][ni], 0, 0, 0);
    }
    __syncthreads();
  }

#pragma unroll
  for (int mi = 0; mi < 4; ++mi) {
#pragma unroll
    for (int ni = 0; ni < 4; ++ni) {
#pragma unroll
      for (int r = 0; r < 4; ++r) {
        int row = m0 + wm * 64 + mi * 16 + lg * 4 + r;
        int col = n0 + wn * 64 + ni * 16 + lr;
        float v = acc[mi][ni][r];
        if (OMODE == 0) ((float*)C)[(size_t)row * N + col]  = v;
        else            ((bf16_t*)C)[(size_t)row * N + col] = (bf16_t)(v * oscale);
      }
    }
  }
}

// ---------------- 64x128x64-tile GEMM (m97 structure), B^T input --------------
template<int OMODE>
__global__ __launch_bounds__(256) void gemm64x128_kernel(
    const bf16_t* __restrict__ A, const bf16_t* __restrict__ BT,
    void* __restrict__ C, int M, int N, int K, float oscale) {
  __shared__ __align__(16) bf16_t sA[64 * 64];    // 8KB
  __shared__ __align__(16) bf16_t sB[128 * 64];   // 16KB
  const int tid = threadIdx.x;
  const int w  = tid >> 6;
  const int l  = tid & 63;
  const int lg = l >> 4, lr = l & 15;
  const int wm = w >> 1, wn = w & 1;
  int bx = blockIdx.x, by = blockIdx.y;
  xcd_remap(bx, by);
  const int m0 = by * 64, n0 = bx * 128;

  size_t aoff[2], boff[4];
  int ldsa[2], ldsb[4];
#pragma unroll
  for (int i = 0; i < 2; ++i) {
    int cid = i * 256 + tid;
    int row = cid >> 3, ch = cid & 7;
    aoff[i] = (size_t)(m0 + row) * K + (ch ^ (row & 7)) * 8;
    ldsa[i] = (i * 256 + w * 64) * 8;
  }
#pragma unroll
  for (int i = 0; i < 4; ++i) {
    int cid = i * 256 + tid;
    int row = cid >> 3, ch = cid & 7;
    boff[i] = (size_t)(n0 + row) * K + (ch ^ (row & 7)) * 8;
    ldsb[i] = (i * 256 + w * 64) * 8;
  }

  f32x4 acc[2][4];
#pragma unroll
  for (int mi = 0; mi < 2; ++mi)
#pragma unroll
    for (int ni = 0; ni < 4; ++ni) acc[mi][ni] = f32x4{0.f, 0.f, 0.f, 0.f};

  for (int k0 = 0; k0 < K; k0 += 64) {
#pragma unroll
    for (int i = 0; i < 2; ++i)
      __builtin_amdgcn_global_load_lds((glb_u32_t*)(A + aoff[i] + k0),
                                       (lds_u32_t*)(sA + ldsa[i]), 16, 0, 0);
#pragma unroll
    for (int i = 0; i < 4; ++i)
      __builtin_amdgcn_global_load_lds((glb_u32_t*)(BT + boff[i] + k0),
                                       (lds_u32_t*)(sB + ldsb[i]), 16, 0, 0);
    asm volatile("s_waitcnt vmcnt(0)" ::: "memory");
    __syncthreads();

#pragma unroll
    for (int ks = 0; ks < 2; ++ks) {
      bf16x8 af[2], bfr[4];
#pragma unroll
      for (int mi = 0; mi < 2; ++mi) {
        int row = wm * 32 + mi * 16 + lr;
        af[mi] = *reinterpret_cast<const bf16x8*>(
            sA + row * 64 + (((ks * 4 + lg) ^ (row & 7)) << 3));
      }
#pragma unroll
      for (int ni = 0; ni < 4; ++ni) {
        int row = wn * 64 + ni * 16 + lr;
        bfr[ni] = *reinterpret_cast<const bf16x8*>(
            sB + row * 64 + (((ks * 4 + lg) ^ (row & 7)) << 3));
      }
#pragma unroll
      for (int mi = 0; mi < 2; ++mi)
#pragma unroll
        for (int ni = 0; ni < 4; ++ni)
          acc[mi][ni] = __builtin_amdgcn_mfma_f32_16x16x32_bf16(af[mi], bfr[ni], acc[mi][ni], 0, 0, 0);
    }
    __syncthreads();
  }

#pragma unroll
  for (int mi = 0; mi < 2; ++mi) {
#pragma unroll
    for (int ni = 0; ni < 4; ++ni) {
#pragma unroll
      for (int r = 0; r < 4; ++r) {
        int row = m0 + wm * 32 + mi * 16 + lg * 4 + r;
        int col = n0 + wn * 64 + ni * 16 + lr;
        float v = acc[mi][ni][r];
        if (OMODE == 0) ((float*)C)[(size_t)row * N + col]  = v;
        else            ((bf16_t*)C)[(size_t)row * N + col] = (bf16_t)(v * oscale);
      }
    }
  }
}

// ---------------- RMSNorm (in-place, one wave per row of 512) ----------------
__global__ __launch_bounds__(64) void rmsnorm_kernel(bf16_t* __restrict__ qa,
                                                     const float* __restrict__ wnorm) {
  int row = blockIdx.x;
  int l = threadIdx.x;
  bf16x8 v = *reinterpret_cast<const bf16x8*>(&qa[(size_t)row * QL_ + l * 8]);
  float f[8];
  float ss = 0.f;
#pragma unroll
  for (int e = 0; e < 8; ++e) { f[e] = (float)v[e]; ss += f[e] * f[e]; }
#pragma unroll
  for (int off = 32; off >= 1; off >>= 1) ss += __shfl_xor(ss, off);
  float rstd = rsqrtf(ss * (1.0f / 512.0f) + 1e-6f);
  bf16x8 o;
#pragma unroll
  for (int e = 0; e < 8; ++e) o[e] = (bf16_t)(f[e] * rstd * wnorm[l * 8 + e]);
  *reinterpret_cast<bf16x8*>(&qa[(size_t)row * QL_ + l * 8]) = o;
}

// ---------------- RoPE for K only (Q-rope fused into attn) ----------------
__global__ void rope_k_kernel(bf16_t* __restrict__ k) {
  int idx = blockIdx.x * blockDim.x + threadIdx.x;  // NROWS*32
  int d   = idx & 31;
  int row = idx >> 5;
  if (row >= NROWS) return;
  int s = row & (S_ - 1);
  float freq = (float)s * expf(-(float)d * (9.210340371976184f / 32.0f));
  float sn, cs;
  sincosf(freq, &sn, &cs);
  size_t base = (size_t)row * DH_ + DN_ + d;
  float k1 = (float)k[base], k2 = (float)k[base + 32];
  k[base]      = (bf16_t)(k1 * cs - k2 * sn);
  k[base + 32] = (bf16_t)(k2 * cs + k1 * sn);
}

// ---------------- causal flash attention with sink (r12 core + setprio) ------
// Q-RoPE applied in-register at load (pair qf[4][e] <-> qf[5][e], once/block).
#define KB32  32
#define SPLD  40

__global__ __launch_bounds__(256, 2) void attn_kernel(
    const bf16_t* __restrict__ q, const bf16_t* __restrict__ k,
    const bf16_t* __restrict__ vt, const float* __restrict__ sink,
    bf16_t* __restrict__ attn) {
  __shared__ __align__(16) bf16_t sK[2][KB32 * DH_];   // 24KB dbuf
  __shared__ __align__(16) bf16_t sV[DH_ * KB32];      // 12KB single
  __shared__ __align__(16) bf16_t sP[4][32][SPLD];     // 10KB
  const int tid = threadIdx.x;
  const int w  = tid >> 6;
  const int l  = tid & 63;
  const int lg = l >> 4, lr = l & 15;
  const int qx = blockIdx.x >> 5;
  const int qt = (qx < 8) ? (15 - qx) : (qx - 8);  // heavy first
  const int bh = blockIdx.x & 31;
  const int b  = bh >> 4, h = bh & 15;
  const int wrow0 = qt * 128 + w * 32;
  const int ktmax_w = 4 * qt + w;
  const int ktmax_b = 4 * qt + 3;

  const bf16_t* kb  = k  + (size_t)(b * S_) * DH_;
  const bf16_t* vtb = vt + (size_t)(b * S_);

  int koff[3], voff[3], ldst[3];
#pragma unroll
  for (int i = 0; i < 3; ++i) {
    int g = i * 256 + tid;
    int krow = g / 24, kch = g - krow * 24;
    koff[i] = krow * DH_ + ((kch ^ (krow & 7)) << 3);
    int vrow = g >> 2, vch = g & 3;
    voff[i] = vrow * NROWS + ((vch ^ (vrow & 3)) << 3);
    ldst[i] = (i * 256 + w * 64) * 8;
  }

  auto stageK = [&](int kt, int bu) {
    const bf16_t* ksrc = kb + (size_t)kt * KB32 * DH_;
#pragma unroll
    for (int i = 0; i < 3; ++i)
      __builtin_amdgcn_global_load_lds((glb_u32_t*)(ksrc + koff[i]),
                                       (lds_u32_t*)(&sK[bu][0] + ldst[i]), 16, 0, 0);
  };
  auto stageV = [&](int kt) {
    const bf16_t* vsrc = vtb + kt * KB32;
#pragma unroll
    for (int i = 0; i < 3; ++i)
      __builtin_amdgcn_global_load_lds((glb_u32_t*)(vsrc + voff[i]),
                                       (lds_u32_t*)(sV + ldst[i]), 16, 0, 0);
  };

  bf16x8 qf[2][6];
#pragma unroll
  for (int rf = 0; rf < 2; ++rf) {
    size_t rowoff = (size_t)(b * S_ + wrow0 + rf * 16 + lr) * QKD + h * DH_;
#pragma unroll
    for (int ks = 0; ks < 6; ++ks)
      qf[rf][ks] = *reinterpret_cast<const bf16x8*>(&q[rowoff + ks * 32 + lg * 8]);
  }
  // ---- fused Q-RoPE: pair (128+j, 160+j), j = lg*8+e -> qf[4][e] <-> qf[5][e]
#pragma unroll
  for (int rf = 0; rf < 2; ++rf) {
    const float s = (float)(wrow0 + rf * 16 + lr);
#pragma unroll
    for (int e = 0; e < 8; ++e) {
      float invf = expf(-(float)(lg * 8 + e) * (9.210340371976184f / 32.0f));
      float sn, cs;
      sincosf(s * invf, &sn, &cs);
      float x1 = (float)qf[rf][4][e], x2 = (float)qf[rf][5][e];
      qf[rf][4][e] = (bf16_t)(x1 * cs - x2 * sn);
      qf[rf][5][e] = (bf16_t)(x2 * cs + x1 * sn);
    }
  }

  bf16x8 vones;
#pragma unroll
  for (int e = 0; e < 8; ++e) vones[e] = (bf16_t)((lr == 0) ? 1.0f : 0.0f);

  f32x4 acc[2][13];
#pragma unroll
  for (int rf = 0; rf < 2; ++rf) {
#pragma unroll
    for (int c = 0; c < 12; ++c) acc[rf][c] = f32x4{0.f, 0.f, 0.f, 0.f};
    float init = (lr == 0) ? 1.0f : 0.0f;
    acc[rf][12] = f32x4{init, init, init, init};
  }

  const float L2E = 1.4426950408889634f;
  float m[2][4];
  float sk2 = sink[h] * L2E;
#pragma unroll
  for (int rf = 0; rf < 2; ++rf)
#pragma unroll
    for (int r = 0; r < 4; ++r) m[rf][r] = sk2;

  stageK(0, 0);
  int cur = 0;

  for (int kt = 0; kt <= ktmax_b; ++kt) {
    __syncthreads();                 // all waves done PV(kt-1): sV free; sK[cur^1] free

    stageV(kt);                      // must land before PV(kt)
    const bool more = (kt < ktmax_b);
    if (more) stageK(kt + 1, cur ^ 1);

    if (kt <= ktmax_w) {
      if (more) { asm volatile("s_waitcnt vmcnt(6)" ::: "memory"); }
      else      { asm volatile("s_waitcnt vmcnt(3)" ::: "memory"); }

      f32x4 sc[2][2];
#pragma unroll
      for (int rf = 0; rf < 2; ++rf)
#pragma unroll
        for (int c = 0; c < 2; ++c) sc[rf][c] = f32x4{0.f, 0.f, 0.f, 0.f};
      __builtin_amdgcn_s_setprio(1);
#pragma unroll
      for (int c = 0; c < 2; ++c) {
        const int row = c * 16 + lr;
        const int rx  = row & 7;
        const bf16_t* kr = &sK[cur][0] + row * DH_;
#pragma unroll
        for (int ks = 0; ks < 6; ++ks) {
          bf16x8 kf = *reinterpret_cast<const bf16x8*>(kr + (((ks * 4 + lg) ^ rx) << 3));
          sc[0][c] = __builtin_amdgcn_mfma_f32_16x16x32_bf16(qf[0][ks], kf, sc[0][c], 0, 0, 0);
          sc[1][c] = __builtin_amdgcn_mfma_f32_16x16x32_bf16(qf[1][ks], kf, sc[1][c], 0, 0, 0);
        }
      }
      __builtin_amdgcn_s_setprio(0);

      if (kt == ktmax_w) {
#pragma unroll
        for (int rf = 0; rf < 2; ++rf)
#pragma unroll
          for (int c = 0; c < 2; ++c)
#pragma unroll
            for (int r = 0; r < 4; ++r)
              if ((kt * 32 + c * 16 + lr) > (wrow0 + rf * 16 + lg * 4 + r))
                sc[rf][c][r] = -1e30f;
      }

      int ok = 1;
      float lmax[2][4];
#pragma unroll
      for (int rf = 0; rf < 2; ++rf)
#pragma unroll
        for (int r = 0; r < 4; ++r) {
          lmax[rf][r] = fmaxf(sc[rf][0][r], sc[rf][1][r]);
          ok &= (lmax[rf][r] <= m[rf][r] + 8.0f);
        }
      if (!__all(ok)) {
#pragma unroll
        for (int rf = 0; rf < 2; ++rf) {
          float rmax[4], alpha[4];
#pragma unroll
          for (int r = 0; r < 4; ++r) rmax[r] = lmax[rf][r];
#pragma unroll
          for (int off = 1; off < 16; off <<= 1) {
#pragma unroll
            for (int r = 0; r < 4; ++r) rmax[r] = fmaxf(rmax[r], __shfl_xor(rmax[r], off));
          }
#pragma unroll
          for (int r = 0; r < 4; ++r) {
            float mn = fmaxf(m[rf][r], rmax[r]);
            alpha[r] = EXP2(m[rf][r] - mn);
            m[rf][r] = mn;
          }
#pragma unroll
          for (int c = 0; c < 13; ++c)
#pragma unroll
            for (int r = 0; r < 4; ++r) acc[rf][c][r] *= alpha[r];
        }
      }

#pragma unroll
      for (int rf = 0; rf < 2; ++rf)
#pragma unroll
        for (int c = 0; c < 2; ++c)
#pragma unroll
          for (int r = 0; r < 4; ++r)
            sP[w][rf * 16 + lg * 4 + r][c * 16 + lr] = (bf16_t)EXP2(sc[rf][c][r] - m[rf][r]);

      if (more) { asm volatile("s_waitcnt vmcnt(3)" ::: "memory"); }
      else      { asm volatile("s_waitcnt vmcnt(0)" ::: "memory"); }

      bf16x8 pf[2];
      pf[0] = *reinterpret_cast<const bf16x8*>(&sP[w][lr][lg * 8]);
      pf[1] = *reinterpret_cast<const bf16x8*>(&sP[w][16 + lr][lg * 8]);
      __builtin_amdgcn_s_setprio(1);
#pragma unroll
      for (int c2 = 0; c2 < 12; ++c2) {
        const int row = c2 * 16 + lr;
        bf16x8 vf = *reinterpret_cast<const bf16x8*>(
            sV + row * KB32 + ((lg ^ (row & 3)) << 3));
        acc[0][c2] = __builtin_amdgcn_mfma_f32_16x16x32_bf16(pf[0], vf, acc[0][c2], 0, 0, 0);
        acc[1][c2] = __builtin_amdgcn_mfma_f32_16x16x32_bf16(pf[1], vf, acc[1][c2], 0, 0, 0);
      }
      acc[0][12] = __builtin_amdgcn_mfma_f32_16x16x32_bf16(pf[0], vones, acc[0][12], 0, 0, 0);
      acc[1][12] = __builtin_amdgcn_mfma_f32_16x16x32_bf16(pf[1], vones, acc[1][12], 0, 0, 0);
      __builtin_amdgcn_s_setprio(0);
    }
    cur ^= 1;
  }

  // ---- epilogue ----
#pragma unroll
  for (int rf = 0; rf < 2; ++rf) {
    float rl[4];
#pragma unroll
    for (int r = 0; r < 4; ++r) rl[r] = 1.0f / __shfl(acc[rf][12][r], l & 48);
#pragma unroll
    for (int c2 = 0; c2 < 12; ++c2) {
#pragma unroll
      for (int r = 0; r < 4; ++r) {
        int i = wrow0 + rf * 16 + lg * 4 + r;
        size_t off = (size_t)(b * S_ + i) * QKD + h * DH_ + c2 * 16 + lr;
        attn[off] = (bf16_t)(acc[rf][c2][r] * rl[r]);
      }
    }
  }
}

// ---------------- launch ----------------
extern "C" void kernel_launch(void* const* d_in, const int* in_sizes, int n_in,
                              void* d_out, int out_size, void* d_ws, size_t ws_size,
                              hipStream_t stream) {
  const float* x        = (const float*)d_in[0];
  const float* w_qa     = (const float*)d_in[1];
  const float* q_norm_w = (const float*)d_in[2];
  const float* w_qb     = (const float*)d_in[3];
  const float* w_k      = (const float*)d_in[4];
  const float* w_v      = (const float*)d_in[5];
  const float* w_o      = (const float*)d_in[6];
  const float* attn_sink= (const float*)d_in[7];
  float* out = (float*)d_out;

  char* ws = (char*)d_ws;
  size_t off = 0;
  auto alloc = [&](size_t bytes) -> void* {
    void* p = ws + off;
    off += (bytes + 255) & ~(size_t)255;
    return p;
  };
  bf16_t* q_b  = (bf16_t*)alloc((size_t)NROWS * QKD * 2);
  bf16_t* k_b  = (bf16_t*)alloc((size_t)NROWS * DH_ * 2);
  bf16_t* vt_b = (bf16_t*)alloc((size_t)DH_ * NROWS * 2);
  bf16_t* wo_t = (bf16_t*)alloc((size_t)HID_ * QKD * 2);   // w_o^T [2048][3072]
  size_t temp_start = off;
  bf16_t* xb    = (bf16_t*)alloc((size_t)NROWS * HID_ * 2);
  bf16_t* wqa_t = (bf16_t*)alloc((size_t)QL_ * HID_ * 2);  // [512][2048]
  bf16_t* wqb_t = (bf16_t*)alloc((size_t)QKD * QL_ * 2);   // [3072][512]
  bf16_t* wkv_t = (bf16_t*)alloc((size_t)(2 * DH_) * HID_ * 2); // [384][2048]
  bf16_t* qa_b  = (bf16_t*)alloc((size_t)NROWS * QL_ * 2);
  bf16_t* attn_b = (bf16_t*)(ws + temp_start);             // overlays dead temps

  const float SCALE2 = 0.10411754646447386f;  // 192^-0.5 * log2(e)

  int n4x = (int)((size_t)NROWS * HID_ / 4);
  cast_f32_to_bf16<<<dim3((n4x + 255) / 256), dim3(256), 0, stream>>>(x, xb, n4x);
  transpose_all<<<dim3(9472), dim3(256), 0, stream>>>(
      w_qa, w_qb, w_k, w_v, w_o,
      wqa_t, wqb_t, wkv_t, wkv_t + (size_t)DH_ * HID_, wo_t);

  // q_a = rmsnorm(x @ w_qa)   [64x128 tile: 256 blocks]
  gemm64x128_kernel<1><<<dim3(QL_ / 128, NROWS / 64), 256, 0, stream>>>(xb, wqa_t, qa_b, NROWS, QL_, HID_, 1.0f);
  rmsnorm_kernel<<<dim3(NROWS), dim3(64), 0, stream>>>(qa_b, q_norm_w);
  // q = (q_a @ w_qb) * SCALE2  [128 tile: 768 blocks]
  gemm128_kernel<1><<<dim3(QKD / 128, NROWS / 128), 256, 0, stream>>>(qa_b, wqb_t, q_b, NROWS, QKD, QL_, SCALE2);
  // k + v^T in one launch    [64x64 m97 tile: 384 blocks]
  gemm_kv_kernel<<<dim3((2 * DH_) / BN, NROWS / BM), 256, 0, stream>>>(xb, wkv_t, k_b, vt_b);
  // K-RoPE only (Q-RoPE fused into attn)
  rope_k_kernel<<<dim3((NROWS * 32) / 256), dim3(256), 0, stream>>>(k_b);
  attn_kernel<<<dim3(512), dim3(256), 0, stream>>>(q_b, k_b, vt_b, attn_sink, attn_b);
  // out = attn @ w_o          [128x128 tile: 512 blocks]
  gemm128_kernel<0><<<dim3(HID_ / 128, NROWS / 128), 256, 0, stream>>>(attn_b, wo_t, out, NROWS, HID_, QKD, 1.0f);
}

// Round 19
// 253.597 us; speedup vs baseline: 1.2429x; 1.0083x over previous
//
#include <hip/hip_runtime.h>
#include <hip/hip_bf16.h>

typedef __bf16 bf16_t;
typedef __bf16 bf16x8 __attribute__((ext_vector_type(8)));
typedef __bf16 bf16x4 __attribute__((ext_vector_type(4)));
typedef float  f32x4  __attribute__((ext_vector_type(4)));
typedef __attribute__((address_space(3))) unsigned int lds_u32_t;
typedef __attribute__((address_space(1))) const unsigned int glb_u32_t;

#define B_    2
#define S_    2048
#define HID_  2048
#define H_    16
#define DH_   192
#define DR_   64
#define DN_   128
#define QL_   512
#define NROWS (B_*S_)          // 4096
#define QKD   (H_*DH_)         // 3072

#if __has_builtin(__builtin_amdgcn_exp2f)
#define EXP2(x) __builtin_amdgcn_exp2f(x)
#else
#define EXP2(x) exp2f(x)
#endif

// XCD-aware bijective block swizzle (requires nwg % 8 == 0).
__device__ inline void xcd_remap(int& bx, int& by) {
  const int gx = gridDim.x;
  const int nwg = gx * gridDim.y;
  const int flat = by * gx + bx;
  const int q = nwg >> 3;
  const int nf = (flat & 7) * q + (flat >> 3);
  bx = nf % gx;
  by = nf / gx;
}

// ---------------- cast f32 -> bf16 (vec4) ----------------
__global__ void cast_f32_to_bf16(const float* __restrict__ in, bf16_t* __restrict__ out, int n4) {
  int i = blockIdx.x * blockDim.x + threadIdx.x;
  if (i >= n4) return;
  const float4 v = reinterpret_cast<const float4*>(in)[i];
  bf16x4 r;
  r[0] = (bf16_t)v.x; r[1] = (bf16_t)v.y; r[2] = (bf16_t)v.z; r[3] = (bf16_t)v.w;
  reinterpret_cast<bf16x4*>(out)[i] = r;
}

// ---------------- all 5 weight transposes in one launch ----------------
__global__ __launch_bounds__(256) void transpose_all(
    const float* __restrict__ i0, const float* __restrict__ i1,
    const float* __restrict__ i2, const float* __restrict__ i3,
    const float* __restrict__ i4,
    bf16_t* __restrict__ o0, bf16_t* __restrict__ o1, bf16_t* __restrict__ o2,
    bf16_t* __restrict__ o3, bf16_t* __restrict__ o4) {
  int id = blockIdx.x;
  const float* in; bf16_t* out; int R, C, lid;
  if (id < 1024)      { in = i0; out = o0; R = 2048; C = 512;  lid = id; }
  else if (id < 2560) { in = i1; out = o1; R = 512;  C = 3072; lid = id - 1024; }
  else if (id < 2944) { in = i2; out = o2; R = 2048; C = 192;  lid = id - 2560; }
  else if (id < 3328) { in = i3; out = o3; R = 2048; C = 192;  lid = id - 2944; }
  else                { in = i4; out = o4; R = 3072; C = 2048; lid = id - 3328; }
  const int cw = C >> 5;
  const int c0 = (lid % cw) * 32, r0 = (lid / cw) * 32;
  __shared__ float t[32][33];
  const int tx = threadIdx.x & 31;
  const int ty = threadIdx.x >> 5;
#pragma unroll
  for (int j = 0; j < 4; ++j)
    t[ty + j * 8][tx] = in[(size_t)(r0 + ty + j * 8) * C + c0 + tx];
  __syncthreads();
#pragma unroll
  for (int j = 0; j < 4; ++j)
    out[(size_t)(c0 + ty + j * 8) * R + r0 + tx] = (bf16_t)t[tx][ty + j * 8];
}

// ---------------- merged K/V GEMM (64x64 tile, m97 staging), B^T input -------
#define BM 64
#define BN 64

__global__ __launch_bounds__(256) void gemm_kv_kernel(
    const bf16_t* __restrict__ A, const bf16_t* __restrict__ BT,
    bf16_t* __restrict__ Kout, bf16_t* __restrict__ VTout) {
  __shared__ __align__(16) bf16_t sA[64 * 64];   // 8KB, swizzled chunks
  __shared__ __align__(16) bf16_t sB[64 * 64];   // 8KB
  const int tid = threadIdx.x;
  const int w  = tid >> 6;
  const int l  = tid & 63;
  const int lg = l >> 4, lr = l & 15;
  const int wm = w >> 1, wn = w & 1;             // 2x2 waves, 32x32 each
  int bx = blockIdx.x, by = blockIdx.y;
  xcd_remap(bx, by);
  const int m0 = by * BM, n0 = bx * BN;
  const int K = HID_;

  size_t aoff[2], boff[2];
  int ldso[2];
#pragma unroll
  for (int i = 0; i < 2; ++i) {
    int cid = i * 256 + tid;            // 0..511 chunk id
    int row = cid >> 3, ch = cid & 7;
    int sch = ch ^ (row & 7);
    aoff[i] = (size_t)(m0 + row) * K + sch * 8;
    boff[i] = (size_t)(n0 + row) * K + sch * 8;
    ldso[i] = (i * 256 + w * 64) * 8;   // wave-uniform base (elems)
  }

  f32x4 acc[2][2];
#pragma unroll
  for (int mi = 0; mi < 2; ++mi)
#pragma unroll
    for (int ni = 0; ni < 2; ++ni) acc[mi][ni] = f32x4{0.f, 0.f, 0.f, 0.f};

  for (int k0 = 0; k0 < K; k0 += 64) {
#pragma unroll
    for (int i = 0; i < 2; ++i) {
      __builtin_amdgcn_global_load_lds((glb_u32_t*)(A + aoff[i] + k0),
                                       (lds_u32_t*)(sA + ldso[i]), 16, 0, 0);
      __builtin_amdgcn_global_load_lds((glb_u32_t*)(BT + boff[i] + k0),
                                       (lds_u32_t*)(sB + ldso[i]), 16, 0, 0);
    }
    asm volatile("s_waitcnt vmcnt(0)" ::: "memory");
    __syncthreads();

#pragma unroll
    for (int ks = 0; ks < 2; ++ks) {
      bf16x8 af[2], bfr[2];
#pragma unroll
      for (int mi = 0; mi < 2; ++mi) {
        int row = wm * 32 + mi * 16 + lr;
        af[mi] = *reinterpret_cast<const bf16x8*>(
            sA + row * 64 + (((ks * 4 + lg) ^ (row & 7)) << 3));
      }
#pragma unroll
      for (int ni = 0; ni < 2; ++ni) {
        int row = wn * 32 + ni * 16 + lr;
        bfr[ni] = *reinterpret_cast<const bf16x8*>(
            sB + row * 64 + (((ks * 4 + lg) ^ (row & 7)) << 3));
      }
#pragma unroll
      for (int mi = 0; mi < 2; ++mi)
#pragma unroll
        for (int ni = 0; ni < 2; ++ni)
          acc[mi][ni] = __builtin_amdgcn_mfma_f32_16x16x32_bf16(af[mi], bfr[ni], acc[mi][ni], 0, 0, 0);
    }
    __syncthreads();
  }

#pragma unroll
  for (int mi = 0; mi < 2; ++mi) {
#pragma unroll
    for (int ni = 0; ni < 2; ++ni) {
#pragma unroll
      for (int r = 0; r < 4; ++r) {
        int row = m0 + wm * 32 + mi * 16 + lg * 4 + r;
        int col = n0 + wn * 32 + ni * 16 + lr;
        float v = acc[mi][ni][r];
        if (col < DH_) Kout[(size_t)row * DH_ + col] = (bf16_t)v;
        else           VTout[(size_t)(col - DH_) * NROWS + row] = (bf16_t)v;
      }
    }
  }
}

// ---------------- big bf16 MFMA GEMM (128x128x64 tile, m97 structure) --------
template<int OMODE>
__global__ __launch_bounds__(256) void gemm128_kernel(
    const bf16_t* __restrict__ A, const bf16_t* __restrict__ BT,
    void* __restrict__ C, int M, int N, int K, float oscale) {
  __shared__ __align__(16) bf16_t sA[128 * 64];
  __shared__ __align__(16) bf16_t sB[128 * 64];
  const int tid = threadIdx.x;
  const int w  = tid >> 6;
  const int l  = tid & 63;
  const int lg = l >> 4, lr = l & 15;
  const int wm = w >> 1, wn = w & 1;
  int bx = blockIdx.x, by = blockIdx.y;
  xcd_remap(bx, by);
  const int m0 = by * 128, n0 = bx * 128;

  size_t aoff[4], boff[4];
  int ldsoff[4];
#pragma unroll
  for (int i = 0; i < 4; ++i) {
    int cid = i * 256 + tid;
    int row = cid >> 3, ch = cid & 7;
    int sch = ch ^ (row & 7);
    aoff[i] = (size_t)(m0 + row) * K + sch * 8;
    boff[i] = (size_t)(n0 + row) * K + sch * 8;
    ldsoff[i] = (i * 256 + w * 64) * 8;
  }

  f32x4 acc[4][4];
#pragma unroll
  for (int mi = 0; mi < 4; ++mi)
#pragma unroll
    for (int ni = 0; ni < 4; ++ni) acc[mi][ni] = f32x4{0.f, 0.f, 0.f, 0.f};

  for (int k0 = 0; k0 < K; k0 += 64) {
#pragma unroll
    for (int i = 0; i < 4; ++i) {
      __builtin_amdgcn_global_load_lds((glb_u32_t*)(A + aoff[i] + k0),
                                       (lds_u32_t*)(sA + ldsoff[i]), 16, 0, 0);
      __builtin_amdgcn_global_load_lds((glb_u32_t*)(BT + boff[i] + k0),
                                       (lds_u32_t*)(sB + ldsoff[i]), 16, 0, 0);
    }
    asm volatile("s_waitcnt vmcnt(0)" ::: "memory");
    __syncthreads();

#pragma unroll
    for (int ks = 0; ks < 2; ++ks) {
      bf16x8 af[4], bfr[4];
#pragma unroll
      for (int mi = 0; mi < 4; ++mi) {
        int row = wm * 64 + mi * 16 + lr;
        af[mi] = *reinterpret_cast<const bf16x8*>(
            sA + row * 64 + (((ks * 4 + lg) ^ (row & 7)) << 3));
      }
#pragma unroll
      for (int ni = 0; ni < 4; ++ni) {
        int row = wn * 64 + ni * 16 + lr;
        bfr[ni] = *reinterpret_cast<const bf16x8*>(
            sB + row * 64 + (((ks * 4 + lg) ^ (row & 7)) << 3));
      }
#pragma unroll
      for (int mi = 0; mi < 4; ++mi)
#pragma unroll
        for (int ni = 0; ni < 4; ++ni)
          acc[mi][ni] = __builtin_amdgcn_mfma_f32_16x16x32_bf16(af[mi], bfr[ni], acc[mi][ni], 0, 0, 0);
    }
    __syncthreads();
  }

#pragma unroll
  for (int mi = 0; mi < 4; ++mi) {
#pragma unroll
    for (int ni = 0; ni < 4; ++ni) {
#pragma unroll
      for (int r = 0; r < 4; ++r) {
        int row = m0 + wm * 64 + mi * 16 + lg * 4 + r;
        int col = n0 + wn * 64 + ni * 16 + lr;
        float v = acc[mi][ni][r];
        if (OMODE == 0) ((float*)C)[(size_t)row * N + col]  = v;
        else            ((bf16_t*)C)[(size_t)row * N + col] = (bf16_t)(v * oscale);
      }
    }
  }
}

// ---------------- 64x128x64-tile GEMM (m97 structure), B^T input --------------
template<int OMODE>
__global__ __launch_bounds__(256) void gemm64x128_kernel(
    const bf16_t* __restrict__ A, const bf16_t* __restrict__ BT,
    void* __restrict__ C, int M, int N, int K, float oscale) {
  __shared__ __align__(16) bf16_t sA[64 * 64];    // 8KB
  __shared__ __align__(16) bf16_t sB[128 * 64];   // 16KB
  const int tid = threadIdx.x;
  const int w  = tid >> 6;
  const int l  = tid & 63;
  const int lg = l >> 4, lr = l & 15;
  const int wm = w >> 1, wn = w & 1;
  int bx = blockIdx.x, by = blockIdx.y;
  xcd_remap(bx, by);
  const int m0 = by * 64, n0 = bx * 128;

  size_t aoff[2], boff[4];
  int ldsa[2], ldsb[4];
#pragma unroll
  for (int i = 0; i < 2; ++i) {
    int cid = i * 256 + tid;
    int row = cid >> 3, ch = cid & 7;
    aoff[i] = (size_t)(m0 + row) * K + (ch ^ (row & 7)) * 8;
    ldsa[i] = (i * 256 + w * 64) * 8;
  }
#pragma unroll
  for (int i = 0; i < 4; ++i) {
    int cid = i * 256 + tid;
    int row = cid >> 3, ch = cid & 7;
    boff[i] = (size_t)(n0 + row) * K + (ch ^ (row & 7)) * 8;
    ldsb[i] = (i * 256 + w * 64) * 8;
  }

  f32x4 acc[2][4];
#pragma unroll
  for (int mi = 0; mi < 2; ++mi)
#pragma unroll
    for (int ni = 0; ni < 4; ++ni) acc[mi][ni] = f32x4{0.f, 0.f, 0.f, 0.f};

  for (int k0 = 0; k0 < K; k0 += 64) {
#pragma unroll
    for (int i = 0; i < 2; ++i)
      __builtin_amdgcn_global_load_lds((glb_u32_t*)(A + aoff[i] + k0),
                                       (lds_u32_t*)(sA + ldsa[i]), 16, 0, 0);
#pragma unroll
    for (int i = 0; i < 4; ++i)
      __builtin_amdgcn_global_load_lds((glb_u32_t*)(BT + boff[i] + k0),
                                       (lds_u32_t*)(sB + ldsb[i]), 16, 0, 0);
    asm volatile("s_waitcnt vmcnt(0)" ::: "memory");
    __syncthreads();

#pragma unroll
    for (int ks = 0; ks < 2; ++ks) {
      bf16x8 af[2], bfr[4];
#pragma unroll
      for (int mi = 0; mi < 2; ++mi) {
        int row = wm * 32 + mi * 16 + lr;
        af[mi] = *reinterpret_cast<const bf16x8*>(
            sA + row * 64 + (((ks * 4 + lg) ^ (row & 7)) << 3));
      }
#pragma unroll
      for (int ni = 0; ni < 4; ++ni) {
        int row = wn * 64 + ni * 16 + lr;
        bfr[ni] = *reinterpret_cast<const bf16x8*>(
            sB + row * 64 + (((ks * 4 + lg) ^ (row & 7)) << 3));
      }
#pragma unroll
      for (int mi = 0; mi < 2; ++mi)
#pragma unroll
        for (int ni = 0; ni < 4; ++ni)
          acc[mi][ni] = __builtin_amdgcn_mfma_f32_16x16x32_bf16(af[mi], bfr[ni], acc[mi][ni], 0, 0, 0);
    }
    __syncthreads();
  }

#pragma unroll
  for (int mi = 0; mi < 2; ++mi) {
#pragma unroll
    for (int ni = 0; ni < 4; ++ni) {
#pragma unroll
      for (int r = 0; r < 4; ++r) {
        int row = m0 + wm * 32 + mi * 16 + lg * 4 + r;
        int col = n0 + wn * 64 + ni * 16 + lr;
        float v = acc[mi][ni][r];
        if (OMODE == 0) ((float*)C)[(size_t)row * N + col]  = v;
        else            ((bf16_t*)C)[(size_t)row * N + col] = (bf16_t)(v * oscale);
      }
    }
  }
}

// ---------------- RMSNorm (in-place, one wave per row of 512) ----------------
__global__ __launch_bounds__(64) void rmsnorm_kernel(bf16_t* __restrict__ qa,
                                                     const float* __restrict__ wnorm) {
  int row = blockIdx.x;
  int l = threadIdx.x;
  bf16x8 v = *reinterpret_cast<const bf16x8*>(&qa[(size_t)row * QL_ + l * 8]);
  float f[8];
  float ss = 0.f;
#pragma unroll
  for (int e = 0; e < 8; ++e) { f[e] = (float)v[e]; ss += f[e] * f[e]; }
#pragma unroll
  for (int off = 32; off >= 1; off >>= 1) ss += __shfl_xor(ss, off);
  float rstd = rsqrtf(ss * (1.0f / 512.0f) + 1e-6f);
  bf16x8 o;
#pragma unroll
  for (int e = 0; e < 8; ++e) o[e] = (bf16_t)(f[e] * rstd * wnorm[l * 8 + e]);
  *reinterpret_cast<bf16x8*>(&qa[(size_t)row * QL_ + l * 8]) = o;
}

// ---------------- RoPE for K only (Q-rope fused into attn) ----------------
__global__ void rope_k_kernel(bf16_t* __restrict__ k) {
  int idx = blockIdx.x * blockDim.x + threadIdx.x;  // NROWS*32
  int d   = idx & 31;
  int row = idx >> 5;
  if (row >= NROWS) return;
  int s = row & (S_ - 1);
  float freq = (float)s * expf(-(float)d * (9.210340371976184f / 32.0f));
  float sn, cs;
  sincosf(freq, &sn, &cs);
  size_t base = (size_t)row * DH_ + DN_ + d;
  float k1 = (float)k[base], k2 = (float)k[base + 32];
  k[base]      = (bf16_t)(k1 * cs - k2 * sn);
  k[base + 32] = (bf16_t)(k2 * cs + k1 * sn);
}

// ---------------- causal flash attention with sink (r12 core + setprio) ------
// Q-RoPE applied in-register at load (pair qf[4][e] <-> qf[5][e], once/block)
// using hardware trig (__sincosf, exp2f) to keep the prologue cheap.
#define KB32  32
#define SPLD  40

__global__ __launch_bounds__(256, 2) void attn_kernel(
    const bf16_t* __restrict__ q, const bf16_t* __restrict__ k,
    const bf16_t* __restrict__ vt, const float* __restrict__ sink,
    bf16_t* __restrict__ attn) {
  __shared__ __align__(16) bf16_t sK[2][KB32 * DH_];   // 24KB dbuf
  __shared__ __align__(16) bf16_t sV[DH_ * KB32];      // 12KB single
  __shared__ __align__(16) bf16_t sP[4][32][SPLD];     // 10KB
  const int tid = threadIdx.x;
  const int w  = tid >> 6;
  const int l  = tid & 63;
  const int lg = l >> 4, lr = l & 15;
  const int qx = blockIdx.x >> 5;
  const int qt = (qx < 8) ? (15 - qx) : (qx - 8);  // heavy first
  const int bh = blockIdx.x & 31;
  const int b  = bh >> 4, h = bh & 15;
  const int wrow0 = qt * 128 + w * 32;
  const int ktmax_w = 4 * qt + w;
  const int ktmax_b = 4 * qt + 3;

  const bf16_t* kb  = k  + (size_t)(b * S_) * DH_;
  const bf16_t* vtb = vt + (size_t)(b * S_);

  int koff[3], voff[3], ldst[3];
#pragma unroll
  for (int i = 0; i < 3; ++i) {
    int g = i * 256 + tid;
    int krow = g / 24, kch = g - krow * 24;
    koff[i] = krow * DH_ + ((kch ^ (krow & 7)) << 3);
    int vrow = g >> 2, vch = g & 3;
    voff[i] = vrow * NROWS + ((vch ^ (vrow & 3)) << 3);
    ldst[i] = (i * 256 + w * 64) * 8;
  }

  auto stageK = [&](int kt, int bu) {
    const bf16_t* ksrc = kb + (size_t)kt * KB32 * DH_;
#pragma unroll
    for (int i = 0; i < 3; ++i)
      __builtin_amdgcn_global_load_lds((glb_u32_t*)(ksrc + koff[i]),
                                       (lds_u32_t*)(&sK[bu][0] + ldst[i]), 16, 0, 0);
  };
  auto stageV = [&](int kt) {
    const bf16_t* vsrc = vtb + kt * KB32;
#pragma unroll
    for (int i = 0; i < 3; ++i)
      __builtin_amdgcn_global_load_lds((glb_u32_t*)(vsrc + voff[i]),
                                       (lds_u32_t*)(sV + ldst[i]), 16, 0, 0);
  };

  bf16x8 qf[2][6];
#pragma unroll
  for (int rf = 0; rf < 2; ++rf) {
    size_t rowoff = (size_t)(b * S_ + wrow0 + rf * 16 + lr) * QKD + h * DH_;
#pragma unroll
    for (int ks = 0; ks < 6; ++ks)
      qf[rf][ks] = *reinterpret_cast<const bf16x8*>(&q[rowoff + ks * 32 + lg * 8]);
  }
  // ---- fused Q-RoPE (hardware trig): pair qf[4][e] <-> qf[5][e] ----
#pragma unroll
  for (int rf = 0; rf < 2; ++rf) {
    const float s = (float)(wrow0 + rf * 16 + lr);
#pragma unroll
    for (int e = 0; e < 8; ++e) {
      // invf = 10000^(-(lg*8+e)/32) = 2^(-(lg*8+e) * log2(10000)/32)
      float invf = exp2f(-(float)(lg * 8 + e) * 0.4152410118609203f);
      float sn, cs;
      __sincosf(s * invf, &sn, &cs);
      float x1 = (float)qf[rf][4][e], x2 = (float)qf[rf][5][e];
      qf[rf][4][e] = (bf16_t)(x1 * cs - x2 * sn);
      qf[rf][5][e] = (bf16_t)(x2 * cs + x1 * sn);
    }
  }

  bf16x8 vones;
#pragma unroll
  for (int e = 0; e < 8; ++e) vones[e] = (bf16_t)((lr == 0) ? 1.0f : 0.0f);

  f32x4 acc[2][13];
#pragma unroll
  for (int rf = 0; rf < 2; ++rf) {
#pragma unroll
    for (int c = 0; c < 12; ++c) acc[rf][c] = f32x4{0.f, 0.f, 0.f, 0.f};
    float init = (lr == 0) ? 1.0f : 0.0f;
    acc[rf][12] = f32x4{init, init, init, init};
  }

  const float L2E = 1.4426950408889634f;
  float m[2][4];
  float sk2 = sink[h] * L2E;
#pragma unroll
  for (int rf = 0; rf < 2; ++rf)
#pragma unroll
    for (int r = 0; r < 4; ++r) m[rf][r] = sk2;

  stageK(0, 0);
  int cur = 0;

  for (int kt = 0; kt <= ktmax_b; ++kt) {
    __syncthreads();                 // all waves done PV(kt-1): sV free; sK[cur^1] free

    stageV(kt);                      // must land before PV(kt)
    const bool more = (kt < ktmax_b);
    if (more) stageK(kt + 1, cur ^ 1);

    if (kt <= ktmax_w) {
      if (more) { asm volatile("s_waitcnt vmcnt(6)" ::: "memory"); }
      else      { asm volatile("s_waitcnt vmcnt(3)" ::: "memory"); }

      f32x4 sc[2][2];
#pragma unroll
      for (int rf = 0; rf < 2; ++rf)
#pragma unroll
        for (int c = 0; c < 2; ++c) sc[rf][c] = f32x4{0.f, 0.f, 0.f, 0.f};
      __builtin_amdgcn_s_setprio(1);
#pragma unroll
      for (int c = 0; c < 2; ++c) {
        const int row = c * 16 + lr;
        const int rx  = row & 7;
        const bf16_t* kr = &sK[cur][0] + row * DH_;
#pragma unroll
        for (int ks = 0; ks < 6; ++ks) {
          bf16x8 kf = *reinterpret_cast<const bf16x8*>(kr + (((ks * 4 + lg) ^ rx) << 3));
          sc[0][c] = __builtin_amdgcn_mfma_f32_16x16x32_bf16(qf[0][ks], kf, sc[0][c], 0, 0, 0);
          sc[1][c] = __builtin_amdgcn_mfma_f32_16x16x32_bf16(qf[1][ks], kf, sc[1][c], 0, 0, 0);
        }
      }
      __builtin_amdgcn_s_setprio(0);

      if (kt == ktmax_w) {
#pragma unroll
        for (int rf = 0; rf < 2; ++rf)
#pragma unroll
          for (int c = 0; c < 2; ++c)
#pragma unroll
            for (int r = 0; r < 4; ++r)
              if ((kt * 32 + c * 16 + lr) > (wrow0 + rf * 16 + lg * 4 + r))
                sc[rf][c][r] = -1e30f;
      }

      int ok = 1;
      float lmax[2][4];
#pragma unroll
      for (int rf = 0; rf < 2; ++rf)
#pragma unroll
        for (int r = 0; r < 4; ++r) {
          lmax[rf][r] = fmaxf(sc[rf][0][r], sc[rf][1][r]);
          ok &= (lmax[rf][r] <= m[rf][r] + 8.0f);
        }
      if (!__all(ok)) {
#pragma unroll
        for (int rf = 0; rf < 2; ++rf) {
          float rmax[4], alpha[4];
#pragma unroll
          for (int r = 0; r < 4; ++r) rmax[r] = lmax[rf][r];
#pragma unroll
          for (int off = 1; off < 16; off <<= 1) {
#pragma unroll
            for (int r = 0; r < 4; ++r) rmax[r] = fmaxf(rmax[r], __shfl_xor(rmax[r], off));
          }
#pragma unroll
          for (int r = 0; r < 4; ++r) {
            float mn = fmaxf(m[rf][r], rmax[r]);
            alpha[r] = EXP2(m[rf][r] - mn);
            m[rf][r] = mn;
          }
#pragma unroll
          for (int c = 0; c < 13; ++c)
#pragma unroll
            for (int r = 0; r < 4; ++r) acc[rf][c][r] *= alpha[r];
        }
      }

#pragma unroll
      for (int rf = 0; rf < 2; ++rf)
#pragma unroll
        for (int c = 0; c < 2; ++c)
#pragma unroll
          for (int r = 0; r < 4; ++r)
            sP[w][rf * 16 + lg * 4 + r][c * 16 + lr] = (bf16_t)EXP2(sc[rf][c][r] - m[rf][r]);

      if (more) { asm volatile("s_waitcnt vmcnt(3)" ::: "memory"); }
      else      { asm volatile("s_waitcnt vmcnt(0)" ::: "memory"); }

      bf16x8 pf[2];
      pf[0] = *reinterpret_cast<const bf16x8*>(&sP[w][lr][lg * 8]);
      pf[1] = *reinterpret_cast<const bf16x8*>(&sP[w][16 + lr][lg * 8]);
      __builtin_amdgcn_s_setprio(1);
#pragma unroll
      for (int c2 = 0; c2 < 12; ++c2) {
        const int row = c2 * 16 + lr;
        bf16x8 vf = *reinterpret_cast<const bf16x8*>(
            sV + row * KB32 + ((lg ^ (row & 3)) << 3));
        acc[0][c2] = __builtin_amdgcn_mfma_f32_16x16x32_bf16(pf[0], vf, acc[0][c2], 0, 0, 0);
        acc[1][c2] = __builtin_amdgcn_mfma_f32_16x16x32_bf16(pf[1], vf, acc[1][c2], 0, 0, 0);
      }
      acc[0][12] = __builtin_amdgcn_mfma_f32_16x16x32_bf16(pf[0], vones, acc[0][12], 0, 0, 0);
      acc[1][12] = __builtin_amdgcn_mfma_f32_16x16x32_bf16(pf[1], vones, acc[1][12], 0, 0, 0);
      __builtin_amdgcn_s_setprio(0);
    }
    cur ^= 1;
  }

  // ---- epilogue ----
#pragma unroll
  for (int rf = 0; rf < 2; ++rf) {
    float rl[4];
#pragma unroll
    for (int r = 0; r < 4; ++r) rl[r] = 1.0f / __shfl(acc[rf][12][r], l & 48);
#pragma unroll
    for (int c2 = 0; c2 < 12; ++c2) {
#pragma unroll
      for (int r = 0; r < 4; ++r) {
        int i = wrow0 + rf * 16 + lg * 4 + r;
        size_t off = (size_t)(b * S_ + i) * QKD + h * DH_ + c2 * 16 + lr;
        attn[off] = (bf16_t)(acc[rf][c2][r] * rl[r]);
      }
    }
  }
}

// ---------------- launch ----------------
extern "C" void kernel_launch(void* const* d_in, const int* in_sizes, int n_in,
                              void* d_out, int out_size, void* d_ws, size_t ws_size,
                              hipStream_t stream) {
  const float* x        = (const float*)d_in[0];
  const float* w_qa     = (const float*)d_in[1];
  const float* q_norm_w = (const float*)d_in[2];
  const float* w_qb     = (const float*)d_in[3];
  const float* w_k      = (const float*)d_in[4];
  const float* w_v      = (const float*)d_in[5];
  const float* w_o      = (const float*)d_in[6];
  const float* attn_sink= (const float*)d_in[7];
  float* out = (float*)d_out;

  char* ws = (char*)d_ws;
  size_t off = 0;
  auto alloc = [&](size_t bytes) -> void* {
    void* p = ws + off;
    off += (bytes + 255) & ~(size_t)255;
    return p;
  };
  bf16_t* q_b  = (bf16_t*)alloc((size_t)NROWS * QKD * 2);
  bf16_t* k_b  = (bf16_t*)alloc((size_t)NROWS * DH_ * 2);
  bf16_t* vt_b = (bf16_t*)alloc((size_t)DH_ * NROWS * 2);
  bf16_t* wo_t = (bf16_t*)alloc((size_t)HID_ * QKD * 2);   // w_o^T [2048][3072]
  size_t temp_start = off;
  bf16_t* xb    = (bf16_t*)alloc((size_t)NROWS * HID_ * 2);
  bf16_t* wqa_t = (bf16_t*)alloc((size_t)QL_ * HID_ * 2);  // [512][2048]
  bf16_t* wqb_t = (bf16_t*)alloc((size_t)QKD * QL_ * 2);   // [3072][512]
  bf16_t* wkv_t = (bf16_t*)alloc((size_t)(2 * DH_) * HID_ * 2); // [384][2048]
  bf16_t* qa_b  = (bf16_t*)alloc((size_t)NROWS * QL_ * 2);
  bf16_t* attn_b = (bf16_t*)(ws + temp_start);             // overlays dead temps

  const float SCALE2 = 0.10411754646447386f;  // 192^-0.5 * log2(e)

  int n4x = (int)((size_t)NROWS * HID_ / 4);
  cast_f32_to_bf16<<<dim3((n4x + 255) / 256), dim3(256), 0, stream>>>(x, xb, n4x);
  transpose_all<<<dim3(9472), dim3(256), 0, stream>>>(
      w_qa, w_qb, w_k, w_v, w_o,
      wqa_t, wqb_t, wkv_t, wkv_t + (size_t)DH_ * HID_, wo_t);

  // q_a = rmsnorm(x @ w_qa)   [64x128 tile: 256 blocks]
  gemm64x128_kernel<1><<<dim3(QL_ / 128, NROWS / 64), 256, 0, stream>>>(xb, wqa_t, qa_b, NROWS, QL_, HID_, 1.0f);
  rmsnorm_kernel<<<dim3(NROWS), dim3(64), 0, stream>>>(qa_b, q_norm_w);
  // q = (q_a @ w_qb) * SCALE2  [128 tile: 768 blocks]
  gemm128_kernel<1><<<dim3(QKD / 128, NROWS / 128), 256, 0, stream>>>(qa_b, wqb_t, q_b, NROWS, QKD, QL_, SCALE2);
  // k + v^T in one launch    [64x64 m97 tile: 384 blocks]
  gemm_kv_kernel<<<dim3((2 * DH_) / BN, NROWS / BM), 256, 0, stream>>>(xb, wkv_t, k_b, vt_b);
  // K-RoPE only (Q-RoPE fused into attn)
  rope_k_kernel<<<dim3((NROWS * 32) / 256), dim3(256), 0, stream>>>(k_b);
  attn_kernel<<<dim3(512), dim3(256), 0, stream>>>(q_b, k_b, vt_b, attn_sink, attn_b);
  // out = attn @ w_o          [128x128 tile: 512 blocks]
  gemm128_kernel<0><<<dim3(HID_ / 128, NROWS / 128), 256, 0, stream>>>(attn_b, wo_t, out, NROWS, HID_, QKD, 1.0f);
}

// Round 20
// 251.900 us; speedup vs baseline: 1.2513x; 1.0067x over previous
//
#include <hip/hip_runtime.h>
#include <hip/hip_bf16.h>

typedef __bf16 bf16_t;
typedef __bf16 bf16x8 __attribute__((ext_vector_type(8)));
typedef __bf16 bf16x4 __attribute__((ext_vector_type(4)));
typedef float  f32x4  __attribute__((ext_vector_type(4)));
typedef __attribute__((address_space(3))) unsigned int lds_u32_t;
typedef __attribute__((address_space(1))) const unsigned int glb_u32_t;

#define B_    2
#define S_    2048
#define HID_  2048
#define H_    16
#define DH_   192
#define DR_   64
#define DN_   128
#define QL_   512
#define NROWS (B_*S_)          // 4096
#define QKD   (H_*DH_)         // 3072

#if __has_builtin(__builtin_amdgcn_exp2f)
#define EXP2(x) __builtin_amdgcn_exp2f(x)
#else
#define EXP2(x) exp2f(x)
#endif

// XCD-aware bijective block swizzle (requires nwg % 8 == 0).
__device__ inline void xcd_remap(int& bx, int& by) {
  const int gx = gridDim.x;
  const int nwg = gx * gridDim.y;
  const int flat = by * gx + bx;
  const int q = nwg >> 3;
  const int nf = (flat & 7) * q + (flat >> 3);
  bx = nf % gx;
  by = nf / gx;
}

// ---------------- weight transposes + x cast, one launch ----------------
// ids [0,9472): f32 [R][C] -> bf16 [C][R] 32x32 tiles (5 weights).
// ids [9472,11520): cast x f32 -> bf16 (1024 float4 per block).
__global__ __launch_bounds__(256) void prep_all(
    const float* __restrict__ i0, const float* __restrict__ i1,
    const float* __restrict__ i2, const float* __restrict__ i3,
    const float* __restrict__ i4, const float* __restrict__ xin,
    bf16_t* __restrict__ o0, bf16_t* __restrict__ o1, bf16_t* __restrict__ o2,
    bf16_t* __restrict__ o3, bf16_t* __restrict__ o4, bf16_t* __restrict__ xout) {
  int id = blockIdx.x;
  if (id >= 9472) {
    const int lid = id - 9472;
    const float4* src = reinterpret_cast<const float4*>(xin);
    bf16x4* dst = reinterpret_cast<bf16x4*>(xout);
    const int base = lid * 1024;
#pragma unroll
    for (int j = 0; j < 4; ++j) {
      int idx = base + j * 256 + threadIdx.x;
      float4 v = src[idx];
      bf16x4 r;
      r[0] = (bf16_t)v.x; r[1] = (bf16_t)v.y; r[2] = (bf16_t)v.z; r[3] = (bf16_t)v.w;
      dst[idx] = r;
    }
    return;
  }
  const float* in; bf16_t* out; int R, C, lid;
  if (id < 1024)      { in = i0; out = o0; R = 2048; C = 512;  lid = id; }
  else if (id < 2560) { in = i1; out = o1; R = 512;  C = 3072; lid = id - 1024; }
  else if (id < 2944) { in = i2; out = o2; R = 2048; C = 192;  lid = id - 2560; }
  else if (id < 3328) { in = i3; out = o3; R = 2048; C = 192;  lid = id - 2944; }
  else                { in = i4; out = o4; R = 3072; C = 2048; lid = id - 3328; }
  const int cw = C >> 5;
  const int c0 = (lid % cw) * 32, r0 = (lid / cw) * 32;
  __shared__ float t[32][33];
  const int tx = threadIdx.x & 31;
  const int ty = threadIdx.x >> 5;
#pragma unroll
  for (int j = 0; j < 4; ++j)
    t[ty + j * 8][tx] = in[(size_t)(r0 + ty + j * 8) * C + c0 + tx];
  __syncthreads();
#pragma unroll
  for (int j = 0; j < 4; ++j)
    out[(size_t)(c0 + ty + j * 8) * R + r0 + tx] = (bf16_t)t[tx][ty + j * 8];
}

// ---------------- merged K/V GEMM (64x64 tile, m97 staging), B^T input -------
#define BM 64
#define BN 64

__global__ __launch_bounds__(256) void gemm_kv_kernel(
    const bf16_t* __restrict__ A, const bf16_t* __restrict__ BT,
    bf16_t* __restrict__ Kout, bf16_t* __restrict__ VTout) {
  __shared__ __align__(16) bf16_t sA[64 * 64];   // 8KB, swizzled chunks
  __shared__ __align__(16) bf16_t sB[64 * 64];   // 8KB
  const int tid = threadIdx.x;
  const int w  = tid >> 6;
  const int l  = tid & 63;
  const int lg = l >> 4, lr = l & 15;
  const int wm = w >> 1, wn = w & 1;             // 2x2 waves, 32x32 each
  int bx = blockIdx.x, by = blockIdx.y;
  xcd_remap(bx, by);
  const int m0 = by * BM, n0 = bx * BN;
  const int K = HID_;

  size_t aoff[2], boff[2];
  int ldso[2];
#pragma unroll
  for (int i = 0; i < 2; ++i) {
    int cid = i * 256 + tid;            // 0..511 chunk id
    int row = cid >> 3, ch = cid & 7;
    int sch = ch ^ (row & 7);
    aoff[i] = (size_t)(m0 + row) * K + sch * 8;
    boff[i] = (size_t)(n0 + row) * K + sch * 8;
    ldso[i] = (i * 256 + w * 64) * 8;   // wave-uniform base (elems)
  }

  f32x4 acc[2][2];
#pragma unroll
  for (int mi = 0; mi < 2; ++mi)
#pragma unroll
    for (int ni = 0; ni < 2; ++ni) acc[mi][ni] = f32x4{0.f, 0.f, 0.f, 0.f};

  for (int k0 = 0; k0 < K; k0 += 64) {
#pragma unroll
    for (int i = 0; i < 2; ++i) {
      __builtin_amdgcn_global_load_lds((glb_u32_t*)(A + aoff[i] + k0),
                                       (lds_u32_t*)(sA + ldso[i]), 16, 0, 0);
      __builtin_amdgcn_global_load_lds((glb_u32_t*)(BT + boff[i] + k0),
                                       (lds_u32_t*)(sB + ldso[i]), 16, 0, 0);
    }
    asm volatile("s_waitcnt vmcnt(0)" ::: "memory");
    __syncthreads();

#pragma unroll
    for (int ks = 0; ks < 2; ++ks) {
      bf16x8 af[2], bfr[2];
#pragma unroll
      for (int mi = 0; mi < 2; ++mi) {
        int row = wm * 32 + mi * 16 + lr;
        af[mi] = *reinterpret_cast<const bf16x8*>(
            sA + row * 64 + (((ks * 4 + lg) ^ (row & 7)) << 3));
      }
#pragma unroll
      for (int ni = 0; ni < 2; ++ni) {
        int row = wn * 32 + ni * 16 + lr;
        bfr[ni] = *reinterpret_cast<const bf16x8*>(
            sB + row * 64 + (((ks * 4 + lg) ^ (row & 7)) << 3));
      }
#pragma unroll
      for (int mi = 0; mi < 2; ++mi)
#pragma unroll
        for (int ni = 0; ni < 2; ++ni)
          acc[mi][ni] = __builtin_amdgcn_mfma_f32_16x16x32_bf16(af[mi], bfr[ni], acc[mi][ni], 0, 0, 0);
    }
    __syncthreads();
  }

#pragma unroll
  for (int mi = 0; mi < 2; ++mi) {
#pragma unroll
    for (int ni = 0; ni < 2; ++ni) {
#pragma unroll
      for (int r = 0; r < 4; ++r) {
        int row = m0 + wm * 32 + mi * 16 + lg * 4 + r;
        int col = n0 + wn * 32 + ni * 16 + lr;
        float v = acc[mi][ni][r];
        if (col < DH_) Kout[(size_t)row * DH_ + col] = (bf16_t)v;
        else           VTout[(size_t)(col - DH_) * NROWS + row] = (bf16_t)v;
      }
    }
  }
}

// ---------------- big bf16 MFMA GEMM (128x128x64 tile, m97 structure) --------
template<int OMODE>
__global__ __launch_bounds__(256) void gemm128_kernel(
    const bf16_t* __restrict__ A, const bf16_t* __restrict__ BT,
    void* __restrict__ C, int M, int N, int K, float oscale) {
  __shared__ __align__(16) bf16_t sA[128 * 64];
  __shared__ __align__(16) bf16_t sB[128 * 64];
  const int tid = threadIdx.x;
  const int w  = tid >> 6;
  const int l  = tid & 63;
  const int lg = l >> 4, lr = l & 15;
  const int wm = w >> 1, wn = w & 1;
  int bx = blockIdx.x, by = blockIdx.y;
  xcd_remap(bx, by);
  const int m0 = by * 128, n0 = bx * 128;

  size_t aoff[4], boff[4];
  int ldsoff[4];
#pragma unroll
  for (int i = 0; i < 4; ++i) {
    int cid = i * 256 + tid;
    int row = cid >> 3, ch = cid & 7;
    int sch = ch ^ (row & 7);
    aoff[i] = (size_t)(m0 + row) * K + sch * 8;
    boff[i] = (size_t)(n0 + row) * K + sch * 8;
    ldsoff[i] = (i * 256 + w * 64) * 8;
  }

  f32x4 acc[4][4];
#pragma unroll
  for (int mi = 0; mi < 4; ++mi)
#pragma unroll
    for (int ni = 0; ni < 4; ++ni) acc[mi][ni] = f32x4{0.f, 0.f, 0.f, 0.f};

  for (int k0 = 0; k0 < K; k0 += 64) {
#pragma unroll
    for (int i = 0; i < 4; ++i) {
      __builtin_amdgcn_global_load_lds((glb_u32_t*)(A + aoff[i] + k0),
                                       (lds_u32_t*)(sA + ldsoff[i]), 16, 0, 0);
      __builtin_amdgcn_global_load_lds((glb_u32_t*)(BT + boff[i] + k0),
                                       (lds_u32_t*)(sB + ldsoff[i]), 16, 0, 0);
    }
    asm volatile("s_waitcnt vmcnt(0)" ::: "memory");
    __syncthreads();

#pragma unroll
    for (int ks = 0; ks < 2; ++ks) {
      bf16x8 af[4], bfr[4];
#pragma unroll
      for (int mi = 0; mi < 4; ++mi) {
        int row = wm * 64 + mi * 16 + lr;
        af[mi] = *reinterpret_cast<const bf16x8*>(
            sA + row * 64 + (((ks * 4 + lg) ^ (row & 7)) << 3));
      }
#pragma unroll
      for (int ni = 0; ni < 4; ++ni) {
        int row = wn * 64 + ni * 16 + lr;
        bfr[ni] = *reinterpret_cast<const bf16x8*>(
            sB + row * 64 + (((ks * 4 + lg) ^ (row & 7)) << 3));
      }
#pragma unroll
      for (int mi = 0; mi < 4; ++mi)
#pragma unroll
        for (int ni = 0; ni < 4; ++ni)
          acc[mi][ni] = __builtin_amdgcn_mfma_f32_16x16x32_bf16(af[mi], bfr[ni], acc[mi][ni], 0, 0, 0);
    }
    __syncthreads();
  }

#pragma unroll
  for (int mi = 0; mi < 4; ++mi) {
#pragma unroll
    for (int ni = 0; ni < 4; ++ni) {
#pragma unroll
      for (int r = 0; r < 4; ++r) {
        int row = m0 + wm * 64 + mi * 16 + lg * 4 + r;
        int col = n0 + wn * 64 + ni * 16 + lr;
        float v = acc[mi][ni][r];
        if (OMODE == 0) ((float*)C)[(size_t)row * N + col]  = v;
        else            ((bf16_t*)C)[(size_t)row * N + col] = (bf16_t)(v * oscale);
      }
    }
  }
}

// ---------------- 64x128x64-tile GEMM (m97 structure), B^T input --------------
template<int OMODE>
__global__ __launch_bounds__(256) void gemm64x128_kernel(
    const bf16_t* __restrict__ A, const bf16_t* __restrict__ BT,
    void* __restrict__ C, int M, int N, int K, float oscale) {
  __shared__ __align__(16) bf16_t sA[64 * 64];    // 8KB
  __shared__ __align__(16) bf16_t sB[128 * 64];   // 16KB
  const int tid = threadIdx.x;
  const int w  = tid >> 6;
  const int l  = tid & 63;
  const int lg = l >> 4, lr = l & 15;
  const int wm = w >> 1, wn = w & 1;
  int bx = blockIdx.x, by = blockIdx.y;
  xcd_remap(bx, by);
  const int m0 = by * 64, n0 = bx * 128;

  size_t aoff[2], boff[4];
  int ldsa[2], ldsb[4];
#pragma unroll
  for (int i = 0; i < 2; ++i) {
    int cid = i * 256 + tid;
    int row = cid >> 3, ch = cid & 7;
    aoff[i] = (size_t)(m0 + row) * K + (ch ^ (row & 7)) * 8;
    ldsa[i] = (i * 256 + w * 64) * 8;
  }
#pragma unroll
  for (int i = 0; i < 4; ++i) {
    int cid = i * 256 + tid;
    int row = cid >> 3, ch = cid & 7;
    boff[i] = (size_t)(n0 + row) * K + (ch ^ (row & 7)) * 8;
    ldsb[i] = (i * 256 + w * 64) * 8;
  }

  f32x4 acc[2][4];
#pragma unroll
  for (int mi = 0; mi < 2; ++mi)
#pragma unroll
    for (int ni = 0; ni < 4; ++ni) acc[mi][ni] = f32x4{0.f, 0.f, 0.f, 0.f};

  for (int k0 = 0; k0 < K; k0 += 64) {
#pragma unroll
    for (int i = 0; i < 2; ++i)
      __builtin_amdgcn_global_load_lds((glb_u32_t*)(A + aoff[i] + k0),
                                       (lds_u32_t*)(sA + ldsa[i]), 16, 0, 0);
#pragma unroll
    for (int i = 0; i < 4; ++i)
      __builtin_amdgcn_global_load_lds((glb_u32_t*)(BT + boff[i] + k0),
                                       (lds_u32_t*)(sB + ldsb[i]), 16, 0, 0);
    asm volatile("s_waitcnt vmcnt(0)" ::: "memory");
    __syncthreads();

#pragma unroll
    for (int ks = 0; ks < 2; ++ks) {
      bf16x8 af[2], bfr[4];
#pragma unroll
      for (int mi = 0; mi < 2; ++mi) {
        int row = wm * 32 + mi * 16 + lr;
        af[mi] = *reinterpret_cast<const bf16x8*>(
            sA + row * 64 + (((ks * 4 + lg) ^ (row & 7)) << 3));
      }
#pragma unroll
      for (int ni = 0; ni < 4; ++ni) {
        int row = wn * 64 + ni * 16 + lr;
        bfr[ni] = *reinterpret_cast<const bf16x8*>(
            sB + row * 64 + (((ks * 4 + lg) ^ (row & 7)) << 3));
      }
#pragma unroll
      for (int mi = 0; mi < 2; ++mi)
#pragma unroll
        for (int ni = 0; ni < 4; ++ni)
          acc[mi][ni] = __builtin_amdgcn_mfma_f32_16x16x32_bf16(af[mi], bfr[ni], acc[mi][ni], 0, 0, 0);
    }
    __syncthreads();
  }

#pragma unroll
  for (int mi = 0; mi < 2; ++mi) {
#pragma unroll
    for (int ni = 0; ni < 4; ++ni) {
#pragma unroll
      for (int r = 0; r < 4; ++r) {
        int row = m0 + wm * 32 + mi * 16 + lg * 4 + r;
        int col = n0 + wn * 64 + ni * 16 + lr;
        float v = acc[mi][ni][r];
        if (OMODE == 0) ((float*)C)[(size_t)row * N + col]  = v;
        else            ((bf16_t*)C)[(size_t)row * N + col] = (bf16_t)(v * oscale);
      }
    }
  }
}

// ---------------- RMSNorm (in-place, one wave per row of 512) ----------------
__global__ __launch_bounds__(64) void rmsnorm_kernel(bf16_t* __restrict__ qa,
                                                     const float* __restrict__ wnorm) {
  int row = blockIdx.x;
  int l = threadIdx.x;
  bf16x8 v = *reinterpret_cast<const bf16x8*>(&qa[(size_t)row * QL_ + l * 8]);
  float f[8];
  float ss = 0.f;
#pragma unroll
  for (int e = 0; e < 8; ++e) { f[e] = (float)v[e]; ss += f[e] * f[e]; }
#pragma unroll
  for (int off = 32; off >= 1; off >>= 1) ss += __shfl_xor(ss, off);
  float rstd = rsqrtf(ss * (1.0f / 512.0f) + 1e-6f);
  bf16x8 o;
#pragma unroll
  for (int e = 0; e < 8; ++e) o[e] = (bf16_t)(f[e] * rstd * wnorm[l * 8 + e]);
  *reinterpret_cast<bf16x8*>(&qa[(size_t)row * QL_ + l * 8]) = o;
}

// ---------------- RoPE for K only (Q-rope fused into attn) ----------------
__global__ void rope_k_kernel(bf16_t* __restrict__ k) {
  int idx = blockIdx.x * blockDim.x + threadIdx.x;  // NROWS*32
  int d   = idx & 31;
  int row = idx >> 5;
  if (row >= NROWS) return;
  int s = row & (S_ - 1);
  float freq = (float)s * expf(-(float)d * (9.210340371976184f / 32.0f));
  float sn, cs;
  sincosf(freq, &sn, &cs);
  size_t base = (size_t)row * DH_ + DN_ + d;
  float k1 = (float)k[base], k2 = (float)k[base + 32];
  k[base]      = (bf16_t)(k1 * cs - k2 * sn);
  k[base + 32] = (bf16_t)(k2 * cs + k1 * sn);
}

// ---------------- causal flash attention with sink (r12 core + setprio) ------
// Q-RoPE applied in-register at load (pair qf[4][e] <-> qf[5][e], once/block)
// using hardware trig (__sincosf, exp2f) to keep the prologue cheap.
#define KB32  32
#define SPLD  40

__global__ __launch_bounds__(256, 2) void attn_kernel(
    const bf16_t* __restrict__ q, const bf16_t* __restrict__ k,
    const bf16_t* __restrict__ vt, const float* __restrict__ sink,
    bf16_t* __restrict__ attn) {
  __shared__ __align__(16) bf16_t sK[2][KB32 * DH_];   // 24KB dbuf
  __shared__ __align__(16) bf16_t sV[DH_ * KB32];      // 12KB single
  __shared__ __align__(16) bf16_t sP[4][32][SPLD];     // 10KB
  const int tid = threadIdx.x;
  const int w  = tid >> 6;
  const int l  = tid & 63;
  const int lg = l >> 4, lr = l & 15;
  const int qx = blockIdx.x >> 5;
  const int qt = (qx < 8) ? (15 - qx) : (qx - 8);  // heavy first
  const int bh = blockIdx.x & 31;
  const int b  = bh >> 4, h = bh & 15;
  const int wrow0 = qt * 128 + w * 32;
  const int ktmax_w = 4 * qt + w;
  const int ktmax_b = 4 * qt + 3;

  const bf16_t* kb  = k  + (size_t)(b * S_) * DH_;
  const bf16_t* vtb = vt + (size_t)(b * S_);

  int koff[3], voff[3], ldst[3];
#pragma unroll
  for (int i = 0; i < 3; ++i) {
    int g = i * 256 + tid;
    int krow = g / 24, kch = g - krow * 24;
    koff[i] = krow * DH_ + ((kch ^ (krow & 7)) << 3);
    int vrow = g >> 2, vch = g & 3;
    voff[i] = vrow * NROWS + ((vch ^ (vrow & 3)) << 3);
    ldst[i] = (i * 256 + w * 64) * 8;
  }

  auto stageK = [&](int kt, int bu) {
    const bf16_t* ksrc = kb + (size_t)kt * KB32 * DH_;
#pragma unroll
    for (int i = 0; i < 3; ++i)
      __builtin_amdgcn_global_load_lds((glb_u32_t*)(ksrc + koff[i]),
                                       (lds_u32_t*)(&sK[bu][0] + ldst[i]), 16, 0, 0);
  };
  auto stageV = [&](int kt) {
    const bf16_t* vsrc = vtb + kt * KB32;
#pragma unroll
    for (int i = 0; i < 3; ++i)
      __builtin_amdgcn_global_load_lds((glb_u32_t*)(vsrc + voff[i]),
                                       (lds_u32_t*)(sV + ldst[i]), 16, 0, 0);
  };

  bf16x8 qf[2][6];
#pragma unroll
  for (int rf = 0; rf < 2; ++rf) {
    size_t rowoff = (size_t)(b * S_ + wrow0 + rf * 16 + lr) * QKD + h * DH_;
#pragma unroll
    for (int ks = 0; ks < 6; ++ks)
      qf[rf][ks] = *reinterpret_cast<const bf16x8*>(&q[rowoff + ks * 32 + lg * 8]);
  }
  // ---- fused Q-RoPE (hardware trig): pair qf[4][e] <-> qf[5][e] ----
#pragma unroll
  for (int rf = 0; rf < 2; ++rf) {
    const float s = (float)(wrow0 + rf * 16 + lr);
#pragma unroll
    for (int e = 0; e < 8; ++e) {
      // invf = 10000^(-(lg*8+e)/32) = 2^(-(lg*8+e) * log2(10000)/32)
      float invf = exp2f(-(float)(lg * 8 + e) * 0.4152410118609203f);
      float sn, cs;
      __sincosf(s * invf, &sn, &cs);
      float x1 = (float)qf[rf][4][e], x2 = (float)qf[rf][5][e];
      qf[rf][4][e] = (bf16_t)(x1 * cs - x2 * sn);
      qf[rf][5][e] = (bf16_t)(x2 * cs + x1 * sn);
    }
  }

  bf16x8 vones;
#pragma unroll
  for (int e = 0; e < 8; ++e) vones[e] = (bf16_t)((lr == 0) ? 1.0f : 0.0f);

  f32x4 acc[2][13];
#pragma unroll
  for (int rf = 0; rf < 2; ++rf) {
#pragma unroll
    for (int c = 0; c < 12; ++c) acc[rf][c] = f32x4{0.f, 0.f, 0.f, 0.f};
    float init = (lr == 0) ? 1.0f : 0.0f;
    acc[rf][12] = f32x4{init, init, init, init};
  }

  const float L2E = 1.4426950408889634f;
  float m[2][4];
  float sk2 = sink[h] * L2E;
#pragma unroll
  for (int rf = 0; rf < 2; ++rf)
#pragma unroll
    for (int r = 0; r < 4; ++r) m[rf][r] = sk2;

  stageK(0, 0);
  int cur = 0;

  for (int kt = 0; kt <= ktmax_b; ++kt) {
    __syncthreads();                 // all waves done PV(kt-1): sV free; sK[cur^1] free

    stageV(kt);                      // must land before PV(kt)
    const bool more = (kt < ktmax_b);
    if (more) stageK(kt + 1, cur ^ 1);

    if (kt <= ktmax_w) {
      if (more) { asm volatile("s_waitcnt vmcnt(6)" ::: "memory"); }
      else      { asm volatile("s_waitcnt vmcnt(3)" ::: "memory"); }

      f32x4 sc[2][2];
#pragma unroll
      for (int rf = 0; rf < 2; ++rf)
#pragma unroll
        for (int c = 0; c < 2; ++c) sc[rf][c] = f32x4{0.f, 0.f, 0.f, 0.f};
      __builtin_amdgcn_s_setprio(1);
#pragma unroll
      for (int c = 0; c < 2; ++c) {
        const int row = c * 16 + lr;
        const int rx  = row & 7;
        const bf16_t* kr = &sK[cur][0] + row * DH_;
#pragma unroll
        for (int ks = 0; ks < 6; ++ks) {
          bf16x8 kf = *reinterpret_cast<const bf16x8*>(kr + (((ks * 4 + lg) ^ rx) << 3));
          sc[0][c] = __builtin_amdgcn_mfma_f32_16x16x32_bf16(qf[0][ks], kf, sc[0][c], 0, 0, 0);
          sc[1][c] = __builtin_amdgcn_mfma_f32_16x16x32_bf16(qf[1][ks], kf, sc[1][c], 0, 0, 0);
        }
      }
      __builtin_amdgcn_s_setprio(0);

      if (kt == ktmax_w) {
#pragma unroll
        for (int rf = 0; rf < 2; ++rf)
#pragma unroll
          for (int c = 0; c < 2; ++c)
#pragma unroll
            for (int r = 0; r < 4; ++r)
              if ((kt * 32 + c * 16 + lr) > (wrow0 + rf * 16 + lg * 4 + r))
                sc[rf][c][r] = -1e30f;
      }

      int ok = 1;
      float lmax[2][4];
#pragma unroll
      for (int rf = 0; rf < 2; ++rf)
#pragma unroll
        for (int r = 0; r < 4; ++r) {
          lmax[rf][r] = fmaxf(sc[rf][0][r], sc[rf][1][r]);
          ok &= (lmax[rf][r] <= m[rf][r] + 8.0f);
        }
      if (!__all(ok)) {
#pragma unroll
        for (int rf = 0; rf < 2; ++rf) {
          float rmax[4], alpha[4];
#pragma unroll
          for (int r = 0; r < 4; ++r) rmax[r] = lmax[rf][r];
#pragma unroll
          for (int off = 1; off < 16; off <<= 1) {
#pragma unroll
            for (int r = 0; r < 4; ++r) rmax[r] = fmaxf(rmax[r], __shfl_xor(rmax[r], off));
          }
#pragma unroll
          for (int r = 0; r < 4; ++r) {
            float mn = fmaxf(m[rf][r], rmax[r]);
            alpha[r] = EXP2(m[rf][r] - mn);
            m[rf][r] = mn;
          }
#pragma unroll
          for (int c = 0; c < 13; ++c)
#pragma unroll
            for (int r = 0; r < 4; ++r) acc[rf][c][r] *= alpha[r];
        }
      }

#pragma unroll
      for (int rf = 0; rf < 2; ++rf)
#pragma unroll
        for (int c = 0; c < 2; ++c)
#pragma unroll
          for (int r = 0; r < 4; ++r)
            sP[w][rf * 16 + lg * 4 + r][c * 16 + lr] = (bf16_t)EXP2(sc[rf][c][r] - m[rf][r]);

      if (more) { asm volatile("s_waitcnt vmcnt(3)" ::: "memory"); }
      else      { asm volatile("s_waitcnt vmcnt(0)" ::: "memory"); }

      bf16x8 pf[2];
      pf[0] = *reinterpret_cast<const bf16x8*>(&sP[w][lr][lg * 8]);
      pf[1] = *reinterpret_cast<const bf16x8*>(&sP[w][16 + lr][lg * 8]);
      __builtin_amdgcn_s_setprio(1);
#pragma unroll
      for (int c2 = 0; c2 < 12; ++c2) {
        const int row = c2 * 16 + lr;
        bf16x8 vf = *reinterpret_cast<const bf16x8*>(
            sV + row * KB32 + ((lg ^ (row & 3)) << 3));
        acc[0][c2] = __builtin_amdgcn_mfma_f32_16x16x32_bf16(pf[0], vf, acc[0][c2], 0, 0, 0);
        acc[1][c2] = __builtin_amdgcn_mfma_f32_16x16x32_bf16(pf[1], vf, acc[1][c2], 0, 0, 0);
      }
      acc[0][12] = __builtin_amdgcn_mfma_f32_16x16x32_bf16(pf[0], vones, acc[0][12], 0, 0, 0);
      acc[1][12] = __builtin_amdgcn_mfma_f32_16x16x32_bf16(pf[1], vones, acc[1][12], 0, 0, 0);
      __builtin_amdgcn_s_setprio(0);
    }
    cur ^= 1;
  }

  // ---- epilogue ----
#pragma unroll
  for (int rf = 0; rf < 2; ++rf) {
    float rl[4];
#pragma unroll
    for (int r = 0; r < 4; ++r) rl[r] = 1.0f / __shfl(acc[rf][12][r], l & 48);
#pragma unroll
    for (int c2 = 0; c2 < 12; ++c2) {
#pragma unroll
      for (int r = 0; r < 4; ++r) {
        int i = wrow0 + rf * 16 + lg * 4 + r;
        size_t off = (size_t)(b * S_ + i) * QKD + h * DH_ + c2 * 16 + lr;
        attn[off] = (bf16_t)(acc[rf][c2][r] * rl[r]);
      }
    }
  }
}

// ---------------- launch ----------------
extern "C" void kernel_launch(void* const* d_in, const int* in_sizes, int n_in,
                              void* d_out, int out_size, void* d_ws, size_t ws_size,
                              hipStream_t stream) {
  const float* x        = (const float*)d_in[0];
  const float* w_qa     = (const float*)d_in[1];
  const float* q_norm_w = (const float*)d_in[2];
  const float* w_qb     = (const float*)d_in[3];
  const float* w_k      = (const float*)d_in[4];
  const float* w_v      = (const float*)d_in[5];
  const float* w_o      = (const float*)d_in[6];
  const float* attn_sink= (const float*)d_in[7];
  float* out = (float*)d_out;

  char* ws = (char*)d_ws;
  size_t off = 0;
  auto alloc = [&](size_t bytes) -> void* {
    void* p = ws + off;
    off += (bytes + 255) & ~(size_t)255;
    return p;
  };
  bf16_t* q_b  = (bf16_t*)alloc((size_t)NROWS * QKD * 2);
  bf16_t* k_b  = (bf16_t*)alloc((size_t)NROWS * DH_ * 2);
  bf16_t* vt_b = (bf16_t*)alloc((size_t)DH_ * NROWS * 2);
  bf16_t* wo_t = (bf16_t*)alloc((size_t)HID_ * QKD * 2);   // w_o^T [2048][3072]
  size_t temp_start = off;
  bf16_t* xb    = (bf16_t*)alloc((size_t)NROWS * HID_ * 2);
  bf16_t* wqa_t = (bf16_t*)alloc((size_t)QL_ * HID_ * 2);  // [512][2048]
  bf16_t* wqb_t = (bf16_t*)alloc((size_t)QKD * QL_ * 2);   // [3072][512]
  bf16_t* wkv_t = (bf16_t*)alloc((size_t)(2 * DH_) * HID_ * 2); // [384][2048]
  bf16_t* qa_b  = (bf16_t*)alloc((size_t)NROWS * QL_ * 2);
  bf16_t* attn_b = (bf16_t*)(ws + temp_start);             // overlays dead temps

  const float SCALE2 = 0.10411754646447386f;  // 192^-0.5 * log2(e)

  // all 5 weight transposes + x cast in one launch
  prep_all<<<dim3(11520), dim3(256), 0, stream>>>(
      w_qa, w_qb, w_k, w_v, w_o, x,
      wqa_t, wqb_t, wkv_t, wkv_t + (size_t)DH_ * HID_, wo_t, xb);

  // q_a = rmsnorm(x @ w_qa)   [64x128 tile: 256 blocks]
  gemm64x128_kernel<1><<<dim3(QL_ / 128, NROWS / 64), 256, 0, stream>>>(xb, wqa_t, qa_b, NROWS, QL_, HID_, 1.0f);
  rmsnorm_kernel<<<dim3(NROWS), dim3(64), 0, stream>>>(qa_b, q_norm_w);
  // q = (q_a @ w_qb) * SCALE2  [128 tile: 768 blocks]
  gemm128_kernel<1><<<dim3(QKD / 128, NROWS / 128), 256, 0, stream>>>(qa_b, wqb_t, q_b, NROWS, QKD, QL_, SCALE2);
  // k + v^T in one launch    [64x64 m97 tile: 384 blocks]
  gemm_kv_kernel<<<dim3((2 * DH_) / BN, NROWS / BM), 256, 0, stream>>>(xb, wkv_t, k_b, vt_b);
  // K-RoPE only (Q-RoPE fused into attn)
  rope_k_kernel<<<dim3((NROWS * 32) / 256), dim3(256), 0, stream>>>(k_b);
  attn_kernel<<<dim3(512), dim3(256), 0, stream>>>(q_b, k_b, vt_b, attn_sink, attn_b);
  // out = attn @ w_o          [128x128 tile: 512 blocks]
  gemm128_kernel<0><<<dim3(HID_ / 128, NROWS / 128), 256, 0, stream>>>(attn_b, wo_t, out, NROWS, HID_, QKD, 1.0f);
}